// Round 2
// baseline (4442.022 us; speedup 1.0000x reference)
//
#include <hip/hip_runtime.h>

constexpr int kN = 50000;
constexpr int kE = 800000;
constexpr int kD = 128;
constexpr int kB = 256;
constexpr int kL = 3;
constexpr float kEps = 1e-5f;

__device__ __forceinline__ float4 bnrelu4(float4 v, float4 sc, float4 sh) {
  float4 r;
  r.x = fmaxf(fmaf(v.x, sc.x, sh.x), 0.f);
  r.y = fmaxf(fmaf(v.y, sc.y, sh.y), 0.f);
  r.z = fmaxf(fmaf(v.z, sc.z, sh.z), 0.f);
  r.w = fmaxf(fmaf(v.w, sc.w, sh.w), 0.f);
  return r;
}

__device__ __forceinline__ void fma4(float4& acc, float s, const float4& wv) {
  acc.x = fmaf(s, wv.x, acc.x);
  acc.y = fmaf(s, wv.y, acc.y);
  acc.z = fmaf(s, wv.z, acc.z);
  acc.w = fmaf(s, wv.w, acc.w);
}

// agg[n] = f(h[n])  where f = bn+relu (if scale) or identity
__global__ void k_init(const float* __restrict__ h, const float* __restrict__ scale,
                       const float* __restrict__ shift, float* __restrict__ agg) {
  int t = blockIdx.x * 256 + threadIdx.x;
  if (t >= kN * 32) return;
  int n = t >> 5, q = t & 31;
  float4 v = reinterpret_cast<const float4*>(h)[(size_t)n * 32 + q];
  if (scale != nullptr) {
    float4 sc = reinterpret_cast<const float4*>(scale)[q];
    float4 sh = reinterpret_cast<const float4*>(shift)[q];
    v = bnrelu4(v, sc, sh);
  }
  reinterpret_cast<float4*>(agg)[(size_t)n * 32 + q] = v;
}

// agg[dst] += f(h[src]) over all edges
__global__ void k_agg(const float* __restrict__ h, const int* __restrict__ ei,
                      const float* __restrict__ scale, const float* __restrict__ shift,
                      float* __restrict__ agg) {
  int t = blockIdx.x * 256 + threadIdx.x;
  int e = t >> 5, q = t & 31;
  if (e >= kE) return;
  int s = ei[e];
  int d = ei[kE + e];
  float4 v = reinterpret_cast<const float4*>(h)[(size_t)s * 32 + q];
  if (scale != nullptr) {
    float4 sc = reinterpret_cast<const float4*>(scale)[q];
    float4 sh = reinterpret_cast<const float4*>(shift)[q];
    v = bnrelu4(v, sc, sh);
  }
  float* ap = agg + (size_t)d * kD + q * 4;
  atomicAdd(ap + 0, v.x);
  atomicAdd(ap + 1, v.y);
  atomicAdd(ap + 2, v.z);
  atomicAdd(ap + 3, v.w);
}

// Y = f(A) @ W + bias ; also accumulate column sum/sumsq of Y into s_sum/s_ss.
// f(A) = relu(A*scaleA+shiftA) per column if scaleA != nullptr, else identity.
// Tile: 64 rows x 128 cols per block of 256 threads; per-thread 8 rows x 4 cols.
__global__ __launch_bounds__(256) void k_gemm(
    const float* __restrict__ A, const float* __restrict__ W,
    const float* __restrict__ bias, const float* __restrict__ scaleA,
    const float* __restrict__ shiftA, float* __restrict__ Y,
    float* __restrict__ s_sum, float* __restrict__ s_ss) {
  __shared__ float as_[64][36];   // +4 pad, keeps 16B alignment
  __shared__ float ws_[32][128];
  __shared__ float red[2][1024];

  const int tid = threadIdx.x;
  const int tx = tid & 31;   // col group: cols tx*4..tx*4+3
  const int ty = tid >> 5;   // row group: rows ty*8..ty*8+7
  const int row0 = blockIdx.x * 64;

  float4 acc[8];
#pragma unroll
  for (int r = 0; r < 8; ++r) acc[r] = make_float4(0.f, 0.f, 0.f, 0.f);

  // staging maps
  const int ar = tid >> 2;          // 0..63
  const int aq = (tid & 3) * 8;     // 0,8,16,24
  const int wk = tid >> 3;          // 0..31
  const int wc = (tid & 7) * 16;    // 0..112

  for (int kk = 0; kk < kD; kk += 32) {
    // ---- stage A[row0..row0+64)[kk..kk+32) ----
    float4 a0 = make_float4(0.f, 0.f, 0.f, 0.f);
    float4 a1 = make_float4(0.f, 0.f, 0.f, 0.f);
    int arow = row0 + ar;
    if (arow < kN) {
      const float* ap = A + (size_t)arow * kD + kk + aq;
      a0 = *reinterpret_cast<const float4*>(ap);
      a1 = *reinterpret_cast<const float4*>(ap + 4);
      if (scaleA != nullptr) {
        float4 sc0 = *reinterpret_cast<const float4*>(scaleA + kk + aq);
        float4 sc1 = *reinterpret_cast<const float4*>(scaleA + kk + aq + 4);
        float4 sh0 = *reinterpret_cast<const float4*>(shiftA + kk + aq);
        float4 sh1 = *reinterpret_cast<const float4*>(shiftA + kk + aq + 4);
        a0 = bnrelu4(a0, sc0, sh0);
        a1 = bnrelu4(a1, sc1, sh1);
      }
    }
    *reinterpret_cast<float4*>(&as_[ar][aq]) = a0;
    *reinterpret_cast<float4*>(&as_[ar][aq + 4]) = a1;

    // ---- stage W[kk..kk+32)[0..128) ----
    const float* wp = W + (size_t)(kk + wk) * kD + wc;
#pragma unroll
    for (int j = 0; j < 4; ++j)
      *reinterpret_cast<float4*>(&ws_[wk][wc + 4 * j]) =
          *reinterpret_cast<const float4*>(wp + 4 * j);

    __syncthreads();

#pragma unroll
    for (int k4 = 0; k4 < 32; k4 += 4) {
      float4 w0 = *reinterpret_cast<float4*>(&ws_[k4 + 0][tx * 4]);
      float4 w1 = *reinterpret_cast<float4*>(&ws_[k4 + 1][tx * 4]);
      float4 w2 = *reinterpret_cast<float4*>(&ws_[k4 + 2][tx * 4]);
      float4 w3 = *reinterpret_cast<float4*>(&ws_[k4 + 3][tx * 4]);
#pragma unroll
      for (int r = 0; r < 8; ++r) {
        float4 a = *reinterpret_cast<float4*>(&as_[ty * 8 + r][k4]);
        fma4(acc[r], a.x, w0);
        fma4(acc[r], a.y, w1);
        fma4(acc[r], a.z, w2);
        fma4(acc[r], a.w, w3);
      }
    }
    __syncthreads();
  }

  // ---- epilogue: bias, store, column stats ----
  float4 b4 = *reinterpret_cast<const float4*>(bias + tx * 4);
  float4 ssum = make_float4(0.f, 0.f, 0.f, 0.f);
  float4 sss = make_float4(0.f, 0.f, 0.f, 0.f);
#pragma unroll
  for (int r = 0; r < 8; ++r) {
    int row = row0 + ty * 8 + r;
    float4 v;
    v.x = acc[r].x + b4.x;
    v.y = acc[r].y + b4.y;
    v.z = acc[r].z + b4.z;
    v.w = acc[r].w + b4.w;
    if (row < kN) {
      *reinterpret_cast<float4*>(Y + (size_t)row * kD + tx * 4) = v;
      ssum.x += v.x; ssum.y += v.y; ssum.z += v.z; ssum.w += v.w;
      sss.x += v.x * v.x; sss.y += v.y * v.y;
      sss.z += v.z * v.z; sss.w += v.w * v.w;
    }
  }
  red[0][(tx * 4 + 0) * 8 + ty] = ssum.x;
  red[0][(tx * 4 + 1) * 8 + ty] = ssum.y;
  red[0][(tx * 4 + 2) * 8 + ty] = ssum.z;
  red[0][(tx * 4 + 3) * 8 + ty] = ssum.w;
  red[1][(tx * 4 + 0) * 8 + ty] = sss.x;
  red[1][(tx * 4 + 1) * 8 + ty] = sss.y;
  red[1][(tx * 4 + 2) * 8 + ty] = sss.z;
  red[1][(tx * 4 + 3) * 8 + ty] = sss.w;
  __syncthreads();
  if (tid < kD) {
    float s = 0.f;
#pragma unroll
    for (int j = 0; j < 8; ++j) s += red[0][tid * 8 + j];
    atomicAdd(&s_sum[tid], s);
  } else if (tid < 2 * kD) {
    int c = tid - kD;
    float s = 0.f;
#pragma unroll
    for (int j = 0; j < 8; ++j) s += red[1][c * 8 + j];
    atomicAdd(&s_ss[c], s);
  }
}

// scale/shift from accumulated stats: bn(x) = x*scale + shift
__global__ void k_bnparams(const float* __restrict__ s_sum, const float* __restrict__ s_ss,
                           const float* __restrict__ g, const float* __restrict__ be,
                           float* __restrict__ scale, float* __restrict__ shift) {
  int c = threadIdx.x;
  float mu = s_sum[c] * (1.f / kN);
  float var = s_ss[c] * (1.f / kN) - mu * mu;
  float sc = g[c] * rsqrtf(var + kEps);
  scale[c] = sc;
  shift[c] = be[c] - mu * sc;
}

// out[batch[n]] += relu(bn(h[n]))
__global__ void k_pool(const float* __restrict__ h, const int* __restrict__ batch,
                       const float* __restrict__ scale, const float* __restrict__ shift,
                       float* __restrict__ out) {
  int t = blockIdx.x * 256 + threadIdx.x;
  if (t >= kN * 32) return;
  int n = t >> 5, q = t & 31;
  float4 v = reinterpret_cast<const float4*>(h)[(size_t)n * 32 + q];
  float4 sc = reinterpret_cast<const float4*>(scale)[q];
  float4 sh = reinterpret_cast<const float4*>(shift)[q];
  v = bnrelu4(v, sc, sh);
  int g = batch[n];
  float* op = out + (size_t)g * kD + q * 4;
  atomicAdd(op + 0, v.x);
  atomicAdd(op + 1, v.y);
  atomicAdd(op + 2, v.z);
  atomicAdd(op + 3, v.w);
}

extern "C" void kernel_launch(void* const* d_in, const int* in_sizes, int n_in,
                              void* d_out, int out_size, void* d_ws, size_t ws_size,
                              hipStream_t stream) {
  const float* x   = (const float*)d_in[0];
  const int*   ei  = (const int*)d_in[1];
  const int*   bat = (const int*)d_in[2];
  const float* W1  = (const float*)d_in[3];
  const float* b1  = (const float*)d_in[4];
  const float* g1  = (const float*)d_in[5];
  const float* be1 = (const float*)d_in[6];
  const float* W2  = (const float*)d_in[7];
  const float* b2  = (const float*)d_in[8];
  const float* g2  = (const float*)d_in[9];
  const float* be2 = (const float*)d_in[10];
  float* out = (float*)d_out;

  float* wsf = (float*)d_ws;
  // stats layout: 6 BN blocks of 512 floats: [sum(128) | sumsq(128) | scale(128) | shift(128)]
  float* bufA = (float*)((char*)d_ws + 16384);
  float* bufB = bufA + (size_t)kN * kD;

  (void)hipMemsetAsync(wsf, 0, 6 * 512 * sizeof(float), stream);
  (void)hipMemsetAsync(d_out, 0, (size_t)kB * kD * sizeof(float), stream);

  const float* curH = x;
  const float* curScale = nullptr;
  const float* curShift = nullptr;
  float* aggBuf = bufA;
  float* other = bufB;

  for (int l = 0; l < kL; ++l) {
    k_init<<<(kN * 32) / 256, 256, 0, stream>>>(curH, curScale, curShift, aggBuf);
    k_agg<<<(kE * 32) / 256, 256, 0, stream>>>(curH, ei, curScale, curShift, aggBuf);

    float* st1 = wsf + (size_t)(l * 2 + 0) * 512;
    k_gemm<<<(kN + 63) / 64, 256, 0, stream>>>(aggBuf, W1 + (size_t)l * kD * kD,
                                               b1 + l * kD, nullptr, nullptr, other,
                                               st1, st1 + 128);
    k_bnparams<<<1, kD, 0, stream>>>(st1, st1 + 128, g1 + l * kD, be1 + l * kD,
                                     st1 + 256, st1 + 384);

    float* st2 = wsf + (size_t)(l * 2 + 1) * 512;
    k_gemm<<<(kN + 63) / 64, 256, 0, stream>>>(other, W2 + (size_t)l * kD * kD,
                                               b2 + l * kD, st1 + 256, st1 + 384, aggBuf,
                                               st2, st2 + 128);
    k_bnparams<<<1, kD, 0, stream>>>(st2, st2 + 128, g2 + l * kD, be2 + l * kD,
                                     st2 + 256, st2 + 384);

    curH = aggBuf;
    curScale = st2 + 256;
    curShift = st2 + 384;
    float* tmp = aggBuf;
    aggBuf = other;
    other = tmp;
  }

  k_pool<<<(kN * 32) / 256, 256, 0, stream>>>(curH, bat, curScale, curShift, out);
}

// Round 3
// 730.078 us; speedup vs baseline: 6.0843x; 6.0843x over previous
//
#include <hip/hip_runtime.h>

constexpr int kN = 50000;
constexpr int kE = 800000;
constexpr int kD = 128;
constexpr int kB = 256;
constexpr int kL = 3;
constexpr float kEps = 1e-5f;

__device__ __forceinline__ float4 bnrelu4(float4 v, float4 sc, float4 sh) {
  float4 r;
  r.x = fmaxf(fmaf(v.x, sc.x, sh.x), 0.f);
  r.y = fmaxf(fmaf(v.y, sc.y, sh.y), 0.f);
  r.z = fmaxf(fmaf(v.z, sc.z, sh.z), 0.f);
  r.w = fmaxf(fmaf(v.w, sc.w, sh.w), 0.f);
  return r;
}

__device__ __forceinline__ float2 bnrelu2(float2 v, float2 sc, float2 sh) {
  float2 r;
  r.x = fmaxf(fmaf(v.x, sc.x, sh.x), 0.f);
  r.y = fmaxf(fmaf(v.y, sc.y, sh.y), 0.f);
  return r;
}

__device__ __forceinline__ void fma4(float4& acc, float s, const float4& wv) {
  acc.x = fmaf(s, wv.x, acc.x);
  acc.y = fmaf(s, wv.y, acc.y);
  acc.z = fmaf(s, wv.z, acc.z);
  acc.w = fmaf(s, wv.w, acc.w);
}

// ---------------- CSR build ----------------

// counts at rowptr[1+dst]
__global__ void k_hist(const int* __restrict__ ei, int* __restrict__ rowptr) {
  int e = blockIdx.x * 256 + threadIdx.x;
  if (e >= kE) return;
  atomicAdd(&rowptr[1 + ei[kE + e]], 1);
}

// single-block inclusive scan over n ints (wave-scan + cross-wave in LDS)
__global__ __launch_bounds__(1024) void k_scan(int* __restrict__ data, int n) {
  __shared__ int wsum[16];
  __shared__ int carry;
  const int tid = threadIdx.x;
  const int lane = tid & 63;
  const int wid = tid >> 6;
  if (tid == 0) carry = 0;
  __syncthreads();
  for (int base = 0; base < n; base += 1024) {
    int i = base + tid;
    int v = (i < n) ? data[i] : 0;
#pragma unroll
    for (int off = 1; off < 64; off <<= 1) {
      int t = __shfl_up(v, off);
      if (lane >= off) v += t;
    }
    if (lane == 63) wsum[wid] = v;
    __syncthreads();
    if (tid == 0) {
      int s = 0;
#pragma unroll
      for (int k = 0; k < 16; ++k) { s += wsum[k]; wsum[k] = s; }
    }
    __syncthreads();
    int out = v + (wid > 0 ? wsum[wid - 1] : 0) + carry;
    if (i < n) data[i] = out;
    __syncthreads();
    if (tid == 0) carry += wsum[15];
    __syncthreads();
  }
}

__global__ void k_fill(const int* __restrict__ ei, int* __restrict__ cursor,
                       int* __restrict__ srcs) {
  int e = blockIdx.x * 256 + threadIdx.x;
  if (e >= kE) return;
  int d = ei[kE + e];
  int p = atomicAdd(&cursor[d], 1);
  srcs[p] = ei[e];
}

// ---------------- aggregation: agg[n] = f(h[n]) + sum_{s in N(n)} f(h[s]) ----------------
// one wave per node; lane owns float2 at col 2*lane
template <bool BN>
__global__ __launch_bounds__(256) void k_gather(
    const float* __restrict__ h, const int* __restrict__ rowptr,
    const int* __restrict__ srcs, const float* __restrict__ scale,
    const float* __restrict__ shift, float* __restrict__ agg) {
  const int node = blockIdx.x * 4 + (threadIdx.x >> 6);
  const int lane = threadIdx.x & 63;
  const float2* h2 = reinterpret_cast<const float2*>(h);
  float2 sc, sh;
  if (BN) {
    sc = reinterpret_cast<const float2*>(scale)[lane];
    sh = reinterpret_cast<const float2*>(shift)[lane];
  }
  float2 acc = h2[(size_t)node * 64 + lane];
  if (BN) acc = bnrelu2(acc, sc, sh);
  const int beg = rowptr[node];
  const int end = rowptr[node + 1];
  for (int j0 = beg; j0 < end; j0 += 64) {
    int mysrc = (j0 + lane < end) ? srcs[j0 + lane] : 0;
    int cnt = min(64, end - j0);
    for (int t = 0; t < cnt; ++t) {
      int s = __shfl(mysrc, t);
      float2 v = h2[(size_t)s * 64 + lane];
      if (BN) v = bnrelu2(v, sc, sh);
      acc.x += v.x;
      acc.y += v.y;
    }
  }
  reinterpret_cast<float2*>(agg)[(size_t)node * 64 + lane] = acc;
}

// ---------------- fused GEMM + BN-stats ----------------
// Y = f(A) @ W + bias ; f = relu(A*scaleA+shiftA) if scaleA else identity.
// Also accumulates column sum/sumsq of Y.
__global__ __launch_bounds__(256) void k_gemm(
    const float* __restrict__ A, const float* __restrict__ W,
    const float* __restrict__ bias, const float* __restrict__ scaleA,
    const float* __restrict__ shiftA, float* __restrict__ Y,
    float* __restrict__ s_sum, float* __restrict__ s_ss) {
  __shared__ float as_[64][36];
  __shared__ float ws_[32][128];
  __shared__ float red[2][1024];

  const int tid = threadIdx.x;
  const int tx = tid & 31;
  const int ty = tid >> 5;
  const int row0 = blockIdx.x * 64;

  float4 acc[8];
#pragma unroll
  for (int r = 0; r < 8; ++r) acc[r] = make_float4(0.f, 0.f, 0.f, 0.f);

  const int ar = tid >> 2;
  const int aq = (tid & 3) * 8;
  const int wk = tid >> 3;
  const int wc = (tid & 7) * 16;

  for (int kk = 0; kk < kD; kk += 32) {
    float4 a0 = make_float4(0.f, 0.f, 0.f, 0.f);
    float4 a1 = make_float4(0.f, 0.f, 0.f, 0.f);
    int arow = row0 + ar;
    if (arow < kN) {
      const float* ap = A + (size_t)arow * kD + kk + aq;
      a0 = *reinterpret_cast<const float4*>(ap);
      a1 = *reinterpret_cast<const float4*>(ap + 4);
      if (scaleA != nullptr) {
        float4 sc0 = *reinterpret_cast<const float4*>(scaleA + kk + aq);
        float4 sc1 = *reinterpret_cast<const float4*>(scaleA + kk + aq + 4);
        float4 sh0 = *reinterpret_cast<const float4*>(shiftA + kk + aq);
        float4 sh1 = *reinterpret_cast<const float4*>(shiftA + kk + aq + 4);
        a0 = bnrelu4(a0, sc0, sh0);
        a1 = bnrelu4(a1, sc1, sh1);
      }
    }
    *reinterpret_cast<float4*>(&as_[ar][aq]) = a0;
    *reinterpret_cast<float4*>(&as_[ar][aq + 4]) = a1;

    const float* wp = W + (size_t)(kk + wk) * kD + wc;
#pragma unroll
    for (int j = 0; j < 4; ++j)
      *reinterpret_cast<float4*>(&ws_[wk][wc + 4 * j]) =
          *reinterpret_cast<const float4*>(wp + 4 * j);

    __syncthreads();

#pragma unroll
    for (int k4 = 0; k4 < 32; k4 += 4) {
      float4 w0 = *reinterpret_cast<float4*>(&ws_[k4 + 0][tx * 4]);
      float4 w1 = *reinterpret_cast<float4*>(&ws_[k4 + 1][tx * 4]);
      float4 w2 = *reinterpret_cast<float4*>(&ws_[k4 + 2][tx * 4]);
      float4 w3 = *reinterpret_cast<float4*>(&ws_[k4 + 3][tx * 4]);
#pragma unroll
      for (int r = 0; r < 8; ++r) {
        float4 a = *reinterpret_cast<float4*>(&as_[ty * 8 + r][k4]);
        fma4(acc[r], a.x, w0);
        fma4(acc[r], a.y, w1);
        fma4(acc[r], a.z, w2);
        fma4(acc[r], a.w, w3);
      }
    }
    __syncthreads();
  }

  float4 b4 = *reinterpret_cast<const float4*>(bias + tx * 4);
  float4 ssum = make_float4(0.f, 0.f, 0.f, 0.f);
  float4 sss = make_float4(0.f, 0.f, 0.f, 0.f);
#pragma unroll
  for (int r = 0; r < 8; ++r) {
    int row = row0 + ty * 8 + r;
    float4 v;
    v.x = acc[r].x + b4.x;
    v.y = acc[r].y + b4.y;
    v.z = acc[r].z + b4.z;
    v.w = acc[r].w + b4.w;
    if (row < kN) {
      *reinterpret_cast<float4*>(Y + (size_t)row * kD + tx * 4) = v;
      ssum.x += v.x; ssum.y += v.y; ssum.z += v.z; ssum.w += v.w;
      sss.x += v.x * v.x; sss.y += v.y * v.y;
      sss.z += v.z * v.z; sss.w += v.w * v.w;
    }
  }
  red[0][(tx * 4 + 0) * 8 + ty] = ssum.x;
  red[0][(tx * 4 + 1) * 8 + ty] = ssum.y;
  red[0][(tx * 4 + 2) * 8 + ty] = ssum.z;
  red[0][(tx * 4 + 3) * 8 + ty] = ssum.w;
  red[1][(tx * 4 + 0) * 8 + ty] = sss.x;
  red[1][(tx * 4 + 1) * 8 + ty] = sss.y;
  red[1][(tx * 4 + 2) * 8 + ty] = sss.z;
  red[1][(tx * 4 + 3) * 8 + ty] = sss.w;
  __syncthreads();
  if (tid < kD) {
    float s = 0.f;
#pragma unroll
    for (int j = 0; j < 8; ++j) s += red[0][tid * 8 + j];
    atomicAdd(&s_sum[tid], s);
  } else if (tid < 2 * kD) {
    int c = tid - kD;
    float s = 0.f;
#pragma unroll
    for (int j = 0; j < 8; ++j) s += red[1][c * 8 + j];
    atomicAdd(&s_ss[c], s);
  }
}

__global__ void k_bnparams(const float* __restrict__ s_sum, const float* __restrict__ s_ss,
                           const float* __restrict__ g, const float* __restrict__ be,
                           float* __restrict__ scale, float* __restrict__ shift) {
  int c = threadIdx.x;
  float mu = s_sum[c] * (1.f / kN);
  float var = s_ss[c] * (1.f / kN) - mu * mu;
  float sc = g[c] * rsqrtf(var + kEps);
  scale[c] = sc;
  shift[c] = be[c] - mu * sc;
}

// out[batch[n]] += relu(bn(h[n]))
__global__ void k_pool(const float* __restrict__ h, const int* __restrict__ batch,
                       const float* __restrict__ scale, const float* __restrict__ shift,
                       float* __restrict__ out) {
  int t = blockIdx.x * 256 + threadIdx.x;
  if (t >= kN * 32) return;
  int n = t >> 5, q = t & 31;
  float4 v = reinterpret_cast<const float4*>(h)[(size_t)n * 32 + q];
  float4 sc = reinterpret_cast<const float4*>(scale)[q];
  float4 sh = reinterpret_cast<const float4*>(shift)[q];
  v = bnrelu4(v, sc, sh);
  int g = batch[n];
  float* op = out + (size_t)g * kD + q * 4;
  atomicAdd(op + 0, v.x);
  atomicAdd(op + 1, v.y);
  atomicAdd(op + 2, v.z);
  atomicAdd(op + 3, v.w);
}

extern "C" void kernel_launch(void* const* d_in, const int* in_sizes, int n_in,
                              void* d_out, int out_size, void* d_ws, size_t ws_size,
                              hipStream_t stream) {
  const float* x   = (const float*)d_in[0];
  const int*   ei  = (const int*)d_in[1];
  const int*   bat = (const int*)d_in[2];
  const float* W1  = (const float*)d_in[3];
  const float* b1  = (const float*)d_in[4];
  const float* g1  = (const float*)d_in[5];
  const float* be1 = (const float*)d_in[6];
  const float* W2  = (const float*)d_in[7];
  const float* b2  = (const float*)d_in[8];
  const float* g2  = (const float*)d_in[9];
  const float* be2 = (const float*)d_in[10];
  float* out = (float*)d_out;

  // workspace layout
  char* p = (char*)d_ws;
  float* wsf = (float*)p;                       p += 16384;           // BN stats: 6 x 512 floats
  float* bufA = (float*)p;                      p += (size_t)kN * kD * 4;
  float* bufB = (float*)p;                      p += (size_t)kN * kD * 4;
  int* rowptr = (int*)p;                        p += (kN + 2) * 4;
  int* cursor = (int*)p;                        p += kN * 4;
  int* srcs = (int*)p;                          p += (size_t)kE * 4;

  (void)hipMemsetAsync(wsf, 0, 6 * 512 * sizeof(float), stream);
  (void)hipMemsetAsync(d_out, 0, (size_t)kB * kD * sizeof(float), stream);
  (void)hipMemsetAsync(rowptr, 0, (kN + 1) * sizeof(int), stream);

  // CSR build (layer-invariant)
  k_hist<<<(kE + 255) / 256, 256, 0, stream>>>(ei, rowptr);
  k_scan<<<1, 1024, 0, stream>>>(rowptr, kN + 1);
  (void)hipMemcpyAsync(cursor, rowptr, kN * sizeof(int), hipMemcpyDeviceToDevice, stream);
  k_fill<<<(kE + 255) / 256, 256, 0, stream>>>(ei, cursor, srcs);

  const float* curH = x;
  const float* curScale = nullptr;
  const float* curShift = nullptr;
  float* aggBuf = bufA;
  float* other = bufB;

  for (int l = 0; l < kL; ++l) {
    if (curScale == nullptr)
      k_gather<false><<<kN / 4, 256, 0, stream>>>(curH, rowptr, srcs, nullptr, nullptr, aggBuf);
    else
      k_gather<true><<<kN / 4, 256, 0, stream>>>(curH, rowptr, srcs, curScale, curShift, aggBuf);

    float* st1 = wsf + (size_t)(l * 2 + 0) * 512;
    k_gemm<<<(kN + 63) / 64, 256, 0, stream>>>(aggBuf, W1 + (size_t)l * kD * kD,
                                               b1 + l * kD, nullptr, nullptr, other,
                                               st1, st1 + 128);
    k_bnparams<<<1, kD, 0, stream>>>(st1, st1 + 128, g1 + l * kD, be1 + l * kD,
                                     st1 + 256, st1 + 384);

    float* st2 = wsf + (size_t)(l * 2 + 1) * 512;
    k_gemm<<<(kN + 63) / 64, 256, 0, stream>>>(other, W2 + (size_t)l * kD * kD,
                                               b2 + l * kD, st1 + 256, st1 + 384, aggBuf,
                                               st2, st2 + 128);
    k_bnparams<<<1, kD, 0, stream>>>(st2, st2 + 128, g2 + l * kD, be2 + l * kD,
                                     st2 + 256, st2 + 384);

    curH = aggBuf;
    curScale = st2 + 256;
    curShift = st2 + 384;
    float* tmp = aggBuf;
    aggBuf = other;
    other = tmp;
  }

  k_pool<<<(kN * 32) / 256, 256, 0, stream>>>(curH, bat, curScale, curShift, out);
}

// Round 4
// 565.567 us; speedup vs baseline: 7.8541x; 1.2909x over previous
//
#include <hip/hip_runtime.h>

constexpr int kN = 50000;
constexpr int kE = 800000;
constexpr int kD = 128;
constexpr int kB = 256;
constexpr int kL = 3;
constexpr float kEps = 1e-5f;

__device__ __forceinline__ float4 bnrelu4(float4 v, float4 sc, float4 sh) {
  float4 r;
  r.x = fmaxf(fmaf(v.x, sc.x, sh.x), 0.f);
  r.y = fmaxf(fmaf(v.y, sc.y, sh.y), 0.f);
  r.z = fmaxf(fmaf(v.z, sc.z, sh.z), 0.f);
  r.w = fmaxf(fmaf(v.w, sc.w, sh.w), 0.f);
  return r;
}

__device__ __forceinline__ float2 bnrelu2(float2 v, float2 sc, float2 sh) {
  float2 r;
  r.x = fmaxf(fmaf(v.x, sc.x, sh.x), 0.f);
  r.y = fmaxf(fmaf(v.y, sc.y, sh.y), 0.f);
  return r;
}

__device__ __forceinline__ void fma4(float4& acc, float s, const float4& wv) {
  acc.x = fmaf(s, wv.x, acc.x);
  acc.y = fmaf(s, wv.y, acc.y);
  acc.z = fmaf(s, wv.z, acc.z);
  acc.w = fmaf(s, wv.w, acc.w);
}

__device__ __forceinline__ void acc4(float4& a, const float4& v) {
  a.x += v.x; a.y += v.y; a.z += v.z; a.w += v.w;
}
__device__ __forceinline__ void accsq4(float4& a, const float4& v) {
  a.x = fmaf(v.x, v.x, a.x); a.y = fmaf(v.y, v.y, a.y);
  a.z = fmaf(v.z, v.z, a.z); a.w = fmaf(v.w, v.w, a.w);
}

// ---------------- CSR build ----------------

__global__ void k_hist(const int* __restrict__ ei, int* __restrict__ rowptr) {
  int e = blockIdx.x * 256 + threadIdx.x;
  if (e >= kE) return;
  atomicAdd(&rowptr[1 + ei[kE + e]], 1);
}

__global__ __launch_bounds__(1024) void k_scan(int* __restrict__ data, int n) {
  __shared__ int wsum[16];
  __shared__ int carry;
  const int tid = threadIdx.x;
  const int lane = tid & 63;
  const int wid = tid >> 6;
  if (tid == 0) carry = 0;
  __syncthreads();
  for (int base = 0; base < n; base += 1024) {
    int i = base + tid;
    int v = (i < n) ? data[i] : 0;
#pragma unroll
    for (int off = 1; off < 64; off <<= 1) {
      int t = __shfl_up(v, off);
      if (lane >= off) v += t;
    }
    if (lane == 63) wsum[wid] = v;
    __syncthreads();
    if (tid == 0) {
      int s = 0;
#pragma unroll
      for (int k = 0; k < 16; ++k) { s += wsum[k]; wsum[k] = s; }
    }
    __syncthreads();
    int out = v + (wid > 0 ? wsum[wid - 1] : 0) + carry;
    if (i < n) data[i] = out;
    __syncthreads();
    if (tid == 0) carry += wsum[15];
    __syncthreads();
  }
}

__global__ void k_fill(const int* __restrict__ ei, int* __restrict__ cursor,
                       int* __restrict__ srcs) {
  int e = blockIdx.x * 256 + threadIdx.x;
  if (e >= kE) return;
  int d = ei[kE + e];
  int p = atomicAdd(&cursor[d], 1);
  srcs[p] = ei[e];
}

// graph boundaries from sorted batch
__global__ void k_bounds(const int* __restrict__ batch, int* __restrict__ gstart) {
  int n = blockIdx.x * 256 + threadIdx.x;
  if (n > kN) return;
  int b = (n < kN) ? batch[n] : kB;
  int bp = (n > 0) ? batch[n - 1] : -1;
  for (int g = bp + 1; g <= b; ++g) gstart[g] = n;
}

// ---------------- aggregation ----------------
template <bool BN>
__global__ __launch_bounds__(256) void k_gather(
    const float* __restrict__ h, const int* __restrict__ rowptr,
    const int* __restrict__ srcs, const float* __restrict__ scale,
    const float* __restrict__ shift, float* __restrict__ agg) {
  const int node = blockIdx.x * 4 + (threadIdx.x >> 6);
  const int lane = threadIdx.x & 63;
  const float2* h2 = reinterpret_cast<const float2*>(h);
  float2 sc, sh;
  if (BN) {
    sc = reinterpret_cast<const float2*>(scale)[lane];
    sh = reinterpret_cast<const float2*>(shift)[lane];
  }
  float2 acc = h2[(size_t)node * 64 + lane];
  if (BN) acc = bnrelu2(acc, sc, sh);
  const int beg = rowptr[node];
  const int end = rowptr[node + 1];
  for (int j0 = beg; j0 < end; j0 += 64) {
    int mysrc = (j0 + lane < end) ? srcs[j0 + lane] : 0;
    int cnt = min(64, end - j0);
    for (int t = 0; t < cnt; ++t) {
      int s = __shfl(mysrc, t);
      float2 v = h2[(size_t)s * 64 + lane];
      if (BN) v = bnrelu2(v, sc, sh);
      acc.x += v.x;
      acc.y += v.y;
    }
  }
  reinterpret_cast<float2*>(agg)[(size_t)node * 64 + lane] = acc;
}

// ---------------- fused GEMM + BN-stats ----------------
// Y = f(A) @ W + bias; 128x128 tile, 256 threads, 8x8 per-thread micro-tile.
// A staged k-major (transposed) in LDS for vector fragment reads.
__global__ __launch_bounds__(256) void k_gemm(
    const float* __restrict__ A, const float* __restrict__ W,
    const float* __restrict__ bias, const float* __restrict__ scaleA,
    const float* __restrict__ shiftA, float* __restrict__ Y,
    float* __restrict__ s_sum, float* __restrict__ s_ss) {
  __shared__ float as_[32][132];   // [k][row], stride 132 keeps 16B align
  __shared__ float ws_[32][132];   // [k][col]

  const int tid = threadIdx.x;
  const int tx = tid & 15;    // cols tx*8 .. tx*8+7
  const int ty = tid >> 4;    // rows ty*8 .. ty*8+7
  const int row0 = blockIdx.x * 128;

  float4 acc[8][2];
#pragma unroll
  for (int r = 0; r < 8; ++r) {
    acc[r][0] = make_float4(0.f, 0.f, 0.f, 0.f);
    acc[r][1] = make_float4(0.f, 0.f, 0.f, 0.f);
  }

  const int srow = tid >> 1;         // 0..127
  const int skq = (tid & 1) * 16;    // 0 / 16
  const int wkk = tid >> 3;          // 0..31
  const int wcc = (tid & 7) * 16;    // col chunk

  for (int kk = 0; kk < kD; kk += 32) {
    // stage A^T: as_[k][row]
    int arow = row0 + srow;
    float4 av[4];
    if (arow < kN) {
      const float* ap = A + (size_t)arow * kD + kk + skq;
#pragma unroll
      for (int j = 0; j < 4; ++j) av[j] = *reinterpret_cast<const float4*>(ap + 4 * j);
      if (scaleA != nullptr) {
#pragma unroll
        for (int j = 0; j < 4; ++j) {
          float4 sc = *reinterpret_cast<const float4*>(scaleA + kk + skq + 4 * j);
          float4 sh = *reinterpret_cast<const float4*>(shiftA + kk + skq + 4 * j);
          av[j] = bnrelu4(av[j], sc, sh);
        }
      }
    } else {
#pragma unroll
      for (int j = 0; j < 4; ++j) av[j] = make_float4(0.f, 0.f, 0.f, 0.f);
    }
#pragma unroll
    for (int j = 0; j < 4; ++j) {
      as_[skq + 4 * j + 0][srow] = av[j].x;
      as_[skq + 4 * j + 1][srow] = av[j].y;
      as_[skq + 4 * j + 2][srow] = av[j].z;
      as_[skq + 4 * j + 3][srow] = av[j].w;
    }

    // stage W: ws_[k][col]
    const float* wp = W + (size_t)(kk + wkk) * kD + wcc;
#pragma unroll
    for (int j = 0; j < 4; ++j)
      *reinterpret_cast<float4*>(&ws_[wkk][wcc + 4 * j]) =
          *reinterpret_cast<const float4*>(wp + 4 * j);

    __syncthreads();

#pragma unroll 8
    for (int k = 0; k < 32; ++k) {
      float4 a0 = *reinterpret_cast<float4*>(&as_[k][ty * 8]);
      float4 a1 = *reinterpret_cast<float4*>(&as_[k][ty * 8 + 4]);
      float4 w0 = *reinterpret_cast<float4*>(&ws_[k][tx * 8]);
      float4 w1 = *reinterpret_cast<float4*>(&ws_[k][tx * 8 + 4]);
      fma4(acc[0][0], a0.x, w0); fma4(acc[0][1], a0.x, w1);
      fma4(acc[1][0], a0.y, w0); fma4(acc[1][1], a0.y, w1);
      fma4(acc[2][0], a0.z, w0); fma4(acc[2][1], a0.z, w1);
      fma4(acc[3][0], a0.w, w0); fma4(acc[3][1], a0.w, w1);
      fma4(acc[4][0], a1.x, w0); fma4(acc[4][1], a1.x, w1);
      fma4(acc[5][0], a1.y, w0); fma4(acc[5][1], a1.y, w1);
      fma4(acc[6][0], a1.z, w0); fma4(acc[6][1], a1.z, w1);
      fma4(acc[7][0], a1.w, w0); fma4(acc[7][1], a1.w, w1);
    }
    __syncthreads();
  }

  // epilogue: bias, store, column stats
  float4 b0 = reinterpret_cast<const float4*>(bias)[tx * 2];
  float4 b1 = reinterpret_cast<const float4*>(bias)[tx * 2 + 1];
  float4 ss0 = make_float4(0.f, 0.f, 0.f, 0.f), ss1 = ss0, qq0 = ss0, qq1 = ss0;
#pragma unroll
  for (int r = 0; r < 8; ++r) {
    int row = row0 + ty * 8 + r;
    float4 v0 = acc[r][0], v1 = acc[r][1];
    acc4(v0, b0);
    acc4(v1, b1);
    if (row < kN) {
      float4* yp = reinterpret_cast<float4*>(Y + (size_t)row * kD + tx * 8);
      yp[0] = v0;
      yp[1] = v1;
      acc4(ss0, v0); acc4(ss1, v1);
      accsq4(qq0, v0); accsq4(qq1, v1);
    }
  }
  // reuse as_ as red[2][16][128] (last k-step ended with syncthreads)
  float* red = &as_[0][0];
  *reinterpret_cast<float4*>(&red[ty * 128 + tx * 8]) = ss0;
  *reinterpret_cast<float4*>(&red[ty * 128 + tx * 8 + 4]) = ss1;
  *reinterpret_cast<float4*>(&red[2048 + ty * 128 + tx * 8]) = qq0;
  *reinterpret_cast<float4*>(&red[2048 + ty * 128 + tx * 8 + 4]) = qq1;
  __syncthreads();
  if (tid < kD) {
    float s = 0.f;
#pragma unroll
    for (int j = 0; j < 16; ++j) s += red[j * 128 + tid];
    atomicAdd(&s_sum[tid], s);
  } else {
    int c = tid - kD;
    float s = 0.f;
#pragma unroll
    for (int j = 0; j < 16; ++j) s += red[2048 + j * 128 + c];
    atomicAdd(&s_ss[c], s);
  }
}

__global__ void k_bnparams(const float* __restrict__ s_sum, const float* __restrict__ s_ss,
                           const float* __restrict__ g, const float* __restrict__ be,
                           float* __restrict__ scale, float* __restrict__ shift) {
  int c = threadIdx.x;
  float mu = s_sum[c] * (1.f / kN);
  float var = s_ss[c] * (1.f / kN) - mu * mu;
  float sc = g[c] * rsqrtf(var + kEps);
  scale[c] = sc;
  shift[c] = be[c] - mu * sc;
}

// segmented pool: one block per graph, batch is sorted
__global__ __launch_bounds__(256) void k_pool(
    const float* __restrict__ h, const int* __restrict__ gstart,
    const float* __restrict__ scale, const float* __restrict__ shift,
    float* __restrict__ out) {
  const int g = blockIdx.x;
  const int q = threadIdx.x & 31;   // float4 column chunk
  const int r = threadIdx.x >> 5;   // 8-way row split
  const int s = gstart[g], e = gstart[g + 1];
  float4 sc = reinterpret_cast<const float4*>(scale)[q];
  float4 sh = reinterpret_cast<const float4*>(shift)[q];
  float4 acc = make_float4(0.f, 0.f, 0.f, 0.f);
  for (int n = s + r; n < e; n += 8) {
    float4 v = reinterpret_cast<const float4*>(h)[(size_t)n * 32 + q];
    acc4(acc, bnrelu4(v, sc, sh));
  }
  __shared__ float4 red[8][32];
  red[r][q] = acc;
  __syncthreads();
  if (r == 0) {
    float4 t = acc;
#pragma unroll
    for (int j = 1; j < 8; ++j) acc4(t, red[j][q]);
    reinterpret_cast<float4*>(out)[(size_t)g * 32 + q] = t;
  }
}

extern "C" void kernel_launch(void* const* d_in, const int* in_sizes, int n_in,
                              void* d_out, int out_size, void* d_ws, size_t ws_size,
                              hipStream_t stream) {
  const float* x   = (const float*)d_in[0];
  const int*   ei  = (const int*)d_in[1];
  const int*   bat = (const int*)d_in[2];
  const float* W1  = (const float*)d_in[3];
  const float* b1  = (const float*)d_in[4];
  const float* g1  = (const float*)d_in[5];
  const float* be1 = (const float*)d_in[6];
  const float* W2  = (const float*)d_in[7];
  const float* b2  = (const float*)d_in[8];
  const float* g2  = (const float*)d_in[9];
  const float* be2 = (const float*)d_in[10];
  float* out = (float*)d_out;

  char* p = (char*)d_ws;
  float* wsf = (float*)p;                       p += 16384;
  float* bufA = (float*)p;                      p += (size_t)kN * kD * 4;
  float* bufB = (float*)p;                      p += (size_t)kN * kD * 4;
  int* rowptr = (int*)p;                        p += (kN + 2) * 4;
  int* cursor = (int*)p;                        p += kN * 4;
  int* gstart = (int*)p;                        p += (kB + 2) * 4;
  int* srcs = (int*)p;                          p += (size_t)kE * 4;

  (void)hipMemsetAsync(wsf, 0, 6 * 512 * sizeof(float), stream);
  (void)hipMemsetAsync(rowptr, 0, (kN + 1) * sizeof(int), stream);

  // CSR + graph bounds (layer-invariant)
  k_hist<<<(kE + 255) / 256, 256, 0, stream>>>(ei, rowptr);
  k_bounds<<<(kN + 256) / 256, 256, 0, stream>>>(bat, gstart);
  k_scan<<<1, 1024, 0, stream>>>(rowptr, kN + 1);
  (void)hipMemcpyAsync(cursor, rowptr, kN * sizeof(int), hipMemcpyDeviceToDevice, stream);
  k_fill<<<(kE + 255) / 256, 256, 0, stream>>>(ei, cursor, srcs);

  const float* curH = x;
  const float* curScale = nullptr;
  const float* curShift = nullptr;
  float* aggBuf = bufA;
  float* other = bufB;

  for (int l = 0; l < kL; ++l) {
    if (curScale == nullptr)
      k_gather<false><<<kN / 4, 256, 0, stream>>>(curH, rowptr, srcs, nullptr, nullptr, aggBuf);
    else
      k_gather<true><<<kN / 4, 256, 0, stream>>>(curH, rowptr, srcs, curScale, curShift, aggBuf);

    float* st1 = wsf + (size_t)(l * 2 + 0) * 512;
    k_gemm<<<(kN + 127) / 128, 256, 0, stream>>>(aggBuf, W1 + (size_t)l * kD * kD,
                                                 b1 + l * kD, nullptr, nullptr, other,
                                                 st1, st1 + 128);
    k_bnparams<<<1, kD, 0, stream>>>(st1, st1 + 128, g1 + l * kD, be1 + l * kD,
                                     st1 + 256, st1 + 384);

    float* st2 = wsf + (size_t)(l * 2 + 1) * 512;
    k_gemm<<<(kN + 127) / 128, 256, 0, stream>>>(other, W2 + (size_t)l * kD * kD,
                                                 b2 + l * kD, st1 + 256, st1 + 384, aggBuf,
                                                 st2, st2 + 128);
    k_bnparams<<<1, kD, 0, stream>>>(st2, st2 + 128, g2 + l * kD, be2 + l * kD,
                                     st2 + 256, st2 + 384);

    curH = aggBuf;
    curScale = st2 + 256;
    curShift = st2 + 384;
    float* tmp = aggBuf;
    aggBuf = other;
    other = tmp;
  }

  k_pool<<<kB, 256, 0, stream>>>(curH, gstart, curScale, curShift, out);
}

// Round 5
// 489.428 us; speedup vs baseline: 9.0759x; 1.1556x over previous
//
#include <hip/hip_runtime.h>

constexpr int kN = 50000;
constexpr int kE = 800000;
constexpr int kD = 128;
constexpr int kB = 256;
constexpr int kL = 3;
constexpr float kEps = 1e-5f;

typedef __attribute__((ext_vector_type(8))) short short8;
typedef __attribute__((ext_vector_type(4))) float f32x4;

__device__ __forceinline__ float4 bnrelu4(float4 v, float4 sc, float4 sh) {
  float4 r;
  r.x = fmaxf(fmaf(v.x, sc.x, sh.x), 0.f);
  r.y = fmaxf(fmaf(v.y, sc.y, sh.y), 0.f);
  r.z = fmaxf(fmaf(v.z, sc.z, sh.z), 0.f);
  r.w = fmaxf(fmaf(v.w, sc.w, sh.w), 0.f);
  return r;
}

__device__ __forceinline__ float2 bnrelu2(float2 v, float2 sc, float2 sh) {
  float2 r;
  r.x = fmaxf(fmaf(v.x, sc.x, sh.x), 0.f);
  r.y = fmaxf(fmaf(v.y, sc.y, sh.y), 0.f);
  return r;
}

__device__ __forceinline__ void acc4(float4& a, const float4& v) {
  a.x += v.x; a.y += v.y; a.z += v.z; a.w += v.w;
}
__device__ __forceinline__ void accsq4(float4& a, const float4& v) {
  a.x = fmaf(v.x, v.x, a.x); a.y = fmaf(v.y, v.y, a.y);
  a.z = fmaf(v.z, v.z, a.z); a.w = fmaf(v.w, v.w, a.w);
}

// fp32 -> bf16 round-to-nearest-even
__device__ __forceinline__ unsigned short f2bf(float x) {
  unsigned int u = __float_as_uint(x);
  u = u + 0x7FFFu + ((u >> 16) & 1u);
  return (unsigned short)(u >> 16);
}

// ---------------- CSR build ----------------

__global__ void k_hist(const int* __restrict__ ei, int* __restrict__ rowptr) {
  int e = blockIdx.x * 256 + threadIdx.x;
  if (e >= kE) return;
  atomicAdd(&rowptr[1 + ei[kE + e]], 1);
}

__global__ __launch_bounds__(1024) void k_scan(int* __restrict__ data, int n) {
  __shared__ int wsum[16];
  __shared__ int carry;
  const int tid = threadIdx.x;
  const int lane = tid & 63;
  const int wid = tid >> 6;
  if (tid == 0) carry = 0;
  __syncthreads();
  for (int base = 0; base < n; base += 1024) {
    int i = base + tid;
    int v = (i < n) ? data[i] : 0;
#pragma unroll
    for (int off = 1; off < 64; off <<= 1) {
      int t = __shfl_up(v, off);
      if (lane >= off) v += t;
    }
    if (lane == 63) wsum[wid] = v;
    __syncthreads();
    if (tid == 0) {
      int s = 0;
#pragma unroll
      for (int k = 0; k < 16; ++k) { s += wsum[k]; wsum[k] = s; }
    }
    __syncthreads();
    int out = v + (wid > 0 ? wsum[wid - 1] : 0) + carry;
    if (i < n) data[i] = out;
    __syncthreads();
    if (tid == 0) carry += wsum[15];
    __syncthreads();
  }
}

__global__ void k_fill(const int* __restrict__ ei, int* __restrict__ cursor,
                       int* __restrict__ srcs) {
  int e = blockIdx.x * 256 + threadIdx.x;
  if (e >= kE) return;
  int d = ei[kE + e];
  int p = atomicAdd(&cursor[d], 1);
  srcs[p] = ei[e];
}

__global__ void k_bounds(const int* __restrict__ batch, int* __restrict__ gstart) {
  int n = blockIdx.x * 256 + threadIdx.x;
  if (n > kN) return;
  int b = (n < kN) ? batch[n] : kB;
  int bp = (n > 0) ? batch[n - 1] : -1;
  for (int g = bp + 1; g <= b; ++g) gstart[g] = n;
}

// ---------------- W fp32 -> bf16 fragment-order ----------------
// B-frag of mfma_f32_16x16x32_bf16: lane holds B[(lane>>4)*8+j][lane&15].
// layout: Wf[mat][ ((kb*8+cb)*64 + lane)*8 + j ], kb=k/32, cb=col/16
__global__ void k_wconv(const float* __restrict__ W, unsigned short* __restrict__ Wf,
                        int nmat) {
  int idx = blockIdx.x * 256 + threadIdx.x;
  if (idx >= nmat * kD * kD) return;
  int m = idx & (kD * kD - 1);
  int w = idx >> 14;
  int k = m >> 7, col = m & 127;
  int kb = k >> 5, cb = col >> 4;
  int lane = (col & 15) + 16 * ((k & 31) >> 3);
  int j = k & 7;
  Wf[(size_t)w * kD * kD + ((size_t)(kb * 8 + cb) * 64 + lane) * 8 + j] = f2bf(W[idx]);
}

// ---------------- aggregation ----------------
template <bool BN>
__global__ __launch_bounds__(256) void k_gather(
    const float* __restrict__ h, const int* __restrict__ rowptr,
    const int* __restrict__ srcs, const float* __restrict__ scale,
    const float* __restrict__ shift, float* __restrict__ agg) {
  const int node = blockIdx.x * 4 + (threadIdx.x >> 6);
  const int lane = threadIdx.x & 63;
  const float2* h2 = reinterpret_cast<const float2*>(h);
  float2 sc, sh;
  if (BN) {
    sc = reinterpret_cast<const float2*>(scale)[lane];
    sh = reinterpret_cast<const float2*>(shift)[lane];
  }
  float2 acc = h2[(size_t)node * 64 + lane];
  if (BN) acc = bnrelu2(acc, sc, sh);
  const int beg = rowptr[node];
  const int end = rowptr[node + 1];
  for (int j0 = beg; j0 < end; j0 += 64) {
    int mysrc = (j0 + lane < end) ? srcs[j0 + lane] : 0;
    int cnt = min(64, end - j0);
    for (int t = 0; t < cnt; ++t) {
      int s = __shfl(mysrc, t);
      float2 v = h2[(size_t)s * 64 + lane];
      if (BN) v = bnrelu2(v, sc, sh);
      acc.x += v.x;
      acc.y += v.y;
    }
  }
  reinterpret_cast<float2*>(agg)[(size_t)node * 64 + lane] = acc;
}

// ---------------- MFMA GEMM + BN-stats ----------------
// Y = f(A) @ W + bias. 128-row tile x full 128 cols, full K in one stage.
// A staged fp32->bf16 into LDS in MFMA-fragment order; W read as bf16 frags
// from global (L2-hot). acc in fp32 via mfma_f32_16x16x32_bf16.
__global__ __launch_bounds__(256) void k_gemm(
    const float* __restrict__ A, const unsigned short* __restrict__ Wf,
    const float* __restrict__ bias, const float* __restrict__ scaleA,
    const float* __restrict__ shiftA, float* __restrict__ Y,
    float* __restrict__ s_sum, float* __restrict__ s_ss) {
  union SMem {
    unsigned short af[32 * 64 * 8];  // 32 A-frags x 64 lanes x 8 bf16 = 32KB
    float epi[64 * 132];             // epilogue staging (33.8KB)
  };
  __shared__ SMem sm;

  const int tid = threadIdx.x;
  const int w = tid >> 6;     // wave 0..3, owns cols w*32..w*32+31
  const int lane = tid & 63;
  const int row0 = blockIdx.x * 128;

  // ---- load B fragments (whole W for this wave's 32 cols) ----
  short8 bfr[4][2];
#pragma unroll
  for (int kb = 0; kb < 4; ++kb)
#pragma unroll
    for (int c = 0; c < 2; ++c)
      bfr[kb][c] = *reinterpret_cast<const short8*>(
          Wf + ((size_t)(kb * 8 + (2 * w + c)) * 64 + lane) * 8);

  // ---- stage A tile (128 rows x 128 k) as bf16 fragments ----
  // thread t: row = (t>>4) + 16*i, k0 = (t&15)*8 ; 8 iterations
  {
    const int rlow = tid >> 4;          // 0..15
    const int k0 = (tid & 15) * 8;      // 0..120
    const int kb = k0 >> 5;
    const int lif = rlow + 16 * ((k0 & 31) >> 3);  // lane-in-frag
    float4 sc0, sc1, sh0, sh1;
    if (scaleA != nullptr) {
      sc0 = *reinterpret_cast<const float4*>(scaleA + k0);
      sc1 = *reinterpret_cast<const float4*>(scaleA + k0 + 4);
      sh0 = *reinterpret_cast<const float4*>(shiftA + k0);
      sh1 = *reinterpret_cast<const float4*>(shiftA + k0 + 4);
    }
#pragma unroll
    for (int i = 0; i < 8; ++i) {
      int grow = row0 + rlow + 16 * i;
      float4 v0 = make_float4(0.f, 0.f, 0.f, 0.f);
      float4 v1 = make_float4(0.f, 0.f, 0.f, 0.f);
      if (grow < kN) {
        const float* ap = A + (size_t)grow * kD + k0;
        v0 = *reinterpret_cast<const float4*>(ap);
        v1 = *reinterpret_cast<const float4*>(ap + 4);
        if (scaleA != nullptr) {
          v0 = bnrelu4(v0, sc0, sh0);
          v1 = bnrelu4(v1, sc1, sh1);
        }
      }
      short8 u;
      u[0] = (short)f2bf(v0.x); u[1] = (short)f2bf(v0.y);
      u[2] = (short)f2bf(v0.z); u[3] = (short)f2bf(v0.w);
      u[4] = (short)f2bf(v1.x); u[5] = (short)f2bf(v1.y);
      u[6] = (short)f2bf(v1.z); u[7] = (short)f2bf(v1.w);
      int frag = i * 4 + kb;  // rb = i
      *reinterpret_cast<short8*>(&sm.af[((size_t)frag * 64 + lif) * 8]) = u;
    }
  }
  __syncthreads();

  // ---- MFMA main: 64 MFMAs per wave ----
  f32x4 acc[8][2];
#pragma unroll
  for (int rb = 0; rb < 8; ++rb) {
    acc[rb][0] = (f32x4){0.f, 0.f, 0.f, 0.f};
    acc[rb][1] = (f32x4){0.f, 0.f, 0.f, 0.f};
  }
#pragma unroll
  for (int kb = 0; kb < 4; ++kb) {
    short8 afr[8];
#pragma unroll
    for (int rb = 0; rb < 8; ++rb)
      afr[rb] = *reinterpret_cast<const short8*>(
          &sm.af[((size_t)(rb * 4 + kb) * 64 + lane) * 8]);
#pragma unroll
    for (int rb = 0; rb < 8; ++rb) {
      acc[rb][0] = __builtin_amdgcn_mfma_f32_16x16x32_bf16(afr[rb], bfr[kb][0],
                                                           acc[rb][0], 0, 0, 0);
      acc[rb][1] = __builtin_amdgcn_mfma_f32_16x16x32_bf16(afr[rb], bfr[kb][1],
                                                           acc[rb][1], 0, 0, 0);
    }
  }

  // ---- epilogue: two 64-row passes through LDS, coalesced store + stats ----
  const int col4 = tid & 31;   // float4 column chunk
  const int rowg = tid >> 5;   // 0..7, owns 8 consecutive local rows
  float4 b4 = reinterpret_cast<const float4*>(bias)[col4];
  float4 ss = make_float4(0.f, 0.f, 0.f, 0.f);
  float4 qq = make_float4(0.f, 0.f, 0.f, 0.f);

#pragma unroll
  for (int p = 0; p < 2; ++p) {
    __syncthreads();
    // dump C-frags: row=(lane>>4)*4+j, col=lane&15 within 16x16
#pragma unroll
    for (int rb4 = 0; rb4 < 4; ++rb4) {
      int rb = p * 4 + rb4;
#pragma unroll
      for (int c = 0; c < 2; ++c) {
#pragma unroll
        for (int j = 0; j < 4; ++j) {
          sm.epi[(size_t)(rb4 * 16 + (lane >> 4) * 4 + j) * 132 +
                 w * 32 + c * 16 + (lane & 15)] = acc[rb][c][j];
        }
      }
    }
    __syncthreads();
#pragma unroll
    for (int i = 0; i < 8; ++i) {
      int lrow = rowg * 8 + i;
      int grow = row0 + p * 64 + lrow;
      float4 v = *reinterpret_cast<float4*>(&sm.epi[(size_t)lrow * 132 + col4 * 4]);
      acc4(v, b4);
      if (grow < kN) {
        *reinterpret_cast<float4*>(Y + (size_t)grow * kD + col4 * 4) = v;
        acc4(ss, v);
        accsq4(qq, v);
      }
    }
  }

  // ---- stats reduce ----
  __syncthreads();
  *reinterpret_cast<float4*>(&sm.epi[(size_t)rowg * 128 + col4 * 4]) = ss;
  *reinterpret_cast<float4*>(&sm.epi[1024 + (size_t)rowg * 128 + col4 * 4]) = qq;
  __syncthreads();
  if (tid < kD) {
    float s = 0.f;
#pragma unroll
    for (int j = 0; j < 8; ++j) s += sm.epi[j * 128 + tid];
    atomicAdd(&s_sum[tid], s);
  } else {
    int c = tid - kD;
    float s = 0.f;
#pragma unroll
    for (int j = 0; j < 8; ++j) s += sm.epi[1024 + j * 128 + c];
    atomicAdd(&s_ss[c], s);
  }
}

__global__ void k_bnparams(const float* __restrict__ s_sum, const float* __restrict__ s_ss,
                           const float* __restrict__ g, const float* __restrict__ be,
                           float* __restrict__ scale, float* __restrict__ shift) {
  int c = threadIdx.x;
  float mu = s_sum[c] * (1.f / kN);
  float var = s_ss[c] * (1.f / kN) - mu * mu;
  float sc = g[c] * rsqrtf(var + kEps);
  scale[c] = sc;
  shift[c] = be[c] - mu * sc;
}

// segmented pool: one block per graph, batch is sorted
__global__ __launch_bounds__(256) void k_pool(
    const float* __restrict__ h, const int* __restrict__ gstart,
    const float* __restrict__ scale, const float* __restrict__ shift,
    float* __restrict__ out) {
  const int g = blockIdx.x;
  const int q = threadIdx.x & 31;
  const int r = threadIdx.x >> 5;
  const int s = gstart[g], e = gstart[g + 1];
  float4 sc = reinterpret_cast<const float4*>(scale)[q];
  float4 sh = reinterpret_cast<const float4*>(shift)[q];
  float4 acc = make_float4(0.f, 0.f, 0.f, 0.f);
  for (int n = s + r; n < e; n += 8) {
    float4 v = reinterpret_cast<const float4*>(h)[(size_t)n * 32 + q];
    acc4(acc, bnrelu4(v, sc, sh));
  }
  __shared__ float4 red[8][32];
  red[r][q] = acc;
  __syncthreads();
  if (r == 0) {
    float4 t = acc;
#pragma unroll
    for (int j = 1; j < 8; ++j) acc4(t, red[j][q]);
    reinterpret_cast<float4*>(out)[(size_t)g * 32 + q] = t;
  }
}

extern "C" void kernel_launch(void* const* d_in, const int* in_sizes, int n_in,
                              void* d_out, int out_size, void* d_ws, size_t ws_size,
                              hipStream_t stream) {
  const float* x   = (const float*)d_in[0];
  const int*   ei  = (const int*)d_in[1];
  const int*   bat = (const int*)d_in[2];
  const float* W1  = (const float*)d_in[3];
  const float* b1  = (const float*)d_in[4];
  const float* g1  = (const float*)d_in[5];
  const float* be1 = (const float*)d_in[6];
  const float* W2  = (const float*)d_in[7];
  const float* b2  = (const float*)d_in[8];
  const float* g2  = (const float*)d_in[9];
  const float* be2 = (const float*)d_in[10];
  float* out = (float*)d_out;

  char* p = (char*)d_ws;
  float* wsf = (float*)p;                       p += 16384;
  float* bufA = (float*)p;                      p += (size_t)kN * kD * 4;
  float* bufB = (float*)p;                      p += (size_t)kN * kD * 4;
  int* rowptr = (int*)p;                        p += (kN + 2) * 4;
  int* cursor = (int*)p;                        p += kN * 4;
  int* gstart = (int*)p;                        p += (kB + 2) * 4;
  unsigned short* Wf1 = (unsigned short*)p;     p += (size_t)kL * kD * kD * 2;
  unsigned short* Wf2 = (unsigned short*)p;     p += (size_t)kL * kD * kD * 2;
  int* srcs = (int*)p;                          p += (size_t)kE * 4;

  (void)hipMemsetAsync(wsf, 0, 6 * 512 * sizeof(float), stream);
  (void)hipMemsetAsync(rowptr, 0, (kN + 1) * sizeof(int), stream);

  // layer-invariant preprocessing
  k_hist<<<(kE + 255) / 256, 256, 0, stream>>>(ei, rowptr);
  k_bounds<<<(kN + 256) / 256, 256, 0, stream>>>(bat, gstart);
  k_wconv<<<(kL * kD * kD + 255) / 256, 256, 0, stream>>>(W1, Wf1, kL);
  k_wconv<<<(kL * kD * kD + 255) / 256, 256, 0, stream>>>(W2, Wf2, kL);
  k_scan<<<1, 1024, 0, stream>>>(rowptr, kN + 1);
  (void)hipMemcpyAsync(cursor, rowptr, kN * sizeof(int), hipMemcpyDeviceToDevice, stream);
  k_fill<<<(kE + 255) / 256, 256, 0, stream>>>(ei, cursor, srcs);

  const float* curH = x;
  const float* curScale = nullptr;
  const float* curShift = nullptr;
  float* aggBuf = bufA;
  float* other = bufB;
  const int ngemm = (kN + 127) / 128;

  for (int l = 0; l < kL; ++l) {
    if (curScale == nullptr)
      k_gather<false><<<kN / 4, 256, 0, stream>>>(curH, rowptr, srcs, nullptr, nullptr, aggBuf);
    else
      k_gather<true><<<kN / 4, 256, 0, stream>>>(curH, rowptr, srcs, curScale, curShift, aggBuf);

    float* st1 = wsf + (size_t)(l * 2 + 0) * 512;
    k_gemm<<<ngemm, 256, 0, stream>>>(aggBuf, Wf1 + (size_t)l * kD * kD,
                                      b1 + l * kD, nullptr, nullptr, other,
                                      st1, st1 + 128);
    k_bnparams<<<1, kD, 0, stream>>>(st1, st1 + 128, g1 + l * kD, be1 + l * kD,
                                     st1 + 256, st1 + 384);

    float* st2 = wsf + (size_t)(l * 2 + 1) * 512;
    k_gemm<<<ngemm, 256, 0, stream>>>(other, Wf2 + (size_t)l * kD * kD,
                                      b2 + l * kD, st1 + 256, st1 + 384, aggBuf,
                                      st2, st2 + 128);
    k_bnparams<<<1, kD, 0, stream>>>(st2, st2 + 128, g2 + l * kD, be2 + l * kD,
                                     st2 + 256, st2 + 384);

    curH = aggBuf;
    curScale = st2 + 256;
    curShift = st2 + 384;
    float* tmp = aggBuf;
    aggBuf = other;
    other = tmp;
  }

  k_pool<<<kB, 256, 0, stream>>>(curH, gstart, curScale, curShift, out);
}

// Round 6
// 468.522 us; speedup vs baseline: 9.4809x; 1.0446x over previous
//
#include <hip/hip_runtime.h>

constexpr int kN = 50000;
constexpr int kE = 800000;
constexpr int kD = 128;
constexpr int kB = 256;
constexpr int kL = 3;
constexpr float kEps = 1e-5f;

typedef __attribute__((ext_vector_type(8))) short short8;
typedef __attribute__((ext_vector_type(4))) float f32x4;

__device__ __forceinline__ float4 bnrelu4(float4 v, float4 sc, float4 sh) {
  float4 r;
  r.x = fmaxf(fmaf(v.x, sc.x, sh.x), 0.f);
  r.y = fmaxf(fmaf(v.y, sc.y, sh.y), 0.f);
  r.z = fmaxf(fmaf(v.z, sc.z, sh.z), 0.f);
  r.w = fmaxf(fmaf(v.w, sc.w, sh.w), 0.f);
  return r;
}

__device__ __forceinline__ void acc4(float4& a, const float4& v) {
  a.x += v.x; a.y += v.y; a.z += v.z; a.w += v.w;
}
__device__ __forceinline__ void accsq4(float4& a, const float4& v) {
  a.x = fmaf(v.x, v.x, a.x); a.y = fmaf(v.y, v.y, a.y);
  a.z = fmaf(v.z, v.z, a.z); a.w = fmaf(v.w, v.w, a.w);
}

// fp32 -> bf16 round-to-nearest-even
__device__ __forceinline__ unsigned int f2bf(float x) {
  unsigned int u = __float_as_uint(x);
  u = u + 0x7FFFu + ((u >> 16) & 1u);
  return u >> 16;
}
__device__ __forceinline__ float bf2f(unsigned int lo16) {
  return __uint_as_float(lo16 << 16);
}

// ---------------- CSR build ----------------

__global__ void k_hist(const int* __restrict__ ei, int* __restrict__ rowptr) {
  int e = blockIdx.x * 256 + threadIdx.x;
  if (e >= kE) return;
  atomicAdd(&rowptr[1 + ei[kE + e]], 1);
}

__global__ __launch_bounds__(1024) void k_scan(int* __restrict__ data, int n) {
  __shared__ int wsum[16];
  __shared__ int carry;
  const int tid = threadIdx.x;
  const int lane = tid & 63;
  const int wid = tid >> 6;
  if (tid == 0) carry = 0;
  __syncthreads();
  for (int base = 0; base < n; base += 1024) {
    int i = base + tid;
    int v = (i < n) ? data[i] : 0;
#pragma unroll
    for (int off = 1; off < 64; off <<= 1) {
      int t = __shfl_up(v, off);
      if (lane >= off) v += t;
    }
    if (lane == 63) wsum[wid] = v;
    __syncthreads();
    if (tid == 0) {
      int s = 0;
#pragma unroll
      for (int k = 0; k < 16; ++k) { s += wsum[k]; wsum[k] = s; }
    }
    __syncthreads();
    int out = v + (wid > 0 ? wsum[wid - 1] : 0) + carry;
    if (i < n) data[i] = out;
    __syncthreads();
    if (tid == 0) carry += wsum[15];
    __syncthreads();
  }
}

__global__ void k_fill(const int* __restrict__ ei, int* __restrict__ cursor,
                       int* __restrict__ srcs) {
  int e = blockIdx.x * 256 + threadIdx.x;
  if (e >= kE) return;
  int d = ei[kE + e];
  int p = atomicAdd(&cursor[d], 1);
  srcs[p] = ei[e];
}

__global__ void k_bounds(const int* __restrict__ batch, int* __restrict__ gstart) {
  int n = blockIdx.x * 256 + threadIdx.x;
  if (n > kN) return;
  int b = (n < kN) ? batch[n] : kB;
  int bp = (n > 0) ? batch[n - 1] : -1;
  for (int g = bp + 1; g <= b; ++g) gstart[g] = n;
}

// ---------------- fp32 -> bf16 feature convert (x) ----------------
__global__ void k_xconv(const float* __restrict__ x, unsigned short* __restrict__ x16) {
  int idx = blockIdx.x * 256 + threadIdx.x;   // 8 elems per thread
  if (idx >= kN * kD / 8) return;
  const float* ap = x + (size_t)idx * 8;
  float4 v0 = *reinterpret_cast<const float4*>(ap);
  float4 v1 = *reinterpret_cast<const float4*>(ap + 4);
  short8 u;
  u[0] = (short)f2bf(v0.x); u[1] = (short)f2bf(v0.y);
  u[2] = (short)f2bf(v0.z); u[3] = (short)f2bf(v0.w);
  u[4] = (short)f2bf(v1.x); u[5] = (short)f2bf(v1.y);
  u[6] = (short)f2bf(v1.z); u[7] = (short)f2bf(v1.w);
  *reinterpret_cast<short8*>(x16 + (size_t)idx * 8) = u;
}

// ---------------- W fp32 -> bf16 fragment-order ----------------
// B-frag of mfma_f32_16x16x32_bf16: lane holds B[(lane>>4)*8+j][lane&15].
__global__ void k_wconv(const float* __restrict__ W, unsigned short* __restrict__ Wf,
                        int nmat) {
  int idx = blockIdx.x * 256 + threadIdx.x;
  if (idx >= nmat * kD * kD) return;
  int m = idx & (kD * kD - 1);
  int w = idx >> 14;
  int k = m >> 7, col = m & 127;
  int kb = k >> 5, cb = col >> 4;
  int lane = (col & 15) + 16 * ((k & 31) >> 3);
  int j = k & 7;
  Wf[(size_t)w * kD * kD + ((size_t)(kb * 8 + cb) * 64 + lane) * 8 + j] =
      (unsigned short)f2bf(W[idx]);
}

// ---------------- aggregation (bf16 h, fp32 accumulate, bf16 out) ----------------
// lane owns cols 2*lane, 2*lane+1 (one packed dword per row)
template <bool BN>
__global__ __launch_bounds__(256) void k_gather(
    const unsigned int* __restrict__ h16, const int* __restrict__ rowptr,
    const int* __restrict__ srcs, const float* __restrict__ scale,
    const float* __restrict__ shift, unsigned int* __restrict__ agg16) {
  const int node = blockIdx.x * 4 + (threadIdx.x >> 6);
  const int lane = threadIdx.x & 63;
  float2 sc, sh;
  if (BN) {
    sc = reinterpret_cast<const float2*>(scale)[lane];
    sh = reinterpret_cast<const float2*>(shift)[lane];
  }
  unsigned int u = h16[(size_t)node * 64 + lane];
  float ax = bf2f(u & 0xFFFFu), ay = __uint_as_float(u & 0xFFFF0000u);
  if (BN) {
    ax = fmaxf(fmaf(ax, sc.x, sh.x), 0.f);
    ay = fmaxf(fmaf(ay, sc.y, sh.y), 0.f);
  }
  const int beg = rowptr[node];
  const int end = rowptr[node + 1];
  for (int j0 = beg; j0 < end; j0 += 64) {
    int mysrc = (j0 + lane < end) ? srcs[j0 + lane] : 0;
    int cnt = min(64, end - j0);
    for (int t = 0; t < cnt; ++t) {
      int s = __shfl(mysrc, t);
      unsigned int v = h16[(size_t)s * 64 + lane];
      float vx = bf2f(v & 0xFFFFu), vy = __uint_as_float(v & 0xFFFF0000u);
      if (BN) {
        vx = fmaxf(fmaf(vx, sc.x, sh.x), 0.f);
        vy = fmaxf(fmaf(vy, sc.y, sh.y), 0.f);
      }
      ax += vx;
      ay += vy;
    }
  }
  agg16[(size_t)node * 64 + lane] = f2bf(ax) | (f2bf(ay) << 16);
}

// ---------------- MFMA GEMM + BN-stats ----------------
// Y = f(A) @ W + bias; A,Y bf16, stats fp32 from pre-rounding accumulator.
__global__ __launch_bounds__(256) void k_gemm(
    const unsigned short* __restrict__ A16, const unsigned short* __restrict__ Wf,
    const float* __restrict__ bias, const float* __restrict__ scaleA,
    const float* __restrict__ shiftA, unsigned short* __restrict__ Y16,
    float* __restrict__ s_sum, float* __restrict__ s_ss) {
  union SMem {
    unsigned short af[32 * 64 * 8];  // 32 A-frags x 64 lanes x 8 bf16 = 32KB
    float epi[64 * 132];             // epilogue staging
  };
  __shared__ SMem sm;

  const int tid = threadIdx.x;
  const int w = tid >> 6;
  const int lane = tid & 63;
  const int row0 = blockIdx.x * 128;

  // ---- B fragments from global (L2-hot) ----
  short8 bfr[4][2];
#pragma unroll
  for (int kb = 0; kb < 4; ++kb)
#pragma unroll
    for (int c = 0; c < 2; ++c)
      bfr[kb][c] = *reinterpret_cast<const short8*>(
          Wf + ((size_t)(kb * 8 + (2 * w + c)) * 64 + lane) * 8);

  // ---- stage A tile as bf16 fragments ----
  {
    const int rlow = tid >> 4;
    const int k0 = (tid & 15) * 8;
    const int kb = k0 >> 5;
    const int lif = rlow + 16 * ((k0 & 31) >> 3);
    float4 sc0, sc1, sh0, sh1;
    if (scaleA != nullptr) {
      sc0 = *reinterpret_cast<const float4*>(scaleA + k0);
      sc1 = *reinterpret_cast<const float4*>(scaleA + k0 + 4);
      sh0 = *reinterpret_cast<const float4*>(shiftA + k0);
      sh1 = *reinterpret_cast<const float4*>(shiftA + k0 + 4);
    }
#pragma unroll
    for (int i = 0; i < 8; ++i) {
      int grow = row0 + rlow + 16 * i;
      short8 u = (short8)0;
      if (grow < kN) {
        u = *reinterpret_cast<const short8*>(A16 + (size_t)grow * kD + k0);
        if (scaleA != nullptr) {
          float4 v0, v1;
          v0.x = bf2f((unsigned short)u[0]); v0.y = bf2f((unsigned short)u[1]);
          v0.z = bf2f((unsigned short)u[2]); v0.w = bf2f((unsigned short)u[3]);
          v1.x = bf2f((unsigned short)u[4]); v1.y = bf2f((unsigned short)u[5]);
          v1.z = bf2f((unsigned short)u[6]); v1.w = bf2f((unsigned short)u[7]);
          v0 = bnrelu4(v0, sc0, sh0);
          v1 = bnrelu4(v1, sc1, sh1);
          u[0] = (short)f2bf(v0.x); u[1] = (short)f2bf(v0.y);
          u[2] = (short)f2bf(v0.z); u[3] = (short)f2bf(v0.w);
          u[4] = (short)f2bf(v1.x); u[5] = (short)f2bf(v1.y);
          u[6] = (short)f2bf(v1.z); u[7] = (short)f2bf(v1.w);
        }
      }
      int frag = i * 4 + kb;
      *reinterpret_cast<short8*>(&sm.af[((size_t)frag * 64 + lif) * 8]) = u;
    }
  }
  __syncthreads();

  // ---- MFMA main: 64 MFMAs per wave ----
  f32x4 acc[8][2];
#pragma unroll
  for (int rb = 0; rb < 8; ++rb) {
    acc[rb][0] = (f32x4){0.f, 0.f, 0.f, 0.f};
    acc[rb][1] = (f32x4){0.f, 0.f, 0.f, 0.f};
  }
#pragma unroll
  for (int kb = 0; kb < 4; ++kb) {
    short8 afr[8];
#pragma unroll
    for (int rb = 0; rb < 8; ++rb)
      afr[rb] = *reinterpret_cast<const short8*>(
          &sm.af[((size_t)(rb * 4 + kb) * 64 + lane) * 8]);
#pragma unroll
    for (int rb = 0; rb < 8; ++rb) {
      acc[rb][0] = __builtin_amdgcn_mfma_f32_16x16x32_bf16(afr[rb], bfr[kb][0],
                                                           acc[rb][0], 0, 0, 0);
      acc[rb][1] = __builtin_amdgcn_mfma_f32_16x16x32_bf16(afr[rb], bfr[kb][1],
                                                           acc[rb][1], 0, 0, 0);
    }
  }

  // ---- epilogue: two 64-row passes through LDS ----
  const int col4 = tid & 31;
  const int rowg = tid >> 5;
  float4 b4 = reinterpret_cast<const float4*>(bias)[col4];
  float4 ss = make_float4(0.f, 0.f, 0.f, 0.f);
  float4 qq = make_float4(0.f, 0.f, 0.f, 0.f);

#pragma unroll
  for (int p = 0; p < 2; ++p) {
    __syncthreads();
#pragma unroll
    for (int rb4 = 0; rb4 < 4; ++rb4) {
      int rb = p * 4 + rb4;
#pragma unroll
      for (int c = 0; c < 2; ++c) {
#pragma unroll
        for (int j = 0; j < 4; ++j) {
          sm.epi[(size_t)(rb4 * 16 + (lane >> 4) * 4 + j) * 132 +
                 w * 32 + c * 16 + (lane & 15)] = acc[rb][c][j];
        }
      }
    }
    __syncthreads();
#pragma unroll
    for (int i = 0; i < 8; ++i) {
      int lrow = rowg * 8 + i;
      int grow = row0 + p * 64 + lrow;
      float4 v = *reinterpret_cast<float4*>(&sm.epi[(size_t)lrow * 132 + col4 * 4]);
      acc4(v, b4);
      if (grow < kN) {
        uint2 pk;
        pk.x = f2bf(v.x) | (f2bf(v.y) << 16);
        pk.y = f2bf(v.z) | (f2bf(v.w) << 16);
        *reinterpret_cast<uint2*>(Y16 + (size_t)grow * kD + col4 * 4) = pk;
        acc4(ss, v);
        accsq4(qq, v);
      }
    }
  }

  // ---- stats reduce ----
  __syncthreads();
  *reinterpret_cast<float4*>(&sm.epi[(size_t)rowg * 128 + col4 * 4]) = ss;
  *reinterpret_cast<float4*>(&sm.epi[1024 + (size_t)rowg * 128 + col4 * 4]) = qq;
  __syncthreads();
  if (tid < kD) {
    float s = 0.f;
#pragma unroll
    for (int j = 0; j < 8; ++j) s += sm.epi[j * 128 + tid];
    atomicAdd(&s_sum[tid], s);
  } else {
    int c = tid - kD;
    float s = 0.f;
#pragma unroll
    for (int j = 0; j < 8; ++j) s += sm.epi[1024 + j * 128 + c];
    atomicAdd(&s_ss[c], s);
  }
}

__global__ void k_bnparams(const float* __restrict__ s_sum, const float* __restrict__ s_ss,
                           const float* __restrict__ g, const float* __restrict__ be,
                           float* __restrict__ scale, float* __restrict__ shift) {
  int c = threadIdx.x;
  float mu = s_sum[c] * (1.f / kN);
  float var = s_ss[c] * (1.f / kN) - mu * mu;
  float sc = g[c] * rsqrtf(var + kEps);
  scale[c] = sc;
  shift[c] = be[c] - mu * sc;
}

// segmented pool over sorted batch; bf16 h, fp32 out
__global__ __launch_bounds__(256) void k_pool(
    const unsigned short* __restrict__ h16, const int* __restrict__ gstart,
    const float* __restrict__ scale, const float* __restrict__ shift,
    float* __restrict__ out) {
  const int g = blockIdx.x;
  const int q = threadIdx.x & 31;   // cols q*4..q*4+3
  const int r = threadIdx.x >> 5;
  const int s = gstart[g], e = gstart[g + 1];
  float4 sc = reinterpret_cast<const float4*>(scale)[q];
  float4 sh = reinterpret_cast<const float4*>(shift)[q];
  float4 acc = make_float4(0.f, 0.f, 0.f, 0.f);
  for (int n = s + r; n < e; n += 8) {
    uint2 u = *reinterpret_cast<const uint2*>(h16 + (size_t)n * kD + q * 4);
    float4 v;
    v.x = bf2f(u.x & 0xFFFFu);
    v.y = __uint_as_float(u.x & 0xFFFF0000u);
    v.z = bf2f(u.y & 0xFFFFu);
    v.w = __uint_as_float(u.y & 0xFFFF0000u);
    acc4(acc, bnrelu4(v, sc, sh));
  }
  __shared__ float4 red[8][32];
  red[r][q] = acc;
  __syncthreads();
  if (r == 0) {
    float4 t = acc;
#pragma unroll
    for (int j = 1; j < 8; ++j) acc4(t, red[j][q]);
    reinterpret_cast<float4*>(out)[(size_t)g * 32 + q] = t;
  }
}

extern "C" void kernel_launch(void* const* d_in, const int* in_sizes, int n_in,
                              void* d_out, int out_size, void* d_ws, size_t ws_size,
                              hipStream_t stream) {
  const float* x   = (const float*)d_in[0];
  const int*   ei  = (const int*)d_in[1];
  const int*   bat = (const int*)d_in[2];
  const float* W1  = (const float*)d_in[3];
  const float* b1  = (const float*)d_in[4];
  const float* g1  = (const float*)d_in[5];
  const float* be1 = (const float*)d_in[6];
  const float* W2  = (const float*)d_in[7];
  const float* b2  = (const float*)d_in[8];
  const float* g2  = (const float*)d_in[9];
  const float* be2 = (const float*)d_in[10];
  float* out = (float*)d_out;

  char* p = (char*)d_ws;
  float* wsf = (float*)p;                       p += 16384;
  unsigned short* x16 = (unsigned short*)p;     p += (size_t)kN * kD * 2;
  unsigned short* bufA = (unsigned short*)p;    p += (size_t)kN * kD * 2;
  unsigned short* bufB = (unsigned short*)p;    p += (size_t)kN * kD * 2;
  unsigned short* Wf1 = (unsigned short*)p;     p += (size_t)kL * kD * kD * 2;
  unsigned short* Wf2 = (unsigned short*)p;     p += (size_t)kL * kD * kD * 2;
  int* rowptr = (int*)p;                        p += (kN + 2) * 4;
  int* cursor = (int*)p;                        p += kN * 4;
  int* gstart = (int*)p;                        p += (kB + 2) * 4;
  int* srcs = (int*)p;                          p += (size_t)kE * 4;

  (void)hipMemsetAsync(wsf, 0, 6 * 512 * sizeof(float), stream);
  (void)hipMemsetAsync(rowptr, 0, (kN + 1) * sizeof(int), stream);

  // layer-invariant preprocessing
  k_hist<<<(kE + 255) / 256, 256, 0, stream>>>(ei, rowptr);
  k_bounds<<<(kN + 256) / 256, 256, 0, stream>>>(bat, gstart);
  k_xconv<<<(kN * kD / 8 + 255) / 256, 256, 0, stream>>>(x, x16);
  k_wconv<<<(kL * kD * kD + 255) / 256, 256, 0, stream>>>(W1, Wf1, kL);
  k_wconv<<<(kL * kD * kD + 255) / 256, 256, 0, stream>>>(W2, Wf2, kL);
  k_scan<<<1, 1024, 0, stream>>>(rowptr, kN + 1);
  (void)hipMemcpyAsync(cursor, rowptr, kN * sizeof(int), hipMemcpyDeviceToDevice, stream);
  k_fill<<<(kE + 255) / 256, 256, 0, stream>>>(ei, cursor, srcs);

  const unsigned short* curH = x16;
  const float* curScale = nullptr;
  const float* curShift = nullptr;
  const int ngemm = (kN + 127) / 128;

  // buffers: gather -> bufA(layer even)/... ping-pong handled explicitly
  unsigned short* aggBuf = bufA;
  unsigned short* yBuf = bufB;

  for (int l = 0; l < kL; ++l) {
    if (curScale == nullptr)
      k_gather<false><<<kN / 4, 256, 0, stream>>>(
          (const unsigned int*)curH, rowptr, srcs, nullptr, nullptr,
          (unsigned int*)aggBuf);
    else
      k_gather<true><<<kN / 4, 256, 0, stream>>>(
          (const unsigned int*)curH, rowptr, srcs, curScale, curShift,
          (unsigned int*)aggBuf);

    float* st1 = wsf + (size_t)(l * 2 + 0) * 512;
    k_gemm<<<ngemm, 256, 0, stream>>>(aggBuf, Wf1 + (size_t)l * kD * kD,
                                      b1 + l * kD, nullptr, nullptr, yBuf,
                                      st1, st1 + 128);
    k_bnparams<<<1, kD, 0, stream>>>(st1, st1 + 128, g1 + l * kD, be1 + l * kD,
                                     st1 + 256, st1 + 384);

    float* st2 = wsf + (size_t)(l * 2 + 1) * 512;
    k_gemm<<<ngemm, 256, 0, stream>>>(yBuf, Wf2 + (size_t)l * kD * kD,
                                      b2 + l * kD, st1 + 256, st1 + 384, aggBuf,
                                      st2, st2 + 128);
    k_bnparams<<<1, kD, 0, stream>>>(st2, st2 + 128, g2 + l * kD, be2 + l * kD,
                                     st2 + 256, st2 + 384);

    curH = aggBuf;
    curScale = st2 + 256;
    curShift = st2 + 384;
    unsigned short* tmp = aggBuf;
    aggBuf = yBuf;
    yBuf = tmp;
  }

  k_pool<<<kB, 256, 0, stream>>>(curH, gstart, curScale, curShift, out);
}

// Round 7
// 381.550 us; speedup vs baseline: 11.6420x; 1.2279x over previous
//
#include <hip/hip_runtime.h>

constexpr int kN = 50000;
constexpr int kE = 800000;
constexpr int kD = 128;
constexpr int kB = 256;
constexpr int kL = 3;
constexpr float kEps = 1e-5f;

typedef __attribute__((ext_vector_type(8))) short short8;
typedef __attribute__((ext_vector_type(4))) float f32x4;

__device__ __forceinline__ float4 bnrelu4(float4 v, float4 sc, float4 sh) {
  float4 r;
  r.x = fmaxf(fmaf(v.x, sc.x, sh.x), 0.f);
  r.y = fmaxf(fmaf(v.y, sc.y, sh.y), 0.f);
  r.z = fmaxf(fmaf(v.z, sc.z, sh.z), 0.f);
  r.w = fmaxf(fmaf(v.w, sc.w, sh.w), 0.f);
  return r;
}

__device__ __forceinline__ void acc4(float4& a, const float4& v) {
  a.x += v.x; a.y += v.y; a.z += v.z; a.w += v.w;
}
__device__ __forceinline__ void accsq4(float4& a, const float4& v) {
  a.x = fmaf(v.x, v.x, a.x); a.y = fmaf(v.y, v.y, a.y);
  a.z = fmaf(v.z, v.z, a.z); a.w = fmaf(v.w, v.w, a.w);
}

// fp32 -> bf16 round-to-nearest-even
__device__ __forceinline__ unsigned int f2bf(float x) {
  unsigned int u = __float_as_uint(x);
  u = u + 0x7FFFu + ((u >> 16) & 1u);
  return u >> 16;
}
__device__ __forceinline__ float bf2f(unsigned int lo16) {
  return __uint_as_float(lo16 << 16);
}

// BN scale/shift from raw stats (replaces k_bnparams, computed inline)
__device__ __forceinline__ void bnmake(float su, float sq, float ga, float be,
                                       float& sc, float& sh) {
  float mu = su * (1.f / kN);
  float var = fmaf(-mu, mu, sq * (1.f / kN));
  float s = ga * rsqrtf(var + kEps);
  sc = s;
  sh = fmaf(-mu, s, be);
}

// ---------------- CSR build ----------------

__global__ void k_hist(const int* __restrict__ ei, int* __restrict__ rowptr) {
  int e = blockIdx.x * 256 + threadIdx.x;
  if (e >= kE) return;
  atomicAdd(&rowptr[1 + ei[kE + e]], 1);
}

__global__ __launch_bounds__(1024) void k_scan(int* __restrict__ data, int n) {
  __shared__ int wsum[16];
  __shared__ int carry;
  const int tid = threadIdx.x;
  const int lane = tid & 63;
  const int wid = tid >> 6;
  if (tid == 0) carry = 0;
  __syncthreads();
  for (int base = 0; base < n; base += 1024) {
    int i = base + tid;
    int v = (i < n) ? data[i] : 0;
#pragma unroll
    for (int off = 1; off < 64; off <<= 1) {
      int t = __shfl_up(v, off);
      if (lane >= off) v += t;
    }
    if (lane == 63) wsum[wid] = v;
    __syncthreads();
    if (tid == 0) {
      int s = 0;
#pragma unroll
      for (int k = 0; k < 16; ++k) { s += wsum[k]; wsum[k] = s; }
    }
    __syncthreads();
    int out = v + (wid > 0 ? wsum[wid - 1] : 0) + carry;
    if (i < n) data[i] = out;
    __syncthreads();
    if (tid == 0) carry += wsum[15];
    __syncthreads();
  }
}

__global__ void k_fill(const int* __restrict__ ei, int* __restrict__ cursor,
                       int* __restrict__ srcs) {
  int e = blockIdx.x * 256 + threadIdx.x;
  if (e >= kE) return;
  int d = ei[kE + e];
  int p = atomicAdd(&cursor[d], 1);
  srcs[p] = ei[e];
}

__global__ void k_bounds(const int* __restrict__ batch, int* __restrict__ gstart) {
  int n = blockIdx.x * 256 + threadIdx.x;
  if (n > kN) return;
  int b = (n < kN) ? batch[n] : kB;
  int bp = (n > 0) ? batch[n - 1] : -1;
  for (int g = bp + 1; g <= b; ++g) gstart[g] = n;
}

// ---------------- fp32 -> bf16 feature convert (x) ----------------
__global__ void k_xconv(const float* __restrict__ x, unsigned short* __restrict__ x16) {
  int idx = blockIdx.x * 256 + threadIdx.x;
  if (idx >= kN * kD / 8) return;
  const float* ap = x + (size_t)idx * 8;
  float4 v0 = *reinterpret_cast<const float4*>(ap);
  float4 v1 = *reinterpret_cast<const float4*>(ap + 4);
  short8 u;
  u[0] = (short)f2bf(v0.x); u[1] = (short)f2bf(v0.y);
  u[2] = (short)f2bf(v0.z); u[3] = (short)f2bf(v0.w);
  u[4] = (short)f2bf(v1.x); u[5] = (short)f2bf(v1.y);
  u[6] = (short)f2bf(v1.z); u[7] = (short)f2bf(v1.w);
  *reinterpret_cast<short8*>(x16 + (size_t)idx * 8) = u;
}

// ---------------- W fp32 -> bf16 fragment-order ----------------
__global__ void k_wconv(const float* __restrict__ W, unsigned short* __restrict__ Wf,
                        int nmat) {
  int idx = blockIdx.x * 256 + threadIdx.x;
  if (idx >= nmat * kD * kD) return;
  int m = idx & (kD * kD - 1);
  int w = idx >> 14;
  int k = m >> 7, col = m & 127;
  int kb = k >> 5, cb = col >> 4;
  int lane = (col & 15) + 16 * ((k & 31) >> 3);
  int j = k & 7;
  Wf[(size_t)w * kD * kD + ((size_t)(kb * 8 + cb) * 64 + lane) * 8 + j] =
      (unsigned short)f2bf(W[idx]);
}

// ---------------- aggregation ----------------
// one wave per node, lane owns cols 2*lane..2*lane+1 (one packed dword/row).
// beg/end hoisted to SGPR -> srcs[j] is a scalar load (no bpermute);
// 4x unroll keeps 4 row-loads in flight.
template <bool BN>
__global__ __launch_bounds__(256) void k_gather(
    const unsigned int* __restrict__ h16, const int* __restrict__ rowptr,
    const int* __restrict__ srcs, const float* __restrict__ stats,
    const float* __restrict__ gam, const float* __restrict__ bet,
    unsigned int* __restrict__ agg16) {
  const int node = blockIdx.x * 4 + (threadIdx.x >> 6);
  const int lane = threadIdx.x & 63;
  float scx, scy, shx, shy;
  if (BN) {
    int c = lane * 2;
    bnmake(stats[c], stats[kD + c], gam[c], bet[c], scx, shx);
    bnmake(stats[c + 1], stats[kD + c + 1], gam[c + 1], bet[c + 1], scy, shy);
  }
  unsigned int u = h16[(size_t)node * 64 + lane];
  float ax = bf2f(u & 0xFFFFu), ay = __uint_as_float(u & 0xFFFF0000u);
  if (BN) {
    ax = fmaxf(fmaf(ax, scx, shx), 0.f);
    ay = fmaxf(fmaf(ay, scy, shy), 0.f);
  }
  const int beg = __builtin_amdgcn_readfirstlane(rowptr[node]);
  const int end = __builtin_amdgcn_readfirstlane(rowptr[node + 1]);
  int j = beg;
  for (; j + 4 <= end; j += 4) {
    int s0 = srcs[j + 0];
    int s1 = srcs[j + 1];
    int s2 = srcs[j + 2];
    int s3 = srcs[j + 3];
    unsigned int v0 = h16[(size_t)s0 * 64 + lane];
    unsigned int v1 = h16[(size_t)s1 * 64 + lane];
    unsigned int v2 = h16[(size_t)s2 * 64 + lane];
    unsigned int v3 = h16[(size_t)s3 * 64 + lane];
    float x0 = bf2f(v0 & 0xFFFFu), y0 = __uint_as_float(v0 & 0xFFFF0000u);
    float x1 = bf2f(v1 & 0xFFFFu), y1 = __uint_as_float(v1 & 0xFFFF0000u);
    float x2 = bf2f(v2 & 0xFFFFu), y2 = __uint_as_float(v2 & 0xFFFF0000u);
    float x3 = bf2f(v3 & 0xFFFFu), y3 = __uint_as_float(v3 & 0xFFFF0000u);
    if (BN) {
      x0 = fmaxf(fmaf(x0, scx, shx), 0.f); y0 = fmaxf(fmaf(y0, scy, shy), 0.f);
      x1 = fmaxf(fmaf(x1, scx, shx), 0.f); y1 = fmaxf(fmaf(y1, scy, shy), 0.f);
      x2 = fmaxf(fmaf(x2, scx, shx), 0.f); y2 = fmaxf(fmaf(y2, scy, shy), 0.f);
      x3 = fmaxf(fmaf(x3, scx, shx), 0.f); y3 = fmaxf(fmaf(y3, scy, shy), 0.f);
    }
    ax += (x0 + x1) + (x2 + x3);
    ay += (y0 + y1) + (y2 + y3);
  }
  for (; j < end; ++j) {
    int s = srcs[j];
    unsigned int v = h16[(size_t)s * 64 + lane];
    float vx = bf2f(v & 0xFFFFu), vy = __uint_as_float(v & 0xFFFF0000u);
    if (BN) {
      vx = fmaxf(fmaf(vx, scx, shx), 0.f);
      vy = fmaxf(fmaf(vy, scy, shy), 0.f);
    }
    ax += vx;
    ay += vy;
  }
  agg16[(size_t)node * 64 + lane] = f2bf(ax) | (f2bf(ay) << 16);
}

// ---------------- MFMA GEMM + BN-stats ----------------
// Y = f(A) @ W + bias; A,Y bf16; BN scale/shift computed inline from statsA.
__global__ __launch_bounds__(256) void k_gemm(
    const unsigned short* __restrict__ A16, const unsigned short* __restrict__ Wf,
    const float* __restrict__ bias, const float* __restrict__ statsA,
    const float* __restrict__ gamA, const float* __restrict__ betA,
    unsigned short* __restrict__ Y16,
    float* __restrict__ s_sum, float* __restrict__ s_ss) {
  union SMem {
    unsigned short af[32 * 64 * 8];
    float epi[64 * 132];
  };
  __shared__ SMem sm;

  const int tid = threadIdx.x;
  const int w = tid >> 6;
  const int lane = tid & 63;
  const int row0 = blockIdx.x * 128;

  // ---- B fragments from global (L2-hot) ----
  short8 bfr[4][2];
#pragma unroll
  for (int kb = 0; kb < 4; ++kb)
#pragma unroll
    for (int c = 0; c < 2; ++c)
      bfr[kb][c] = *reinterpret_cast<const short8*>(
          Wf + ((size_t)(kb * 8 + (2 * w + c)) * 64 + lane) * 8);

  // ---- stage A tile as bf16 fragments ----
  {
    const int rlow = tid >> 4;
    const int k0 = (tid & 15) * 8;
    const int kb = k0 >> 5;
    const int lif = rlow + 16 * ((k0 & 31) >> 3);
    float4 sc0, sc1, sh0, sh1;
    if (statsA != nullptr) {
      float4 su0 = *reinterpret_cast<const float4*>(statsA + k0);
      float4 su1 = *reinterpret_cast<const float4*>(statsA + k0 + 4);
      float4 sq0 = *reinterpret_cast<const float4*>(statsA + kD + k0);
      float4 sq1 = *reinterpret_cast<const float4*>(statsA + kD + k0 + 4);
      float4 ga0 = *reinterpret_cast<const float4*>(gamA + k0);
      float4 ga1 = *reinterpret_cast<const float4*>(gamA + k0 + 4);
      float4 be0 = *reinterpret_cast<const float4*>(betA + k0);
      float4 be1 = *reinterpret_cast<const float4*>(betA + k0 + 4);
      bnmake(su0.x, sq0.x, ga0.x, be0.x, sc0.x, sh0.x);
      bnmake(su0.y, sq0.y, ga0.y, be0.y, sc0.y, sh0.y);
      bnmake(su0.z, sq0.z, ga0.z, be0.z, sc0.z, sh0.z);
      bnmake(su0.w, sq0.w, ga0.w, be0.w, sc0.w, sh0.w);
      bnmake(su1.x, sq1.x, ga1.x, be1.x, sc1.x, sh1.x);
      bnmake(su1.y, sq1.y, ga1.y, be1.y, sc1.y, sh1.y);
      bnmake(su1.z, sq1.z, ga1.z, be1.z, sc1.z, sh1.z);
      bnmake(su1.w, sq1.w, ga1.w, be1.w, sc1.w, sh1.w);
    }
#pragma unroll
    for (int i = 0; i < 8; ++i) {
      int grow = row0 + rlow + 16 * i;
      short8 u = (short8)0;
      if (grow < kN) {
        u = *reinterpret_cast<const short8*>(A16 + (size_t)grow * kD + k0);
        if (statsA != nullptr) {
          float4 v0, v1;
          v0.x = bf2f((unsigned short)u[0]); v0.y = bf2f((unsigned short)u[1]);
          v0.z = bf2f((unsigned short)u[2]); v0.w = bf2f((unsigned short)u[3]);
          v1.x = bf2f((unsigned short)u[4]); v1.y = bf2f((unsigned short)u[5]);
          v1.z = bf2f((unsigned short)u[6]); v1.w = bf2f((unsigned short)u[7]);
          v0 = bnrelu4(v0, sc0, sh0);
          v1 = bnrelu4(v1, sc1, sh1);
          u[0] = (short)f2bf(v0.x); u[1] = (short)f2bf(v0.y);
          u[2] = (short)f2bf(v0.z); u[3] = (short)f2bf(v0.w);
          u[4] = (short)f2bf(v1.x); u[5] = (short)f2bf(v1.y);
          u[6] = (short)f2bf(v1.z); u[7] = (short)f2bf(v1.w);
        }
      }
      int frag = i * 4 + kb;
      *reinterpret_cast<short8*>(&sm.af[((size_t)frag * 64 + lif) * 8]) = u;
    }
  }
  __syncthreads();

  // ---- MFMA main: 64 MFMAs per wave ----
  f32x4 acc[8][2];
#pragma unroll
  for (int rb = 0; rb < 8; ++rb) {
    acc[rb][0] = (f32x4){0.f, 0.f, 0.f, 0.f};
    acc[rb][1] = (f32x4){0.f, 0.f, 0.f, 0.f};
  }
#pragma unroll
  for (int kb = 0; kb < 4; ++kb) {
    short8 afr[8];
#pragma unroll
    for (int rb = 0; rb < 8; ++rb)
      afr[rb] = *reinterpret_cast<const short8*>(
          &sm.af[((size_t)(rb * 4 + kb) * 64 + lane) * 8]);
#pragma unroll
    for (int rb = 0; rb < 8; ++rb) {
      acc[rb][0] = __builtin_amdgcn_mfma_f32_16x16x32_bf16(afr[rb], bfr[kb][0],
                                                           acc[rb][0], 0, 0, 0);
      acc[rb][1] = __builtin_amdgcn_mfma_f32_16x16x32_bf16(afr[rb], bfr[kb][1],
                                                           acc[rb][1], 0, 0, 0);
    }
  }

  // ---- epilogue: two 64-row passes through LDS ----
  const int col4 = tid & 31;
  const int rowg = tid >> 5;
  float4 b4 = reinterpret_cast<const float4*>(bias)[col4];
  float4 ss = make_float4(0.f, 0.f, 0.f, 0.f);
  float4 qq = make_float4(0.f, 0.f, 0.f, 0.f);

#pragma unroll
  for (int p = 0; p < 2; ++p) {
    __syncthreads();
#pragma unroll
    for (int rb4 = 0; rb4 < 4; ++rb4) {
      int rb = p * 4 + rb4;
#pragma unroll
      for (int c = 0; c < 2; ++c) {
#pragma unroll
        for (int j = 0; j < 4; ++j) {
          sm.epi[(size_t)(rb4 * 16 + (lane >> 4) * 4 + j) * 132 +
                 w * 32 + c * 16 + (lane & 15)] = acc[rb][c][j];
        }
      }
    }
    __syncthreads();
#pragma unroll
    for (int i = 0; i < 8; ++i) {
      int lrow = rowg * 8 + i;
      int grow = row0 + p * 64 + lrow;
      float4 v = *reinterpret_cast<float4*>(&sm.epi[(size_t)lrow * 132 + col4 * 4]);
      acc4(v, b4);
      if (grow < kN) {
        uint2 pk;
        pk.x = f2bf(v.x) | (f2bf(v.y) << 16);
        pk.y = f2bf(v.z) | (f2bf(v.w) << 16);
        *reinterpret_cast<uint2*>(Y16 + (size_t)grow * kD + col4 * 4) = pk;
        acc4(ss, v);
        accsq4(qq, v);
      }
    }
  }

  // ---- stats reduce ----
  __syncthreads();
  *reinterpret_cast<float4*>(&sm.epi[(size_t)rowg * 128 + col4 * 4]) = ss;
  *reinterpret_cast<float4*>(&sm.epi[1024 + (size_t)rowg * 128 + col4 * 4]) = qq;
  __syncthreads();
  if (tid < kD) {
    float s = 0.f;
#pragma unroll
    for (int j = 0; j < 8; ++j) s += sm.epi[j * 128 + tid];
    atomicAdd(&s_sum[tid], s);
  } else {
    int c = tid - kD;
    float s = 0.f;
#pragma unroll
    for (int j = 0; j < 8; ++j) s += sm.epi[1024 + j * 128 + c];
    atomicAdd(&s_ss[c], s);
  }
}

// segmented pool over sorted batch; bf16 h, inline BN, fp32 out
__global__ __launch_bounds__(256) void k_pool(
    const unsigned short* __restrict__ h16, const int* __restrict__ gstart,
    const float* __restrict__ stats, const float* __restrict__ gam,
    const float* __restrict__ bet, float* __restrict__ out) {
  const int g = blockIdx.x;
  const int q = threadIdx.x & 31;
  const int r = threadIdx.x >> 5;
  const int s = gstart[g], e = gstart[g + 1];
  float4 sc, sh;
  {
    int c = q * 4;
    bnmake(stats[c + 0], stats[kD + c + 0], gam[c + 0], bet[c + 0], sc.x, sh.x);
    bnmake(stats[c + 1], stats[kD + c + 1], gam[c + 1], bet[c + 1], sc.y, sh.y);
    bnmake(stats[c + 2], stats[kD + c + 2], gam[c + 2], bet[c + 2], sc.z, sh.z);
    bnmake(stats[c + 3], stats[kD + c + 3], gam[c + 3], bet[c + 3], sc.w, sh.w);
  }
  float4 acc = make_float4(0.f, 0.f, 0.f, 0.f);
  for (int n = s + r; n < e; n += 8) {
    uint2 u = *reinterpret_cast<const uint2*>(h16 + (size_t)n * kD + q * 4);
    float4 v;
    v.x = bf2f(u.x & 0xFFFFu);
    v.y = __uint_as_float(u.x & 0xFFFF0000u);
    v.z = bf2f(u.y & 0xFFFFu);
    v.w = __uint_as_float(u.y & 0xFFFF0000u);
    acc4(acc, bnrelu4(v, sc, sh));
  }
  __shared__ float4 red[8][32];
  red[r][q] = acc;
  __syncthreads();
  if (r == 0) {
    float4 t = acc;
#pragma unroll
    for (int j = 1; j < 8; ++j) acc4(t, red[j][q]);
    reinterpret_cast<float4*>(out)[(size_t)g * 32 + q] = t;
  }
}

extern "C" void kernel_launch(void* const* d_in, const int* in_sizes, int n_in,
                              void* d_out, int out_size, void* d_ws, size_t ws_size,
                              hipStream_t stream) {
  const float* x   = (const float*)d_in[0];
  const int*   ei  = (const int*)d_in[1];
  const int*   bat = (const int*)d_in[2];
  const float* W1  = (const float*)d_in[3];
  const float* b1  = (const float*)d_in[4];
  const float* g1  = (const float*)d_in[5];
  const float* be1 = (const float*)d_in[6];
  const float* W2  = (const float*)d_in[7];
  const float* b2  = (const float*)d_in[8];
  const float* g2  = (const float*)d_in[9];
  const float* be2 = (const float*)d_in[10];
  float* out = (float*)d_out;

  char* p = (char*)d_ws;
  float* wsf = (float*)p;                       p += 16384;
  unsigned short* x16 = (unsigned short*)p;     p += (size_t)kN * kD * 2;
  unsigned short* bufA = (unsigned short*)p;    p += (size_t)kN * kD * 2;
  unsigned short* bufB = (unsigned short*)p;    p += (size_t)kN * kD * 2;
  unsigned short* Wf1 = (unsigned short*)p;     p += (size_t)kL * kD * kD * 2;
  unsigned short* Wf2 = (unsigned short*)p;     p += (size_t)kL * kD * kD * 2;
  int* rowptr = (int*)p;                        p += (kN + 2) * 4;
  int* cursor = (int*)p;                        p += kN * 4;
  int* gstart = (int*)p;                        p += (kB + 2) * 4;
  int* srcs = (int*)p;                          p += (size_t)kE * 4;

  (void)hipMemsetAsync(wsf, 0, 6 * 512 * sizeof(float), stream);
  (void)hipMemsetAsync(rowptr, 0, (kN + 1) * sizeof(int), stream);

  // layer-invariant preprocessing
  k_hist<<<(kE + 255) / 256, 256, 0, stream>>>(ei, rowptr);
  k_bounds<<<(kN + 256) / 256, 256, 0, stream>>>(bat, gstart);
  k_xconv<<<(kN * kD / 8 + 255) / 256, 256, 0, stream>>>(x, x16);
  k_wconv<<<(kL * kD * kD + 255) / 256, 256, 0, stream>>>(W1, Wf1, kL);
  k_wconv<<<(kL * kD * kD + 255) / 256, 256, 0, stream>>>(W2, Wf2, kL);
  k_scan<<<1, 1024, 0, stream>>>(rowptr, kN + 1);
  (void)hipMemcpyAsync(cursor, rowptr, kN * sizeof(int), hipMemcpyDeviceToDevice, stream);
  k_fill<<<(kE + 255) / 256, 256, 0, stream>>>(ei, cursor, srcs);

  const unsigned short* curH = x16;
  const float* curStats = nullptr;   // prev layer's outer-BN raw stats
  const float* curGam = nullptr;
  const float* curBet = nullptr;
  const int ngemm = (kN + 127) / 128;

  unsigned short* aggBuf = bufA;
  unsigned short* yBuf = bufB;

  for (int l = 0; l < kL; ++l) {
    if (curStats == nullptr)
      k_gather<false><<<kN / 4, 256, 0, stream>>>(
          (const unsigned int*)curH, rowptr, srcs, nullptr, nullptr, nullptr,
          (unsigned int*)aggBuf);
    else
      k_gather<true><<<kN / 4, 256, 0, stream>>>(
          (const unsigned int*)curH, rowptr, srcs, curStats, curGam, curBet,
          (unsigned int*)aggBuf);

    float* st1 = wsf + (size_t)(l * 2 + 0) * 512;
    k_gemm<<<ngemm, 256, 0, stream>>>(aggBuf, Wf1 + (size_t)l * kD * kD,
                                      b1 + l * kD, nullptr, nullptr, nullptr,
                                      yBuf, st1, st1 + kD);

    float* st2 = wsf + (size_t)(l * 2 + 1) * 512;
    k_gemm<<<ngemm, 256, 0, stream>>>(yBuf, Wf2 + (size_t)l * kD * kD,
                                      b2 + l * kD, st1, g1 + l * kD, be1 + l * kD,
                                      aggBuf, st2, st2 + kD);

    curH = aggBuf;
    curStats = st2;
    curGam = g2 + l * kD;
    curBet = be2 + l * kD;
    unsigned short* tmp = aggBuf;
    aggBuf = yBuf;
    yBuf = tmp;
  }

  k_pool<<<kB, 256, 0, stream>>>(curH, gstart, curStats, curGam, curBet, out);
}

// Round 8
// 369.605 us; speedup vs baseline: 12.0183x; 1.0323x over previous
//
#include <hip/hip_runtime.h>

constexpr int kN = 50000;
constexpr int kE = 800000;
constexpr int kD = 128;
constexpr int kB = 256;
constexpr int kL = 3;
constexpr float kEps = 1e-5f;

constexpr int kShift = 7;                          // 128 nodes per bucket
constexpr int kNBuk = (kN + 127) >> 7;             // 391
constexpr int kEPB = 8192;                         // edges per binning block
constexpr int kNBinBlk = (kE + kEPB - 1) / kEPB;   // 98

typedef __attribute__((ext_vector_type(8))) short short8;
typedef __attribute__((ext_vector_type(4))) float f32x4;

__device__ __forceinline__ float4 bnrelu4(float4 v, float4 sc, float4 sh) {
  float4 r;
  r.x = fmaxf(fmaf(v.x, sc.x, sh.x), 0.f);
  r.y = fmaxf(fmaf(v.y, sc.y, sh.y), 0.f);
  r.z = fmaxf(fmaf(v.z, sc.z, sh.z), 0.f);
  r.w = fmaxf(fmaf(v.w, sc.w, sh.w), 0.f);
  return r;
}

__device__ __forceinline__ void acc4(float4& a, const float4& v) {
  a.x += v.x; a.y += v.y; a.z += v.z; a.w += v.w;
}
__device__ __forceinline__ void accsq4(float4& a, const float4& v) {
  a.x = fmaf(v.x, v.x, a.x); a.y = fmaf(v.y, v.y, a.y);
  a.z = fmaf(v.z, v.z, a.z); a.w = fmaf(v.w, v.w, a.w);
}

// fp32 -> bf16 round-to-nearest-even
__device__ __forceinline__ unsigned int f2bf(float x) {
  unsigned int u = __float_as_uint(x);
  u = u + 0x7FFFu + ((u >> 16) & 1u);
  return u >> 16;
}
__device__ __forceinline__ float bf2f(unsigned int lo16) {
  return __uint_as_float(lo16 << 16);
}

// BN scale/shift from raw stats
__device__ __forceinline__ void bnmake(float su, float sq, float ga, float be,
                                       float& sc, float& sh) {
  float mu = su * (1.f / kN);
  float var = fmaf(-mu, mu, sq * (1.f / kN));
  float s = ga * rsqrtf(var + kEps);
  sc = s;
  sh = fmaf(-mu, s, be);
}

// ---------------- CSR build ----------------

__global__ void k_hist(const int* __restrict__ ei, int* __restrict__ rowptr) {
  int e = blockIdx.x * 256 + threadIdx.x;
  if (e >= kE) return;
  atomicAdd(&rowptr[1 + ei[kE + e]], 1);
}

__global__ __launch_bounds__(1024) void k_scan(int* __restrict__ data, int n) {
  __shared__ int wsum[16];
  __shared__ int carry;
  const int tid = threadIdx.x;
  const int lane = tid & 63;
  const int wid = tid >> 6;
  if (tid == 0) carry = 0;
  __syncthreads();
  for (int base = 0; base < n; base += 1024) {
    int i = base + tid;
    int v = (i < n) ? data[i] : 0;
#pragma unroll
    for (int off = 1; off < 64; off <<= 1) {
      int t = __shfl_up(v, off);
      if (lane >= off) v += t;
    }
    if (lane == 63) wsum[wid] = v;
    __syncthreads();
    if (tid == 0) {
      int s = 0;
#pragma unroll
      for (int k = 0; k < 16; ++k) { s += wsum[k]; wsum[k] = s; }
    }
    __syncthreads();
    int out = v + (wid > 0 ? wsum[wid - 1] : 0) + carry;
    if (i < n) data[i] = out;
    __syncthreads();
    if (tid == 0) carry += wsum[15];
    __syncthreads();
  }
}

// bucket cursors = CSR region starts
__global__ void k_bcur(const int* __restrict__ rowptr, int* __restrict__ bcur) {
  int b = blockIdx.x * 256 + threadIdx.x;
  if (b < kNBuk) bcur[b] = rowptr[min(b << kShift, kN)];
}

// bin edges into dst-buckets as packed (dst<<16)|src, block-aggregated
// so each block writes contiguous >=64B runs per bucket (no cross-XCD
// false sharing).
__global__ __launch_bounds__(256) void k_binpairs(
    const int* __restrict__ ei, int* __restrict__ bcur,
    unsigned int* __restrict__ pairs) {
  __shared__ int cnt[kNBuk];
  __shared__ int base[kNBuk];
  const int tid = threadIdx.x;
  const int e0 = blockIdx.x * kEPB;
  for (int t = tid; t < kNBuk; t += 256) cnt[t] = 0;
  __syncthreads();
  unsigned int dr[32];  // (dst<<16) | within-block-bucket rank
#pragma unroll
  for (int i = 0; i < 32; ++i) {
    int e = e0 + i * 256 + tid;
    unsigned int v = 0xFFFFFFFFu;
    if (e < kE) {
      int d = ei[kE + e];
      int r = atomicAdd(&cnt[d >> kShift], 1);
      v = ((unsigned int)d << 16) | (unsigned int)r;
    }
    dr[i] = v;
  }
  __syncthreads();
  for (int t = tid; t < kNBuk; t += 256) {
    int c = cnt[t];
    base[t] = (c > 0) ? atomicAdd(&bcur[t], c) : 0;
  }
  __syncthreads();
#pragma unroll
  for (int i = 0; i < 32; ++i) {
    unsigned int v = dr[i];
    if (v == 0xFFFFFFFFu) continue;
    int e = e0 + i * 256 + tid;
    unsigned int s = (unsigned int)ei[e];
    int b = (int)(v >> 16) >> kShift;
    int pos = base[b] + (int)(v & 0xFFFFu);
    pairs[pos] = (v & 0xFFFF0000u) | s;
  }
}

// one block per bucket: scatter srcs within an 8KB block-owned region
__global__ __launch_bounds__(256) void k_csrfill(
    const unsigned int* __restrict__ pairs, const int* __restrict__ rowptr,
    int* __restrict__ srcs) {
  __shared__ int cur[128];
  const int b = blockIdx.x;
  const int tid = threadIdx.x;
  const int n0 = b << kShift;
  if (tid < 128) {
    int n = n0 + tid;
    cur[tid] = (n < kN) ? rowptr[n] : 0;
  }
  __syncthreads();
  const int pbeg = rowptr[n0];
  const int pend = rowptr[min(n0 + 128, kN)];
  for (int p = pbeg + tid; p < pend; p += 256) {
    unsigned int u = pairs[p];
    int local = (int)(u >> 16) - n0;
    int pos = atomicAdd(&cur[local], 1);
    srcs[pos] = (int)(u & 0xFFFFu);
  }
}

__global__ void k_bounds(const int* __restrict__ batch, int* __restrict__ gstart) {
  int n = blockIdx.x * 256 + threadIdx.x;
  if (n > kN) return;
  int b = (n < kN) ? batch[n] : kB;
  int bp = (n > 0) ? batch[n - 1] : -1;
  for (int g = bp + 1; g <= b; ++g) gstart[g] = n;
}

// ---------------- fp32 -> bf16 feature convert (x) ----------------
__global__ void k_xconv(const float* __restrict__ x, unsigned short* __restrict__ x16) {
  int idx = blockIdx.x * 256 + threadIdx.x;
  if (idx >= kN * kD / 8) return;
  const float* ap = x + (size_t)idx * 8;
  float4 v0 = *reinterpret_cast<const float4*>(ap);
  float4 v1 = *reinterpret_cast<const float4*>(ap + 4);
  short8 u;
  u[0] = (short)f2bf(v0.x); u[1] = (short)f2bf(v0.y);
  u[2] = (short)f2bf(v0.z); u[3] = (short)f2bf(v0.w);
  u[4] = (short)f2bf(v1.x); u[5] = (short)f2bf(v1.y);
  u[6] = (short)f2bf(v1.z); u[7] = (short)f2bf(v1.w);
  *reinterpret_cast<short8*>(x16 + (size_t)idx * 8) = u;
}

// ---------------- W fp32 -> bf16 fragment-order ----------------
__global__ void k_wconv(const float* __restrict__ W, unsigned short* __restrict__ Wf,
                        int nmat) {
  int idx = blockIdx.x * 256 + threadIdx.x;
  if (idx >= nmat * kD * kD) return;
  int m = idx & (kD * kD - 1);
  int w = idx >> 14;
  int k = m >> 7, col = m & 127;
  int kb = k >> 5, cb = col >> 4;
  int lane = (col & 15) + 16 * ((k & 31) >> 3);
  int j = k & 7;
  Wf[(size_t)w * kD * kD + ((size_t)(kb * 8 + cb) * 64 + lane) * 8 + j] =
      (unsigned short)f2bf(W[idx]);
}

// ---------------- aggregation ----------------
template <bool BN>
__global__ __launch_bounds__(256) void k_gather(
    const unsigned int* __restrict__ h16, const int* __restrict__ rowptr,
    const int* __restrict__ srcs, const float* __restrict__ stats,
    const float* __restrict__ gam, const float* __restrict__ bet,
    unsigned int* __restrict__ agg16) {
  const int node = blockIdx.x * 4 + (threadIdx.x >> 6);
  const int lane = threadIdx.x & 63;
  float scx, scy, shx, shy;
  if (BN) {
    int c = lane * 2;
    bnmake(stats[c], stats[kD + c], gam[c], bet[c], scx, shx);
    bnmake(stats[c + 1], stats[kD + c + 1], gam[c + 1], bet[c + 1], scy, shy);
  }
  unsigned int u = h16[(size_t)node * 64 + lane];
  float ax = bf2f(u & 0xFFFFu), ay = __uint_as_float(u & 0xFFFF0000u);
  if (BN) {
    ax = fmaxf(fmaf(ax, scx, shx), 0.f);
    ay = fmaxf(fmaf(ay, scy, shy), 0.f);
  }
  const int beg = __builtin_amdgcn_readfirstlane(rowptr[node]);
  const int end = __builtin_amdgcn_readfirstlane(rowptr[node + 1]);
  int j = beg;
  for (; j + 4 <= end; j += 4) {
    int s0 = srcs[j + 0];
    int s1 = srcs[j + 1];
    int s2 = srcs[j + 2];
    int s3 = srcs[j + 3];
    unsigned int v0 = h16[(size_t)s0 * 64 + lane];
    unsigned int v1 = h16[(size_t)s1 * 64 + lane];
    unsigned int v2 = h16[(size_t)s2 * 64 + lane];
    unsigned int v3 = h16[(size_t)s3 * 64 + lane];
    float x0 = bf2f(v0 & 0xFFFFu), y0 = __uint_as_float(v0 & 0xFFFF0000u);
    float x1 = bf2f(v1 & 0xFFFFu), y1 = __uint_as_float(v1 & 0xFFFF0000u);
    float x2 = bf2f(v2 & 0xFFFFu), y2 = __uint_as_float(v2 & 0xFFFF0000u);
    float x3 = bf2f(v3 & 0xFFFFu), y3 = __uint_as_float(v3 & 0xFFFF0000u);
    if (BN) {
      x0 = fmaxf(fmaf(x0, scx, shx), 0.f); y0 = fmaxf(fmaf(y0, scy, shy), 0.f);
      x1 = fmaxf(fmaf(x1, scx, shx), 0.f); y1 = fmaxf(fmaf(y1, scy, shy), 0.f);
      x2 = fmaxf(fmaf(x2, scx, shx), 0.f); y2 = fmaxf(fmaf(y2, scy, shy), 0.f);
      x3 = fmaxf(fmaf(x3, scx, shx), 0.f); y3 = fmaxf(fmaf(y3, scy, shy), 0.f);
    }
    ax += (x0 + x1) + (x2 + x3);
    ay += (y0 + y1) + (y2 + y3);
  }
  for (; j < end; ++j) {
    int s = srcs[j];
    unsigned int v = h16[(size_t)s * 64 + lane];
    float vx = bf2f(v & 0xFFFFu), vy = __uint_as_float(v & 0xFFFF0000u);
    if (BN) {
      vx = fmaxf(fmaf(vx, scx, shx), 0.f);
      vy = fmaxf(fmaf(vy, scy, shy), 0.f);
    }
    ax += vx;
    ay += vy;
  }
  agg16[(size_t)node * 64 + lane] = f2bf(ax) | (f2bf(ay) << 16);
}

// ---------------- MFMA GEMM + BN-stats ----------------
__global__ __launch_bounds__(256) void k_gemm(
    const unsigned short* __restrict__ A16, const unsigned short* __restrict__ Wf,
    const float* __restrict__ bias, const float* __restrict__ statsA,
    const float* __restrict__ gamA, const float* __restrict__ betA,
    unsigned short* __restrict__ Y16,
    float* __restrict__ s_sum, float* __restrict__ s_ss) {
  union SMem {
    unsigned short af[32 * 64 * 8];
    float epi[64 * 132];
  };
  __shared__ SMem sm;

  const int tid = threadIdx.x;
  const int w = tid >> 6;
  const int lane = tid & 63;
  const int row0 = blockIdx.x * 128;

  short8 bfr[4][2];
#pragma unroll
  for (int kb = 0; kb < 4; ++kb)
#pragma unroll
    for (int c = 0; c < 2; ++c)
      bfr[kb][c] = *reinterpret_cast<const short8*>(
          Wf + ((size_t)(kb * 8 + (2 * w + c)) * 64 + lane) * 8);

  {
    const int rlow = tid >> 4;
    const int k0 = (tid & 15) * 8;
    const int kb = k0 >> 5;
    const int lif = rlow + 16 * ((k0 & 31) >> 3);
    float4 sc0, sc1, sh0, sh1;
    if (statsA != nullptr) {
      float4 su0 = *reinterpret_cast<const float4*>(statsA + k0);
      float4 su1 = *reinterpret_cast<const float4*>(statsA + k0 + 4);
      float4 sq0 = *reinterpret_cast<const float4*>(statsA + kD + k0);
      float4 sq1 = *reinterpret_cast<const float4*>(statsA + kD + k0 + 4);
      float4 ga0 = *reinterpret_cast<const float4*>(gamA + k0);
      float4 ga1 = *reinterpret_cast<const float4*>(gamA + k0 + 4);
      float4 be0 = *reinterpret_cast<const float4*>(betA + k0);
      float4 be1 = *reinterpret_cast<const float4*>(betA + k0 + 4);
      bnmake(su0.x, sq0.x, ga0.x, be0.x, sc0.x, sh0.x);
      bnmake(su0.y, sq0.y, ga0.y, be0.y, sc0.y, sh0.y);
      bnmake(su0.z, sq0.z, ga0.z, be0.z, sc0.z, sh0.z);
      bnmake(su0.w, sq0.w, ga0.w, be0.w, sc0.w, sh0.w);
      bnmake(su1.x, sq1.x, ga1.x, be1.x, sc1.x, sh1.x);
      bnmake(su1.y, sq1.y, ga1.y, be1.y, sc1.y, sh1.y);
      bnmake(su1.z, sq1.z, ga1.z, be1.z, sc1.z, sh1.z);
      bnmake(su1.w, sq1.w, ga1.w, be1.w, sc1.w, sh1.w);
    }
#pragma unroll
    for (int i = 0; i < 8; ++i) {
      int grow = row0 + rlow + 16 * i;
      short8 u = (short8)0;
      if (grow < kN) {
        u = *reinterpret_cast<const short8*>(A16 + (size_t)grow * kD + k0);
        if (statsA != nullptr) {
          float4 v0, v1;
          v0.x = bf2f((unsigned short)u[0]); v0.y = bf2f((unsigned short)u[1]);
          v0.z = bf2f((unsigned short)u[2]); v0.w = bf2f((unsigned short)u[3]);
          v1.x = bf2f((unsigned short)u[4]); v1.y = bf2f((unsigned short)u[5]);
          v1.z = bf2f((unsigned short)u[6]); v1.w = bf2f((unsigned short)u[7]);
          v0 = bnrelu4(v0, sc0, sh0);
          v1 = bnrelu4(v1, sc1, sh1);
          u[0] = (short)f2bf(v0.x); u[1] = (short)f2bf(v0.y);
          u[2] = (short)f2bf(v0.z); u[3] = (short)f2bf(v0.w);
          u[4] = (short)f2bf(v1.x); u[5] = (short)f2bf(v1.y);
          u[6] = (short)f2bf(v1.z); u[7] = (short)f2bf(v1.w);
        }
      }
      int frag = i * 4 + kb;
      *reinterpret_cast<short8*>(&sm.af[((size_t)frag * 64 + lif) * 8]) = u;
    }
  }
  __syncthreads();

  f32x4 acc[8][2];
#pragma unroll
  for (int rb = 0; rb < 8; ++rb) {
    acc[rb][0] = (f32x4){0.f, 0.f, 0.f, 0.f};
    acc[rb][1] = (f32x4){0.f, 0.f, 0.f, 0.f};
  }
#pragma unroll
  for (int kb = 0; kb < 4; ++kb) {
    short8 afr[8];
#pragma unroll
    for (int rb = 0; rb < 8; ++rb)
      afr[rb] = *reinterpret_cast<const short8*>(
          &sm.af[((size_t)(rb * 4 + kb) * 64 + lane) * 8]);
#pragma unroll
    for (int rb = 0; rb < 8; ++rb) {
      acc[rb][0] = __builtin_amdgcn_mfma_f32_16x16x32_bf16(afr[rb], bfr[kb][0],
                                                           acc[rb][0], 0, 0, 0);
      acc[rb][1] = __builtin_amdgcn_mfma_f32_16x16x32_bf16(afr[rb], bfr[kb][1],
                                                           acc[rb][1], 0, 0, 0);
    }
  }

  const int col4 = tid & 31;
  const int rowg = tid >> 5;
  float4 b4 = reinterpret_cast<const float4*>(bias)[col4];
  float4 ss = make_float4(0.f, 0.f, 0.f, 0.f);
  float4 qq = make_float4(0.f, 0.f, 0.f, 0.f);

#pragma unroll
  for (int p = 0; p < 2; ++p) {
    __syncthreads();
#pragma unroll
    for (int rb4 = 0; rb4 < 4; ++rb4) {
      int rb = p * 4 + rb4;
#pragma unroll
      for (int c = 0; c < 2; ++c) {
#pragma unroll
        for (int j = 0; j < 4; ++j) {
          sm.epi[(size_t)(rb4 * 16 + (lane >> 4) * 4 + j) * 132 +
                 w * 32 + c * 16 + (lane & 15)] = acc[rb][c][j];
        }
      }
    }
    __syncthreads();
#pragma unroll
    for (int i = 0; i < 8; ++i) {
      int lrow = rowg * 8 + i;
      int grow = row0 + p * 64 + lrow;
      float4 v = *reinterpret_cast<float4*>(&sm.epi[(size_t)lrow * 132 + col4 * 4]);
      acc4(v, b4);
      if (grow < kN) {
        uint2 pk;
        pk.x = f2bf(v.x) | (f2bf(v.y) << 16);
        pk.y = f2bf(v.z) | (f2bf(v.w) << 16);
        *reinterpret_cast<uint2*>(Y16 + (size_t)grow * kD + col4 * 4) = pk;
        acc4(ss, v);
        accsq4(qq, v);
      }
    }
  }

  __syncthreads();
  *reinterpret_cast<float4*>(&sm.epi[(size_t)rowg * 128 + col4 * 4]) = ss;
  *reinterpret_cast<float4*>(&sm.epi[1024 + (size_t)rowg * 128 + col4 * 4]) = qq;
  __syncthreads();
  if (tid < kD) {
    float s = 0.f;
#pragma unroll
    for (int j = 0; j < 8; ++j) s += sm.epi[j * 128 + tid];
    atomicAdd(&s_sum[tid], s);
  } else {
    int c = tid - kD;
    float s = 0.f;
#pragma unroll
    for (int j = 0; j < 8; ++j) s += sm.epi[1024 + j * 128 + c];
    atomicAdd(&s_ss[c], s);
  }
}

// segmented pool over sorted batch; bf16 h, inline BN, fp32 out
__global__ __launch_bounds__(256) void k_pool(
    const unsigned short* __restrict__ h16, const int* __restrict__ gstart,
    const float* __restrict__ stats, const float* __restrict__ gam,
    const float* __restrict__ bet, float* __restrict__ out) {
  const int g = blockIdx.x;
  const int q = threadIdx.x & 31;
  const int r = threadIdx.x >> 5;
  const int s = gstart[g], e = gstart[g + 1];
  float4 sc, sh;
  {
    int c = q * 4;
    bnmake(stats[c + 0], stats[kD + c + 0], gam[c + 0], bet[c + 0], sc.x, sh.x);
    bnmake(stats[c + 1], stats[kD + c + 1], gam[c + 1], bet[c + 1], sc.y, sh.y);
    bnmake(stats[c + 2], stats[kD + c + 2], gam[c + 2], bet[c + 2], sc.z, sh.z);
    bnmake(stats[c + 3], stats[kD + c + 3], gam[c + 3], bet[c + 3], sc.w, sh.w);
  }
  float4 acc = make_float4(0.f, 0.f, 0.f, 0.f);
  for (int n = s + r; n < e; n += 8) {
    uint2 u = *reinterpret_cast<const uint2*>(h16 + (size_t)n * kD + q * 4);
    float4 v;
    v.x = bf2f(u.x & 0xFFFFu);
    v.y = __uint_as_float(u.x & 0xFFFF0000u);
    v.z = bf2f(u.y & 0xFFFFu);
    v.w = __uint_as_float(u.y & 0xFFFF0000u);
    acc4(acc, bnrelu4(v, sc, sh));
  }
  __shared__ float4 red[8][32];
  red[r][q] = acc;
  __syncthreads();
  if (r == 0) {
    float4 t = acc;
#pragma unroll
    for (int j = 1; j < 8; ++j) acc4(t, red[j][q]);
    reinterpret_cast<float4*>(out)[(size_t)g * 32 + q] = t;
  }
}

extern "C" void kernel_launch(void* const* d_in, const int* in_sizes, int n_in,
                              void* d_out, int out_size, void* d_ws, size_t ws_size,
                              hipStream_t stream) {
  const float* x   = (const float*)d_in[0];
  const int*   ei  = (const int*)d_in[1];
  const int*   bat = (const int*)d_in[2];
  const float* W1  = (const float*)d_in[3];
  const float* b1  = (const float*)d_in[4];
  const float* g1  = (const float*)d_in[5];
  const float* be1 = (const float*)d_in[6];
  const float* W2  = (const float*)d_in[7];
  const float* b2  = (const float*)d_in[8];
  const float* g2  = (const float*)d_in[9];
  const float* be2 = (const float*)d_in[10];
  float* out = (float*)d_out;

  char* p = (char*)d_ws;
  float* wsf = (float*)p;                       p += 16384;
  unsigned short* x16 = (unsigned short*)p;     p += (size_t)kN * kD * 2;
  unsigned short* bufA = (unsigned short*)p;    p += (size_t)kN * kD * 2;
  unsigned short* bufB = (unsigned short*)p;    p += (size_t)kN * kD * 2;
  unsigned short* Wf1 = (unsigned short*)p;     p += (size_t)kL * kD * kD * 2;
  unsigned short* Wf2 = (unsigned short*)p;     p += (size_t)kL * kD * kD * 2;
  int* rowptr = (int*)p;                        p += (kN + 2) * 4;
  int* bcur = (int*)p;                          p += (kNBuk + 1) * 4;
  int* gstart = (int*)p;                        p += (kB + 2) * 4;
  unsigned int* pairs = (unsigned int*)p;       p += (size_t)kE * 4;
  int* srcs = (int*)p;                          p += (size_t)kE * 4;

  (void)hipMemsetAsync(wsf, 0, 6 * 512 * sizeof(float), stream);
  (void)hipMemsetAsync(rowptr, 0, (kN + 1) * sizeof(int), stream);

  // layer-invariant preprocessing
  k_hist<<<(kE + 255) / 256, 256, 0, stream>>>(ei, rowptr);
  k_bounds<<<(kN + 256) / 256, 256, 0, stream>>>(bat, gstart);
  k_xconv<<<(kN * kD / 8 + 255) / 256, 256, 0, stream>>>(x, x16);
  k_wconv<<<(kL * kD * kD + 255) / 256, 256, 0, stream>>>(W1, Wf1, kL);
  k_wconv<<<(kL * kD * kD + 255) / 256, 256, 0, stream>>>(W2, Wf2, kL);
  k_scan<<<1, 1024, 0, stream>>>(rowptr, kN + 1);
  k_bcur<<<(kNBuk + 255) / 256, 256, 0, stream>>>(rowptr, bcur);
  k_binpairs<<<kNBinBlk, 256, 0, stream>>>(ei, bcur, pairs);
  k_csrfill<<<kNBuk, 256, 0, stream>>>(pairs, rowptr, srcs);

  const unsigned short* curH = x16;
  const float* curStats = nullptr;
  const float* curGam = nullptr;
  const float* curBet = nullptr;
  const int ngemm = (kN + 127) / 128;

  unsigned short* aggBuf = bufA;
  unsigned short* yBuf = bufB;

  for (int l = 0; l < kL; ++l) {
    if (curStats == nullptr)
      k_gather<false><<<kN / 4, 256, 0, stream>>>(
          (const unsigned int*)curH, rowptr, srcs, nullptr, nullptr, nullptr,
          (unsigned int*)aggBuf);
    else
      k_gather<true><<<kN / 4, 256, 0, stream>>>(
          (const unsigned int*)curH, rowptr, srcs, curStats, curGam, curBet,
          (unsigned int*)aggBuf);

    float* st1 = wsf + (size_t)(l * 2 + 0) * 512;
    k_gemm<<<ngemm, 256, 0, stream>>>(aggBuf, Wf1 + (size_t)l * kD * kD,
                                      b1 + l * kD, nullptr, nullptr, nullptr,
                                      yBuf, st1, st1 + kD);

    float* st2 = wsf + (size_t)(l * 2 + 1) * 512;
    k_gemm<<<ngemm, 256, 0, stream>>>(yBuf, Wf2 + (size_t)l * kD * kD,
                                      b2 + l * kD, st1, g1 + l * kD, be1 + l * kD,
                                      aggBuf, st2, st2 + kD);

    curH = aggBuf;
    curStats = st2;
    curGam = g2 + l * kD;
    curBet = be2 + l * kD;
    unsigned short* tmp = aggBuf;
    aggBuf = yBuf;
    yBuf = tmp;
  }

  k_pool<<<kB, 256, 0, stream>>>(curH, gstart, curStats, curGam, curBet, out);
}

// Round 9
// 321.966 us; speedup vs baseline: 13.7966x; 1.1480x over previous
//
#include <hip/hip_runtime.h>

constexpr int kN = 50000;
constexpr int kE = 800000;
constexpr int kD = 128;
constexpr int kB = 256;
constexpr int kL = 3;
constexpr float kEps = 1e-5f;

constexpr int kShift = 7;                          // 128 nodes per bucket
constexpr int kNBuk = (kN + 127) >> 7;             // 391
constexpr int kEPB = 8192;                         // edges per binning block
constexpr int kNBinBlk = (kE + kEPB - 1) / kEPB;   // 98

constexpr int kScanN = kN + 1;                     // 50001
constexpr int kScanGrid = (kScanN + 1023) / 1024;  // 49 (<=64 required)

// merged-prep range offsets
constexpr int kPxc = kN * kD / 8;                  // xconv items (8 elems each)
constexpr int kPhist = kPxc + kE;                  // hist items
constexpr int kPbnd = kPhist + kN + 1;             // bounds items
constexpr int kPw1 = kPbnd + kL * kD * kD;         // W1 conv items
constexpr int kPw2 = kPw1 + kL * kD * kD;          // W2 conv items

typedef __attribute__((ext_vector_type(8))) short short8;
typedef __attribute__((ext_vector_type(4))) float f32x4;

__device__ __forceinline__ float4 bnrelu4(float4 v, float4 sc, float4 sh) {
  float4 r;
  r.x = fmaxf(fmaf(v.x, sc.x, sh.x), 0.f);
  r.y = fmaxf(fmaf(v.y, sc.y, sh.y), 0.f);
  r.z = fmaxf(fmaf(v.z, sc.z, sh.z), 0.f);
  r.w = fmaxf(fmaf(v.w, sc.w, sh.w), 0.f);
  return r;
}

__device__ __forceinline__ void acc4(float4& a, const float4& v) {
  a.x += v.x; a.y += v.y; a.z += v.z; a.w += v.w;
}
__device__ __forceinline__ void accsq4(float4& a, const float4& v) {
  a.x = fmaf(v.x, v.x, a.x); a.y = fmaf(v.y, v.y, a.y);
  a.z = fmaf(v.z, v.z, a.z); a.w = fmaf(v.w, v.w, a.w);
}

// fp32 -> bf16 round-to-nearest-even
__device__ __forceinline__ unsigned int f2bf(float x) {
  unsigned int u = __float_as_uint(x);
  u = u + 0x7FFFu + ((u >> 16) & 1u);
  return u >> 16;
}
__device__ __forceinline__ float bf2f(unsigned int lo16) {
  return __uint_as_float(lo16 << 16);
}

// BN scale/shift from raw stats
__device__ __forceinline__ void bnmake(float su, float sq, float ga, float be,
                                       float& sc, float& sh) {
  float mu = su * (1.f / kN);
  float var = fmaf(-mu, mu, sq * (1.f / kN));
  float s = ga * rsqrtf(var + kEps);
  sc = s;
  sh = fmaf(-mu, s, be);
}

// ---------------- merged preprocessing ----------------
// ranges: [0,kPxc) xconv | [kPxc,kPhist) hist | [kPhist,kPbnd) bounds |
//         [kPbnd,kPw1) wconv W1 | [kPw1,kPw2) wconv W2
__global__ void k_prep(const float* __restrict__ x, const int* __restrict__ ei,
                       const int* __restrict__ bat, const float* __restrict__ W1,
                       const float* __restrict__ W2,
                       unsigned short* __restrict__ x16, int* __restrict__ rowptr,
                       int* __restrict__ gstart, unsigned short* __restrict__ Wf1,
                       unsigned short* __restrict__ Wf2) {
  int idx = blockIdx.x * 256 + threadIdx.x;
  if (idx < kPxc) {
    const float* ap = x + (size_t)idx * 8;
    float4 v0 = *reinterpret_cast<const float4*>(ap);
    float4 v1 = *reinterpret_cast<const float4*>(ap + 4);
    short8 u;
    u[0] = (short)f2bf(v0.x); u[1] = (short)f2bf(v0.y);
    u[2] = (short)f2bf(v0.z); u[3] = (short)f2bf(v0.w);
    u[4] = (short)f2bf(v1.x); u[5] = (short)f2bf(v1.y);
    u[6] = (short)f2bf(v1.z); u[7] = (short)f2bf(v1.w);
    *reinterpret_cast<short8*>(x16 + (size_t)idx * 8) = u;
  } else if (idx < kPhist) {
    int e = idx - kPxc;
    atomicAdd(&rowptr[1 + ei[kE + e]], 1);
  } else if (idx < kPbnd) {
    int n = idx - kPhist;
    int b = (n < kN) ? bat[n] : kB;
    int bp = (n > 0) ? bat[n - 1] : -1;
    for (int g = bp + 1; g <= b; ++g) gstart[g] = n;
  } else if (idx < kPw2) {
    const float* W = (idx < kPw1) ? W1 : W2;
    unsigned short* Wf = (idx < kPw1) ? Wf1 : Wf2;
    int id2 = idx - ((idx < kPw1) ? kPbnd : kPw1);
    int m = id2 & (kD * kD - 1);
    int w = id2 >> 14;
    int k = m >> 7, col = m & 127;
    int kb = k >> 5, cb = col >> 4;
    int lane = (col & 15) + 16 * ((k & 31) >> 3);
    int j = k & 7;
    Wf[(size_t)w * kD * kD + ((size_t)(kb * 8 + cb) * 64 + lane) * 8 + j] =
        (unsigned short)f2bf(W[id2]);
  }
}

// ---------------- multi-block scan ----------------
// A: per-block (1024 elems) inclusive scan in place + block total
__global__ __launch_bounds__(256) void k_scanA(int* __restrict__ data,
                                               int* __restrict__ partial) {
  __shared__ int wsum[4];
  const int tid = threadIdx.x;
  const int lane = tid & 63, wid = tid >> 6;
  const int base = blockIdx.x * 1024 + tid * 4;
  int4 v = make_int4(0, 0, 0, 0);
  if (base + 3 < kScanN) {
    v = *reinterpret_cast<const int4*>(data + base);
  } else if (base < kScanN) {
    v.x = data[base];
    if (base + 1 < kScanN) v.y = data[base + 1];
    if (base + 2 < kScanN) v.z = data[base + 2];
  }
  int s = v.x + v.y + v.z + v.w;
  int inc = s;
#pragma unroll
  for (int off = 1; off < 64; off <<= 1) {
    int t = __shfl_up(inc, off);
    if (lane >= off) inc += t;
  }
  if (lane == 63) wsum[wid] = inc;
  __syncthreads();
  int wpre = 0, total = 0;
#pragma unroll
  for (int k = 0; k < 4; ++k) {
    int t = wsum[k];
    if (k < wid) wpre += t;
    total += t;
  }
  if (tid == 0) partial[blockIdx.x] = total;
  int excl = wpre + inc - s;
  v.x += excl;
  v.y += v.x;
  v.z += v.y;
  v.w += v.z;
  if (base + 3 < kScanN) {
    *reinterpret_cast<int4*>(data + base) = v;
  } else if (base < kScanN) {
    data[base] = v.x;
    if (base + 1 < kScanN) data[base + 1] = v.y;
    if (base + 2 < kScanN) data[base + 2] = v.z;
  }
}

// C: add preceding-block offsets; also emit bucket cursors (CSR region starts)
__global__ __launch_bounds__(256) void k_scanC(int* __restrict__ data,
                                               const int* __restrict__ partial,
                                               int* __restrict__ bcur) {
  const int b = blockIdx.x;
  const int tid = threadIdx.x;
  const int lane = tid & 63;
  int p = (lane < b) ? partial[lane] : 0;  // kScanGrid <= 64
#pragma unroll
  for (int off = 32; off; off >>= 1) p += __shfl_down(p, off);
  const int off0 = __shfl(p, 0);
  const int base = b * 1024 + tid * 4;
  if (base + 3 < kScanN) {
    int4 v = *reinterpret_cast<int4*>(data + base);
    v.x += off0; v.y += off0; v.z += off0; v.w += off0;
    *reinterpret_cast<int4*>(data + base) = v;
    // bucket starts are at idx = bk*128, i.e. tid multiples of 32
    if ((tid & 31) == 0) {
      int bk = b * 8 + (tid >> 5);
      if (bk < kNBuk) bcur[bk] = v.x;
    }
  } else if (base < kScanN) {
    for (int j = 0; j < 4 && base + j < kScanN; ++j) data[base + j] += off0;
  }
}

// bin edges into dst-buckets as packed (dst<<16)|src, block-aggregated
__global__ __launch_bounds__(256) void k_binpairs(
    const int* __restrict__ ei, int* __restrict__ bcur,
    unsigned int* __restrict__ pairs) {
  __shared__ int cnt[kNBuk];
  __shared__ int base[kNBuk];
  const int tid = threadIdx.x;
  const int e0 = blockIdx.x * kEPB;
  for (int t = tid; t < kNBuk; t += 256) cnt[t] = 0;
  __syncthreads();
  unsigned int dr[32];
#pragma unroll
  for (int i = 0; i < 32; ++i) {
    int e = e0 + i * 256 + tid;
    unsigned int v = 0xFFFFFFFFu;
    if (e < kE) {
      int d = ei[kE + e];
      int r = atomicAdd(&cnt[d >> kShift], 1);
      v = ((unsigned int)d << 16) | (unsigned int)r;
    }
    dr[i] = v;
  }
  __syncthreads();
  for (int t = tid; t < kNBuk; t += 256) {
    int c = cnt[t];
    base[t] = (c > 0) ? atomicAdd(&bcur[t], c) : 0;
  }
  __syncthreads();
#pragma unroll
  for (int i = 0; i < 32; ++i) {
    unsigned int v = dr[i];
    if (v == 0xFFFFFFFFu) continue;
    int e = e0 + i * 256 + tid;
    unsigned int s = (unsigned int)ei[e];
    int b = (int)(v >> 16) >> kShift;
    int pos = base[b] + (int)(v & 0xFFFFu);
    pairs[pos] = (v & 0xFFFF0000u) | s;
  }
}

// one block per bucket: scatter srcs within an 8KB block-owned region
__global__ __launch_bounds__(256) void k_csrfill(
    const unsigned int* __restrict__ pairs, const int* __restrict__ rowptr,
    int* __restrict__ srcs) {
  __shared__ int cur[128];
  const int b = blockIdx.x;
  const int tid = threadIdx.x;
  const int n0 = b << kShift;
  if (tid < 128) {
    int n = n0 + tid;
    cur[tid] = (n < kN) ? rowptr[n] : 0;
  }
  __syncthreads();
  const int pbeg = rowptr[n0];
  const int pend = rowptr[min(n0 + 128, kN)];
  for (int p = pbeg + tid; p < pend; p += 256) {
    unsigned int u = pairs[p];
    int local = (int)(u >> 16) - n0;
    int pos = atomicAdd(&cur[local], 1);
    srcs[pos] = (int)(u & 0xFFFFu);
  }
}

// ---------------- aggregation ----------------
template <bool BN>
__global__ __launch_bounds__(256) void k_gather(
    const unsigned int* __restrict__ h16, const int* __restrict__ rowptr,
    const int* __restrict__ srcs, const float* __restrict__ stats,
    const float* __restrict__ gam, const float* __restrict__ bet,
    unsigned int* __restrict__ agg16) {
  const int node = blockIdx.x * 4 + (threadIdx.x >> 6);
  const int lane = threadIdx.x & 63;
  float scx, scy, shx, shy;
  if (BN) {
    int c = lane * 2;
    bnmake(stats[c], stats[kD + c], gam[c], bet[c], scx, shx);
    bnmake(stats[c + 1], stats[kD + c + 1], gam[c + 1], bet[c + 1], scy, shy);
  }
  unsigned int u = h16[(size_t)node * 64 + lane];
  float ax = bf2f(u & 0xFFFFu), ay = __uint_as_float(u & 0xFFFF0000u);
  if (BN) {
    ax = fmaxf(fmaf(ax, scx, shx), 0.f);
    ay = fmaxf(fmaf(ay, scy, shy), 0.f);
  }
  const int beg = __builtin_amdgcn_readfirstlane(rowptr[node]);
  const int end = __builtin_amdgcn_readfirstlane(rowptr[node + 1]);
  int j = beg;
  for (; j + 4 <= end; j += 4) {
    int s0 = srcs[j + 0];
    int s1 = srcs[j + 1];
    int s2 = srcs[j + 2];
    int s3 = srcs[j + 3];
    unsigned int v0 = h16[(size_t)s0 * 64 + lane];
    unsigned int v1 = h16[(size_t)s1 * 64 + lane];
    unsigned int v2 = h16[(size_t)s2 * 64 + lane];
    unsigned int v3 = h16[(size_t)s3 * 64 + lane];
    float x0 = bf2f(v0 & 0xFFFFu), y0 = __uint_as_float(v0 & 0xFFFF0000u);
    float x1 = bf2f(v1 & 0xFFFFu), y1 = __uint_as_float(v1 & 0xFFFF0000u);
    float x2 = bf2f(v2 & 0xFFFFu), y2 = __uint_as_float(v2 & 0xFFFF0000u);
    float x3 = bf2f(v3 & 0xFFFFu), y3 = __uint_as_float(v3 & 0xFFFF0000u);
    if (BN) {
      x0 = fmaxf(fmaf(x0, scx, shx), 0.f); y0 = fmaxf(fmaf(y0, scy, shy), 0.f);
      x1 = fmaxf(fmaf(x1, scx, shx), 0.f); y1 = fmaxf(fmaf(y1, scy, shy), 0.f);
      x2 = fmaxf(fmaf(x2, scx, shx), 0.f); y2 = fmaxf(fmaf(y2, scy, shy), 0.f);
      x3 = fmaxf(fmaf(x3, scx, shx), 0.f); y3 = fmaxf(fmaf(y3, scy, shy), 0.f);
    }
    ax += (x0 + x1) + (x2 + x3);
    ay += (y0 + y1) + (y2 + y3);
  }
  for (; j < end; ++j) {
    int s = srcs[j];
    unsigned int v = h16[(size_t)s * 64 + lane];
    float vx = bf2f(v & 0xFFFFu), vy = __uint_as_float(v & 0xFFFF0000u);
    if (BN) {
      vx = fmaxf(fmaf(vx, scx, shx), 0.f);
      vy = fmaxf(fmaf(vy, scy, shy), 0.f);
    }
    ax += vx;
    ay += vy;
  }
  agg16[(size_t)node * 64 + lane] = f2bf(ax) | (f2bf(ay) << 16);
}

// ---------------- MFMA GEMM + BN-stats ----------------
__global__ __launch_bounds__(256) void k_gemm(
    const unsigned short* __restrict__ A16, const unsigned short* __restrict__ Wf,
    const float* __restrict__ bias, const float* __restrict__ statsA,
    const float* __restrict__ gamA, const float* __restrict__ betA,
    unsigned short* __restrict__ Y16,
    float* __restrict__ s_sum, float* __restrict__ s_ss) {
  union SMem {
    unsigned short af[32 * 64 * 8];
    float epi[64 * 132];
  };
  __shared__ SMem sm;

  const int tid = threadIdx.x;
  const int w = tid >> 6;
  const int lane = tid & 63;
  const int row0 = blockIdx.x * 128;

  short8 bfr[4][2];
#pragma unroll
  for (int kb = 0; kb < 4; ++kb)
#pragma unroll
    for (int c = 0; c < 2; ++c)
      bfr[kb][c] = *reinterpret_cast<const short8*>(
          Wf + ((size_t)(kb * 8 + (2 * w + c)) * 64 + lane) * 8);

  {
    const int rlow = tid >> 4;
    const int k0 = (tid & 15) * 8;
    const int kb = k0 >> 5;
    const int lif = rlow + 16 * ((k0 & 31) >> 3);
    float4 sc0, sc1, sh0, sh1;
    if (statsA != nullptr) {
      float4 su0 = *reinterpret_cast<const float4*>(statsA + k0);
      float4 su1 = *reinterpret_cast<const float4*>(statsA + k0 + 4);
      float4 sq0 = *reinterpret_cast<const float4*>(statsA + kD + k0);
      float4 sq1 = *reinterpret_cast<const float4*>(statsA + kD + k0 + 4);
      float4 ga0 = *reinterpret_cast<const float4*>(gamA + k0);
      float4 ga1 = *reinterpret_cast<const float4*>(gamA + k0 + 4);
      float4 be0 = *reinterpret_cast<const float4*>(betA + k0);
      float4 be1 = *reinterpret_cast<const float4*>(betA + k0 + 4);
      bnmake(su0.x, sq0.x, ga0.x, be0.x, sc0.x, sh0.x);
      bnmake(su0.y, sq0.y, ga0.y, be0.y, sc0.y, sh0.y);
      bnmake(su0.z, sq0.z, ga0.z, be0.z, sc0.z, sh0.z);
      bnmake(su0.w, sq0.w, ga0.w, be0.w, sc0.w, sh0.w);
      bnmake(su1.x, sq1.x, ga1.x, be1.x, sc1.x, sh1.x);
      bnmake(su1.y, sq1.y, ga1.y, be1.y, sc1.y, sh1.y);
      bnmake(su1.z, sq1.z, ga1.z, be1.z, sc1.z, sh1.z);
      bnmake(su1.w, sq1.w, ga1.w, be1.w, sc1.w, sh1.w);
    }
#pragma unroll
    for (int i = 0; i < 8; ++i) {
      int grow = row0 + rlow + 16 * i;
      short8 u = (short8)0;
      if (grow < kN) {
        u = *reinterpret_cast<const short8*>(A16 + (size_t)grow * kD + k0);
        if (statsA != nullptr) {
          float4 v0, v1;
          v0.x = bf2f((unsigned short)u[0]); v0.y = bf2f((unsigned short)u[1]);
          v0.z = bf2f((unsigned short)u[2]); v0.w = bf2f((unsigned short)u[3]);
          v1.x = bf2f((unsigned short)u[4]); v1.y = bf2f((unsigned short)u[5]);
          v1.z = bf2f((unsigned short)u[6]); v1.w = bf2f((unsigned short)u[7]);
          v0 = bnrelu4(v0, sc0, sh0);
          v1 = bnrelu4(v1, sc1, sh1);
          u[0] = (short)f2bf(v0.x); u[1] = (short)f2bf(v0.y);
          u[2] = (short)f2bf(v0.z); u[3] = (short)f2bf(v0.w);
          u[4] = (short)f2bf(v1.x); u[5] = (short)f2bf(v1.y);
          u[6] = (short)f2bf(v1.z); u[7] = (short)f2bf(v1.w);
        }
      }
      int frag = i * 4 + kb;
      *reinterpret_cast<short8*>(&sm.af[((size_t)frag * 64 + lif) * 8]) = u;
    }
  }
  __syncthreads();

  f32x4 acc[8][2];
#pragma unroll
  for (int rb = 0; rb < 8; ++rb) {
    acc[rb][0] = (f32x4){0.f, 0.f, 0.f, 0.f};
    acc[rb][1] = (f32x4){0.f, 0.f, 0.f, 0.f};
  }
#pragma unroll
  for (int kb = 0; kb < 4; ++kb) {
    short8 afr[8];
#pragma unroll
    for (int rb = 0; rb < 8; ++rb)
      afr[rb] = *reinterpret_cast<const short8*>(
          &sm.af[((size_t)(rb * 4 + kb) * 64 + lane) * 8]);
#pragma unroll
    for (int rb = 0; rb < 8; ++rb) {
      acc[rb][0] = __builtin_amdgcn_mfma_f32_16x16x32_bf16(afr[rb], bfr[kb][0],
                                                           acc[rb][0], 0, 0, 0);
      acc[rb][1] = __builtin_amdgcn_mfma_f32_16x16x32_bf16(afr[rb], bfr[kb][1],
                                                           acc[rb][1], 0, 0, 0);
    }
  }

  const int col4 = tid & 31;
  const int rowg = tid >> 5;
  float4 b4 = reinterpret_cast<const float4*>(bias)[col4];
  float4 ss = make_float4(0.f, 0.f, 0.f, 0.f);
  float4 qq = make_float4(0.f, 0.f, 0.f, 0.f);

#pragma unroll
  for (int p = 0; p < 2; ++p) {
    __syncthreads();
#pragma unroll
    for (int rb4 = 0; rb4 < 4; ++rb4) {
      int rb = p * 4 + rb4;
#pragma unroll
      for (int c = 0; c < 2; ++c) {
#pragma unroll
        for (int j = 0; j < 4; ++j) {
          sm.epi[(size_t)(rb4 * 16 + (lane >> 4) * 4 + j) * 132 +
                 w * 32 + c * 16 + (lane & 15)] = acc[rb][c][j];
        }
      }
    }
    __syncthreads();
#pragma unroll
    for (int i = 0; i < 8; ++i) {
      int lrow = rowg * 8 + i;
      int grow = row0 + p * 64 + lrow;
      float4 v = *reinterpret_cast<float4*>(&sm.epi[(size_t)lrow * 132 + col4 * 4]);
      acc4(v, b4);
      if (grow < kN) {
        uint2 pk;
        pk.x = f2bf(v.x) | (f2bf(v.y) << 16);
        pk.y = f2bf(v.z) | (f2bf(v.w) << 16);
        *reinterpret_cast<uint2*>(Y16 + (size_t)grow * kD + col4 * 4) = pk;
        acc4(ss, v);
        accsq4(qq, v);
      }
    }
  }

  __syncthreads();
  *reinterpret_cast<float4*>(&sm.epi[(size_t)rowg * 128 + col4 * 4]) = ss;
  *reinterpret_cast<float4*>(&sm.epi[1024 + (size_t)rowg * 128 + col4 * 4]) = qq;
  __syncthreads();
  if (tid < kD) {
    float s = 0.f;
#pragma unroll
    for (int j = 0; j < 8; ++j) s += sm.epi[j * 128 + tid];
    atomicAdd(&s_sum[tid], s);
  } else {
    int c = tid - kD;
    float s = 0.f;
#pragma unroll
    for (int j = 0; j < 8; ++j) s += sm.epi[1024 + j * 128 + c];
    atomicAdd(&s_ss[c], s);
  }
}

// segmented pool over sorted batch; bf16 h, inline BN, fp32 out
__global__ __launch_bounds__(256) void k_pool(
    const unsigned short* __restrict__ h16, const int* __restrict__ gstart,
    const float* __restrict__ stats, const float* __restrict__ gam,
    const float* __restrict__ bet, float* __restrict__ out) {
  const int g = blockIdx.x;
  const int q = threadIdx.x & 31;
  const int r = threadIdx.x >> 5;
  const int s = gstart[g], e = gstart[g + 1];
  float4 sc, sh;
  {
    int c = q * 4;
    bnmake(stats[c + 0], stats[kD + c + 0], gam[c + 0], bet[c + 0], sc.x, sh.x);
    bnmake(stats[c + 1], stats[kD + c + 1], gam[c + 1], bet[c + 1], sc.y, sh.y);
    bnmake(stats[c + 2], stats[kD + c + 2], gam[c + 2], bet[c + 2], sc.z, sh.z);
    bnmake(stats[c + 3], stats[kD + c + 3], gam[c + 3], bet[c + 3], sc.w, sh.w);
  }
  float4 acc = make_float4(0.f, 0.f, 0.f, 0.f);
  for (int n = s + r; n < e; n += 8) {
    uint2 u = *reinterpret_cast<const uint2*>(h16 + (size_t)n * kD + q * 4);
    float4 v;
    v.x = bf2f(u.x & 0xFFFFu);
    v.y = __uint_as_float(u.x & 0xFFFF0000u);
    v.z = bf2f(u.y & 0xFFFFu);
    v.w = __uint_as_float(u.y & 0xFFFF0000u);
    acc4(acc, bnrelu4(v, sc, sh));
  }
  __shared__ float4 red[8][32];
  red[r][q] = acc;
  __syncthreads();
  if (r == 0) {
    float4 t = acc;
#pragma unroll
    for (int j = 1; j < 8; ++j) acc4(t, red[j][q]);
    reinterpret_cast<float4*>(out)[(size_t)g * 32 + q] = t;
  }
}

extern "C" void kernel_launch(void* const* d_in, const int* in_sizes, int n_in,
                              void* d_out, int out_size, void* d_ws, size_t ws_size,
                              hipStream_t stream) {
  const float* x   = (const float*)d_in[0];
  const int*   ei  = (const int*)d_in[1];
  const int*   bat = (const int*)d_in[2];
  const float* W1  = (const float*)d_in[3];
  const float* b1  = (const float*)d_in[4];
  const float* g1  = (const float*)d_in[5];
  const float* be1 = (const float*)d_in[6];
  const float* W2  = (const float*)d_in[7];
  const float* b2  = (const float*)d_in[8];
  const float* g2  = (const float*)d_in[9];
  const float* be2 = (const float*)d_in[10];
  float* out = (float*)d_out;

  char* p = (char*)d_ws;
  float* wsf = (float*)p;                       p += 16384;
  unsigned short* x16 = (unsigned short*)p;     p += (size_t)kN * kD * 2;
  unsigned short* bufA = (unsigned short*)p;    p += (size_t)kN * kD * 2;
  unsigned short* bufB = (unsigned short*)p;    p += (size_t)kN * kD * 2;
  unsigned short* Wf1 = (unsigned short*)p;     p += (size_t)kL * kD * kD * 2;
  unsigned short* Wf2 = (unsigned short*)p;     p += (size_t)kL * kD * kD * 2;
  int* rowptr = (int*)p;                        p += (kN + 2) * 4;     // 16B-aligned
  int* bcur = (int*)p;                          p += (kNBuk + 1) * 4;
  int* partial = (int*)p;                       p += 64 * 4;
  int* gstart = (int*)p;                        p += (kB + 2) * 4;
  unsigned int* pairs = (unsigned int*)p;       p += (size_t)kE * 4;
  int* srcs = (int*)p;                          p += (size_t)kE * 4;

  (void)hipMemsetAsync(wsf, 0, 6 * 512 * sizeof(float), stream);
  (void)hipMemsetAsync(rowptr, 0, (kN + 1) * sizeof(int), stream);

  // layer-invariant preprocessing (merged) + CSR build
  k_prep<<<(kPw2 + 255) / 256, 256, 0, stream>>>(x, ei, bat, W1, W2, x16, rowptr,
                                                 gstart, Wf1, Wf2);
  k_scanA<<<kScanGrid, 256, 0, stream>>>(rowptr, partial);
  k_scanC<<<kScanGrid, 256, 0, stream>>>(rowptr, partial, bcur);
  k_binpairs<<<kNBinBlk, 256, 0, stream>>>(ei, bcur, pairs);
  k_csrfill<<<kNBuk, 256, 0, stream>>>(pairs, rowptr, srcs);

  const unsigned short* curH = x16;
  const float* curStats = nullptr;
  const float* curGam = nullptr;
  const float* curBet = nullptr;
  const int ngemm = (kN + 127) / 128;

  unsigned short* aggBuf = bufA;
  unsigned short* yBuf = bufB;

  for (int l = 0; l < kL; ++l) {
    if (curStats == nullptr)
      k_gather<false><<<kN / 4, 256, 0, stream>>>(
          (const unsigned int*)curH, rowptr, srcs, nullptr, nullptr, nullptr,
          (unsigned int*)aggBuf);
    else
      k_gather<true><<<kN / 4, 256, 0, stream>>>(
          (const unsigned int*)curH, rowptr, srcs, curStats, curGam, curBet,
          (unsigned int*)aggBuf);

    float* st1 = wsf + (size_t)(l * 2 + 0) * 512;
    k_gemm<<<ngemm, 256, 0, stream>>>(aggBuf, Wf1 + (size_t)l * kD * kD,
                                      b1 + l * kD, nullptr, nullptr, nullptr,
                                      yBuf, st1, st1 + kD);

    float* st2 = wsf + (size_t)(l * 2 + 1) * 512;
    k_gemm<<<ngemm, 256, 0, stream>>>(yBuf, Wf2 + (size_t)l * kD * kD,
                                      b2 + l * kD, st1, g1 + l * kD, be1 + l * kD,
                                      aggBuf, st2, st2 + kD);

    curH = aggBuf;
    curStats = st2;
    curGam = g2 + l * kD;
    curBet = be2 + l * kD;
    unsigned short* tmp = aggBuf;
    aggBuf = yBuf;
    yBuf = tmp;
  }

  k_pool<<<kB, 256, 0, stream>>>(curH, gstart, curStats, curGam, curBet, out);
}

// Round 10
// 321.661 us; speedup vs baseline: 13.8097x; 1.0009x over previous
//
#include <hip/hip_runtime.h>

constexpr int kN = 50000;
constexpr int kE = 800000;
constexpr int kD = 128;
constexpr int kB = 256;
constexpr int kL = 3;
constexpr float kEps = 1e-5f;

constexpr int kShift = 7;                          // 128 nodes per bucket
constexpr int kNBuk = (kN + 127) >> 7;             // 391
constexpr int kEPB = 8192;                         // edges per binning block
constexpr int kNBinBlk = (kE + kEPB - 1) / kEPB;   // 98

constexpr int kScanN = kN + 1;                     // 50001
constexpr int kScanGrid = (kScanN + 1023) / 1024;  // 49 (<=64 required)

// merged-prep range offsets
constexpr int kPxc = kN * kD / 8;                  // xconv items (8 elems each)
constexpr int kPhist = kPxc + kE;                  // hist items
constexpr int kPbnd = kPhist + kN + 1;             // bounds items
constexpr int kPw1 = kPbnd + kL * kD * kD;         // W1 conv items
constexpr int kPw2 = kPw1 + kL * kD * kD;          // W2 conv items

typedef __attribute__((ext_vector_type(8))) short short8;
typedef __attribute__((ext_vector_type(4))) float f32x4;

__device__ __forceinline__ float4 bnrelu4(float4 v, float4 sc, float4 sh) {
  float4 r;
  r.x = fmaxf(fmaf(v.x, sc.x, sh.x), 0.f);
  r.y = fmaxf(fmaf(v.y, sc.y, sh.y), 0.f);
  r.z = fmaxf(fmaf(v.z, sc.z, sh.z), 0.f);
  r.w = fmaxf(fmaf(v.w, sc.w, sh.w), 0.f);
  return r;
}

__device__ __forceinline__ void acc4(float4& a, const float4& v) {
  a.x += v.x; a.y += v.y; a.z += v.z; a.w += v.w;
}
__device__ __forceinline__ void accsq4(float4& a, const float4& v) {
  a.x = fmaf(v.x, v.x, a.x); a.y = fmaf(v.y, v.y, a.y);
  a.z = fmaf(v.z, v.z, a.z); a.w = fmaf(v.w, v.w, a.w);
}

// fp32 -> bf16 round-to-nearest-even
__device__ __forceinline__ unsigned int f2bf(float x) {
  unsigned int u = __float_as_uint(x);
  u = u + 0x7FFFu + ((u >> 16) & 1u);
  return u >> 16;
}
__device__ __forceinline__ float bf2f(unsigned int lo16) {
  return __uint_as_float(lo16 << 16);
}

// BN scale/shift from raw stats
__device__ __forceinline__ void bnmake(float su, float sq, float ga, float be,
                                       float& sc, float& sh) {
  float mu = su * (1.f / kN);
  float var = fmaf(-mu, mu, sq * (1.f / kN));
  float s = ga * rsqrtf(var + kEps);
  sc = s;
  sh = fmaf(-mu, s, be);
}

// ---------------- merged preprocessing ----------------
// ranges: [0,kPxc) xconv | [kPxc,kPhist) hist | [kPhist,kPbnd) bounds |
//         [kPbnd,kPw1) wconv W1 | [kPw1,kPw2) wconv W2
__global__ void k_prep(const float* __restrict__ x, const int* __restrict__ ei,
                       const int* __restrict__ bat, const float* __restrict__ W1,
                       const float* __restrict__ W2,
                       unsigned short* __restrict__ x16, int* __restrict__ rowptr,
                       int* __restrict__ gstart, unsigned short* __restrict__ Wf1,
                       unsigned short* __restrict__ Wf2) {
  int idx = blockIdx.x * 256 + threadIdx.x;
  if (idx < kPxc) {
    const float* ap = x + (size_t)idx * 8;
    float4 v0 = *reinterpret_cast<const float4*>(ap);
    float4 v1 = *reinterpret_cast<const float4*>(ap + 4);
    short8 u;
    u[0] = (short)f2bf(v0.x); u[1] = (short)f2bf(v0.y);
    u[2] = (short)f2bf(v0.z); u[3] = (short)f2bf(v0.w);
    u[4] = (short)f2bf(v1.x); u[5] = (short)f2bf(v1.y);
    u[6] = (short)f2bf(v1.z); u[7] = (short)f2bf(v1.w);
    *reinterpret_cast<short8*>(x16 + (size_t)idx * 8) = u;
  } else if (idx < kPhist) {
    int e = idx - kPxc;
    atomicAdd(&rowptr[1 + ei[kE + e]], 1);
  } else if (idx < kPbnd) {
    int n = idx - kPhist;
    int b = (n < kN) ? bat[n] : kB;
    int bp = (n > 0) ? bat[n - 1] : -1;
    for (int g = bp + 1; g <= b; ++g) gstart[g] = n;
  } else if (idx < kPw2) {
    const float* W = (idx < kPw1) ? W1 : W2;
    unsigned short* Wf = (idx < kPw1) ? Wf1 : Wf2;
    int id2 = idx - ((idx < kPw1) ? kPbnd : kPw1);
    int m = id2 & (kD * kD - 1);
    int w = id2 >> 14;
    int k = m >> 7, col = m & 127;
    int kb = k >> 5, cb = col >> 4;
    int lane = (col & 15) + 16 * ((k & 31) >> 3);
    int j = k & 7;
    Wf[(size_t)w * kD * kD + ((size_t)(kb * 8 + cb) * 64 + lane) * 8 + j] =
        (unsigned short)f2bf(W[id2]);
  }
}

// ---------------- multi-block scan ----------------
// A: per-block (1024 elems) inclusive scan in place + block total
__global__ __launch_bounds__(256) void k_scanA(int* __restrict__ data,
                                               int* __restrict__ partial) {
  __shared__ int wsum[4];
  const int tid = threadIdx.x;
  const int lane = tid & 63, wid = tid >> 6;
  const int base = blockIdx.x * 1024 + tid * 4;
  int4 v = make_int4(0, 0, 0, 0);
  if (base + 3 < kScanN) {
    v = *reinterpret_cast<const int4*>(data + base);
  } else if (base < kScanN) {
    v.x = data[base];
    if (base + 1 < kScanN) v.y = data[base + 1];
    if (base + 2 < kScanN) v.z = data[base + 2];
  }
  int s = v.x + v.y + v.z + v.w;
  int inc = s;
#pragma unroll
  for (int off = 1; off < 64; off <<= 1) {
    int t = __shfl_up(inc, off);
    if (lane >= off) inc += t;
  }
  if (lane == 63) wsum[wid] = inc;
  __syncthreads();
  int wpre = 0, total = 0;
#pragma unroll
  for (int k = 0; k < 4; ++k) {
    int t = wsum[k];
    if (k < wid) wpre += t;
    total += t;
  }
  if (tid == 0) partial[blockIdx.x] = total;
  int excl = wpre + inc - s;
  v.x += excl;
  v.y += v.x;
  v.z += v.y;
  v.w += v.z;
  if (base + 3 < kScanN) {
    *reinterpret_cast<int4*>(data + base) = v;
  } else if (base < kScanN) {
    data[base] = v.x;
    if (base + 1 < kScanN) data[base + 1] = v.y;
    if (base + 2 < kScanN) data[base + 2] = v.z;
  }
}

// C: add preceding-block offsets; also emit bucket cursors (CSR region starts)
__global__ __launch_bounds__(256) void k_scanC(int* __restrict__ data,
                                               const int* __restrict__ partial,
                                               int* __restrict__ bcur) {
  const int b = blockIdx.x;
  const int tid = threadIdx.x;
  const int lane = tid & 63;
  int p = (lane < b) ? partial[lane] : 0;  // kScanGrid <= 64
#pragma unroll
  for (int off = 32; off; off >>= 1) p += __shfl_down(p, off);
  const int off0 = __shfl(p, 0);
  const int base = b * 1024 + tid * 4;
  if (base + 3 < kScanN) {
    int4 v = *reinterpret_cast<int4*>(data + base);
    v.x += off0; v.y += off0; v.z += off0; v.w += off0;
    *reinterpret_cast<int4*>(data + base) = v;
    // bucket starts are at idx = bk*128, i.e. tid multiples of 32
    if ((tid & 31) == 0) {
      int bk = b * 8 + (tid >> 5);
      if (bk < kNBuk) bcur[bk] = v.x;
    }
  } else if (base < kScanN) {
    for (int j = 0; j < 4 && base + j < kScanN; ++j) data[base + j] += off0;
  }
}

// bin edges into dst-buckets as packed (dst<<16)|src, block-aggregated
__global__ __launch_bounds__(256) void k_binpairs(
    const int* __restrict__ ei, int* __restrict__ bcur,
    unsigned int* __restrict__ pairs) {
  __shared__ int cnt[kNBuk];
  __shared__ int base[kNBuk];
  const int tid = threadIdx.x;
  const int e0 = blockIdx.x * kEPB;
  for (int t = tid; t < kNBuk; t += 256) cnt[t] = 0;
  __syncthreads();
  unsigned int dr[32];
#pragma unroll
  for (int i = 0; i < 32; ++i) {
    int e = e0 + i * 256 + tid;
    unsigned int v = 0xFFFFFFFFu;
    if (e < kE) {
      int d = ei[kE + e];
      int r = atomicAdd(&cnt[d >> kShift], 1);
      v = ((unsigned int)d << 16) | (unsigned int)r;
    }
    dr[i] = v;
  }
  __syncthreads();
  for (int t = tid; t < kNBuk; t += 256) {
    int c = cnt[t];
    base[t] = (c > 0) ? atomicAdd(&bcur[t], c) : 0;
  }
  __syncthreads();
#pragma unroll
  for (int i = 0; i < 32; ++i) {
    unsigned int v = dr[i];
    if (v == 0xFFFFFFFFu) continue;
    int e = e0 + i * 256 + tid;
    unsigned int s = (unsigned int)ei[e];
    int b = (int)(v >> 16) >> kShift;
    int pos = base[b] + (int)(v & 0xFFFFu);
    pairs[pos] = (v & 0xFFFF0000u) | s;
  }
}

// one block per bucket: scatter srcs within an 8KB block-owned region
__global__ __launch_bounds__(256) void k_csrfill(
    const unsigned int* __restrict__ pairs, const int* __restrict__ rowptr,
    int* __restrict__ srcs) {
  __shared__ int cur[128];
  const int b = blockIdx.x;
  const int tid = threadIdx.x;
  const int n0 = b << kShift;
  if (tid < 128) {
    int n = n0 + tid;
    cur[tid] = (n < kN) ? rowptr[n] : 0;
  }
  __syncthreads();
  const int pbeg = rowptr[n0];
  const int pend = rowptr[min(n0 + 128, kN)];
  for (int p = pbeg + tid; p < pend; p += 256) {
    unsigned int u = pairs[p];
    int local = (int)(u >> 16) - n0;
    int pos = atomicAdd(&cur[local], 1);
    srcs[pos] = (int)(u & 0xFFFFu);
  }
}

// ---------------- aggregation ----------------
template <bool BN>
__global__ __launch_bounds__(256) void k_gather(
    const unsigned int* __restrict__ h16, const int* __restrict__ rowptr,
    const int* __restrict__ srcs, const float* __restrict__ stats,
    const float* __restrict__ gam, const float* __restrict__ bet,
    unsigned int* __restrict__ agg16) {
  const int node = blockIdx.x * 4 + (threadIdx.x >> 6);
  const int lane = threadIdx.x & 63;
  float scx, scy, shx, shy;
  if (BN) {
    int c = lane * 2;
    bnmake(stats[c], stats[kD + c], gam[c], bet[c], scx, shx);
    bnmake(stats[c + 1], stats[kD + c + 1], gam[c + 1], bet[c + 1], scy, shy);
  }
  unsigned int u = h16[(size_t)node * 64 + lane];
  float ax = bf2f(u & 0xFFFFu), ay = __uint_as_float(u & 0xFFFF0000u);
  if (BN) {
    ax = fmaxf(fmaf(ax, scx, shx), 0.f);
    ay = fmaxf(fmaf(ay, scy, shy), 0.f);
  }
  const int beg = __builtin_amdgcn_readfirstlane(rowptr[node]);
  const int end = __builtin_amdgcn_readfirstlane(rowptr[node + 1]);
  int j = beg;
  for (; j + 4 <= end; j += 4) {
    int s0 = srcs[j + 0];
    int s1 = srcs[j + 1];
    int s2 = srcs[j + 2];
    int s3 = srcs[j + 3];
    unsigned int v0 = h16[(size_t)s0 * 64 + lane];
    unsigned int v1 = h16[(size_t)s1 * 64 + lane];
    unsigned int v2 = h16[(size_t)s2 * 64 + lane];
    unsigned int v3 = h16[(size_t)s3 * 64 + lane];
    float x0 = bf2f(v0 & 0xFFFFu), y0 = __uint_as_float(v0 & 0xFFFF0000u);
    float x1 = bf2f(v1 & 0xFFFFu), y1 = __uint_as_float(v1 & 0xFFFF0000u);
    float x2 = bf2f(v2 & 0xFFFFu), y2 = __uint_as_float(v2 & 0xFFFF0000u);
    float x3 = bf2f(v3 & 0xFFFFu), y3 = __uint_as_float(v3 & 0xFFFF0000u);
    if (BN) {
      x0 = fmaxf(fmaf(x0, scx, shx), 0.f); y0 = fmaxf(fmaf(y0, scy, shy), 0.f);
      x1 = fmaxf(fmaf(x1, scx, shx), 0.f); y1 = fmaxf(fmaf(y1, scy, shy), 0.f);
      x2 = fmaxf(fmaf(x2, scx, shx), 0.f); y2 = fmaxf(fmaf(y2, scy, shy), 0.f);
      x3 = fmaxf(fmaf(x3, scx, shx), 0.f); y3 = fmaxf(fmaf(y3, scy, shy), 0.f);
    }
    ax += (x0 + x1) + (x2 + x3);
    ay += (y0 + y1) + (y2 + y3);
  }
  for (; j < end; ++j) {
    int s = srcs[j];
    unsigned int v = h16[(size_t)s * 64 + lane];
    float vx = bf2f(v & 0xFFFFu), vy = __uint_as_float(v & 0xFFFF0000u);
    if (BN) {
      vx = fmaxf(fmaf(vx, scx, shx), 0.f);
      vy = fmaxf(fmaf(vy, scy, shy), 0.f);
    }
    ax += vx;
    ay += vy;
  }
  agg16[(size_t)node * 64 + lane] = f2bf(ax) | (f2bf(ay) << 16);
}

// ---------------- MFMA GEMM + BN-stats ----------------
__global__ __launch_bounds__(256) void k_gemm(
    const unsigned short* __restrict__ A16, const unsigned short* __restrict__ Wf,
    const float* __restrict__ bias, const float* __restrict__ statsA,
    const float* __restrict__ gamA, const float* __restrict__ betA,
    unsigned short* __restrict__ Y16,
    float* __restrict__ s_sum, float* __restrict__ s_ss) {
  union SMem {
    unsigned short af[32 * 64 * 8];
    float epi[64 * 132];
  };
  __shared__ SMem sm;

  const int tid = threadIdx.x;
  const int w = tid >> 6;
  const int lane = tid & 63;
  const int row0 = blockIdx.x * 128;

  short8 bfr[4][2];
#pragma unroll
  for (int kb = 0; kb < 4; ++kb)
#pragma unroll
    for (int c = 0; c < 2; ++c)
      bfr[kb][c] = *reinterpret_cast<const short8*>(
          Wf + ((size_t)(kb * 8 + (2 * w + c)) * 64 + lane) * 8);

  {
    const int rlow = tid >> 4;
    const int k0 = (tid & 15) * 8;
    const int kb = k0 >> 5;
    const int lif = rlow + 16 * ((k0 & 31) >> 3);
    float4 sc0, sc1, sh0, sh1;
    if (statsA != nullptr) {
      float4 su0 = *reinterpret_cast<const float4*>(statsA + k0);
      float4 su1 = *reinterpret_cast<const float4*>(statsA + k0 + 4);
      float4 sq0 = *reinterpret_cast<const float4*>(statsA + kD + k0);
      float4 sq1 = *reinterpret_cast<const float4*>(statsA + kD + k0 + 4);
      float4 ga0 = *reinterpret_cast<const float4*>(gamA + k0);
      float4 ga1 = *reinterpret_cast<const float4*>(gamA + k0 + 4);
      float4 be0 = *reinterpret_cast<const float4*>(betA + k0);
      float4 be1 = *reinterpret_cast<const float4*>(betA + k0 + 4);
      bnmake(su0.x, sq0.x, ga0.x, be0.x, sc0.x, sh0.x);
      bnmake(su0.y, sq0.y, ga0.y, be0.y, sc0.y, sh0.y);
      bnmake(su0.z, sq0.z, ga0.z, be0.z, sc0.z, sh0.z);
      bnmake(su0.w, sq0.w, ga0.w, be0.w, sc0.w, sh0.w);
      bnmake(su1.x, sq1.x, ga1.x, be1.x, sc1.x, sh1.x);
      bnmake(su1.y, sq1.y, ga1.y, be1.y, sc1.y, sh1.y);
      bnmake(su1.z, sq1.z, ga1.z, be1.z, sc1.z, sh1.z);
      bnmake(su1.w, sq1.w, ga1.w, be1.w, sc1.w, sh1.w);
    }
#pragma unroll
    for (int i = 0; i < 8; ++i) {
      int grow = row0 + rlow + 16 * i;
      short8 u = (short8)0;
      if (grow < kN) {
        u = *reinterpret_cast<const short8*>(A16 + (size_t)grow * kD + k0);
        if (statsA != nullptr) {
          float4 v0, v1;
          v0.x = bf2f((unsigned short)u[0]); v0.y = bf2f((unsigned short)u[1]);
          v0.z = bf2f((unsigned short)u[2]); v0.w = bf2f((unsigned short)u[3]);
          v1.x = bf2f((unsigned short)u[4]); v1.y = bf2f((unsigned short)u[5]);
          v1.z = bf2f((unsigned short)u[6]); v1.w = bf2f((unsigned short)u[7]);
          v0 = bnrelu4(v0, sc0, sh0);
          v1 = bnrelu4(v1, sc1, sh1);
          u[0] = (short)f2bf(v0.x); u[1] = (short)f2bf(v0.y);
          u[2] = (short)f2bf(v0.z); u[3] = (short)f2bf(v0.w);
          u[4] = (short)f2bf(v1.x); u[5] = (short)f2bf(v1.y);
          u[6] = (short)f2bf(v1.z); u[7] = (short)f2bf(v1.w);
        }
      }
      int frag = i * 4 + kb;
      *reinterpret_cast<short8*>(&sm.af[((size_t)frag * 64 + lif) * 8]) = u;
    }
  }
  __syncthreads();

  f32x4 acc[8][2];
#pragma unroll
  for (int rb = 0; rb < 8; ++rb) {
    acc[rb][0] = (f32x4){0.f, 0.f, 0.f, 0.f};
    acc[rb][1] = (f32x4){0.f, 0.f, 0.f, 0.f};
  }
#pragma unroll
  for (int kb = 0; kb < 4; ++kb) {
    short8 afr[8];
#pragma unroll
    for (int rb = 0; rb < 8; ++rb)
      afr[rb] = *reinterpret_cast<const short8*>(
          &sm.af[((size_t)(rb * 4 + kb) * 64 + lane) * 8]);
#pragma unroll
    for (int rb = 0; rb < 8; ++rb) {
      acc[rb][0] = __builtin_amdgcn_mfma_f32_16x16x32_bf16(afr[rb], bfr[kb][0],
                                                           acc[rb][0], 0, 0, 0);
      acc[rb][1] = __builtin_amdgcn_mfma_f32_16x16x32_bf16(afr[rb], bfr[kb][1],
                                                           acc[rb][1], 0, 0, 0);
    }
  }

  const int col4 = tid & 31;
  const int rowg = tid >> 5;
  float4 b4 = reinterpret_cast<const float4*>(bias)[col4];
  float4 ss = make_float4(0.f, 0.f, 0.f, 0.f);
  float4 qq = make_float4(0.f, 0.f, 0.f, 0.f);

#pragma unroll
  for (int p = 0; p < 2; ++p) {
    __syncthreads();
#pragma unroll
    for (int rb4 = 0; rb4 < 4; ++rb4) {
      int rb = p * 4 + rb4;
#pragma unroll
      for (int c = 0; c < 2; ++c) {
#pragma unroll
        for (int j = 0; j < 4; ++j) {
          sm.epi[(size_t)(rb4 * 16 + (lane >> 4) * 4 + j) * 132 +
                 w * 32 + c * 16 + (lane & 15)] = acc[rb][c][j];
        }
      }
    }
    __syncthreads();
#pragma unroll
    for (int i = 0; i < 8; ++i) {
      int lrow = rowg * 8 + i;
      int grow = row0 + p * 64 + lrow;
      float4 v = *reinterpret_cast<float4*>(&sm.epi[(size_t)lrow * 132 + col4 * 4]);
      acc4(v, b4);
      if (grow < kN) {
        uint2 pk;
        pk.x = f2bf(v.x) | (f2bf(v.y) << 16);
        pk.y = f2bf(v.z) | (f2bf(v.w) << 16);
        *reinterpret_cast<uint2*>(Y16 + (size_t)grow * kD + col4 * 4) = pk;
        acc4(ss, v);
        accsq4(qq, v);
      }
    }
  }

  __syncthreads();
  *reinterpret_cast<float4*>(&sm.epi[(size_t)rowg * 128 + col4 * 4]) = ss;
  *reinterpret_cast<float4*>(&sm.epi[1024 + (size_t)rowg * 128 + col4 * 4]) = qq;
  __syncthreads();
  if (tid < kD) {
    float s = 0.f;
#pragma unroll
    for (int j = 0; j < 8; ++j) s += sm.epi[j * 128 + tid];
    atomicAdd(&s_sum[tid], s);
  } else {
    int c = tid - kD;
    float s = 0.f;
#pragma unroll
    for (int j = 0; j < 8; ++j) s += sm.epi[1024 + j * 128 + c];
    atomicAdd(&s_ss[c], s);
  }
}

// segmented pool over sorted batch; bf16 h, inline BN, fp32 out
__global__ __launch_bounds__(256) void k_pool(
    const unsigned short* __restrict__ h16, const int* __restrict__ gstart,
    const float* __restrict__ stats, const float* __restrict__ gam,
    const float* __restrict__ bet, float* __restrict__ out) {
  const int g = blockIdx.x;
  const int q = threadIdx.x & 31;
  const int r = threadIdx.x >> 5;
  const int s = gstart[g], e = gstart[g + 1];
  float4 sc, sh;
  {
    int c = q * 4;
    bnmake(stats[c + 0], stats[kD + c + 0], gam[c + 0], bet[c + 0], sc.x, sh.x);
    bnmake(stats[c + 1], stats[kD + c + 1], gam[c + 1], bet[c + 1], sc.y, sh.y);
    bnmake(stats[c + 2], stats[kD + c + 2], gam[c + 2], bet[c + 2], sc.z, sh.z);
    bnmake(stats[c + 3], stats[kD + c + 3], gam[c + 3], bet[c + 3], sc.w, sh.w);
  }
  float4 acc = make_float4(0.f, 0.f, 0.f, 0.f);
  for (int n = s + r; n < e; n += 8) {
    uint2 u = *reinterpret_cast<const uint2*>(h16 + (size_t)n * kD + q * 4);
    float4 v;
    v.x = bf2f(u.x & 0xFFFFu);
    v.y = __uint_as_float(u.x & 0xFFFF0000u);
    v.z = bf2f(u.y & 0xFFFFu);
    v.w = __uint_as_float(u.y & 0xFFFF0000u);
    acc4(acc, bnrelu4(v, sc, sh));
  }
  __shared__ float4 red[8][32];
  red[r][q] = acc;
  __syncthreads();
  if (r == 0) {
    float4 t = acc;
#pragma unroll
    for (int j = 1; j < 8; ++j) acc4(t, red[j][q]);
    reinterpret_cast<float4*>(out)[(size_t)g * 32 + q] = t;
  }
}

extern "C" void kernel_launch(void* const* d_in, const int* in_sizes, int n_in,
                              void* d_out, int out_size, void* d_ws, size_t ws_size,
                              hipStream_t stream) {
  const float* x   = (const float*)d_in[0];
  const int*   ei  = (const int*)d_in[1];
  const int*   bat = (const int*)d_in[2];
  const float* W1  = (const float*)d_in[3];
  const float* b1  = (const float*)d_in[4];
  const float* g1  = (const float*)d_in[5];
  const float* be1 = (const float*)d_in[6];
  const float* W2  = (const float*)d_in[7];
  const float* b2  = (const float*)d_in[8];
  const float* g2  = (const float*)d_in[9];
  const float* be2 = (const float*)d_in[10];
  float* out = (float*)d_out;

  char* p = (char*)d_ws;
  float* wsf = (float*)p;                       p += 16384;
  unsigned short* x16 = (unsigned short*)p;     p += (size_t)kN * kD * 2;
  unsigned short* bufA = (unsigned short*)p;    p += (size_t)kN * kD * 2;
  unsigned short* bufB = (unsigned short*)p;    p += (size_t)kN * kD * 2;
  unsigned short* Wf1 = (unsigned short*)p;     p += (size_t)kL * kD * kD * 2;
  unsigned short* Wf2 = (unsigned short*)p;     p += (size_t)kL * kD * kD * 2;
  int* rowptr = (int*)p;                        p += (kN + 2) * 4;     // 16B-aligned
  int* bcur = (int*)p;                          p += (kNBuk + 1) * 4;
  int* partial = (int*)p;                       p += 64 * 4;
  int* gstart = (int*)p;                        p += (kB + 2) * 4;
  unsigned int* pairs = (unsigned int*)p;       p += (size_t)kE * 4;
  int* srcs = (int*)p;                          p += (size_t)kE * 4;

  (void)hipMemsetAsync(wsf, 0, 6 * 512 * sizeof(float), stream);
  (void)hipMemsetAsync(rowptr, 0, (kN + 1) * sizeof(int), stream);

  // layer-invariant preprocessing (merged) + CSR build
  k_prep<<<(kPw2 + 255) / 256, 256, 0, stream>>>(x, ei, bat, W1, W2, x16, rowptr,
                                                 gstart, Wf1, Wf2);
  k_scanA<<<kScanGrid, 256, 0, stream>>>(rowptr, partial);
  k_scanC<<<kScanGrid, 256, 0, stream>>>(rowptr, partial, bcur);
  k_binpairs<<<kNBinBlk, 256, 0, stream>>>(ei, bcur, pairs);
  k_csrfill<<<kNBuk, 256, 0, stream>>>(pairs, rowptr, srcs);

  const unsigned short* curH = x16;
  const float* curStats = nullptr;
  const float* curGam = nullptr;
  const float* curBet = nullptr;
  const int ngemm = (kN + 127) / 128;

  unsigned short* aggBuf = bufA;
  unsigned short* yBuf = bufB;

  for (int l = 0; l < kL; ++l) {
    if (curStats == nullptr)
      k_gather<false><<<kN / 4, 256, 0, stream>>>(
          (const unsigned int*)curH, rowptr, srcs, nullptr, nullptr, nullptr,
          (unsigned int*)aggBuf);
    else
      k_gather<true><<<kN / 4, 256, 0, stream>>>(
          (const unsigned int*)curH, rowptr, srcs, curStats, curGam, curBet,
          (unsigned int*)aggBuf);

    float* st1 = wsf + (size_t)(l * 2 + 0) * 512;
    k_gemm<<<ngemm, 256, 0, stream>>>(aggBuf, Wf1 + (size_t)l * kD * kD,
                                      b1 + l * kD, nullptr, nullptr, nullptr,
                                      yBuf, st1, st1 + kD);

    float* st2 = wsf + (size_t)(l * 2 + 1) * 512;
    k_gemm<<<ngemm, 256, 0, stream>>>(yBuf, Wf2 + (size_t)l * kD * kD,
                                      b2 + l * kD, st1, g1 + l * kD, be1 + l * kD,
                                      aggBuf, st2, st2 + kD);

    curH = aggBuf;
    curStats = st2;
    curGam = g2 + l * kD;
    curBet = be2 + l * kD;
    unsigned short* tmp = aggBuf;
    aggBuf = yBuf;
    yBuf = tmp;
  }

  k_pool<<<kB, 256, 0, stream>>>(curH, gstart, curStats, curGam, curBet, out);
}

// Round 11
// 293.603 us; speedup vs baseline: 15.1293x; 1.0956x over previous
//
#include <hip/hip_runtime.h>

constexpr int kN = 50000;
constexpr int kE = 800000;
constexpr int kD = 128;
constexpr int kB = 256;
constexpr int kL = 3;
constexpr float kEps = 1e-5f;

constexpr int kShift = 7;                          // 128 nodes per bucket
constexpr int kNBuk = (kN + 127) >> 7;             // 391
constexpr int kEPB = 8192;                         // edges per binning block
constexpr int kNBinBlk = (kE + kEPB - 1) / kEPB;   // 98

// merged-prep per-thread range offsets (after the kNBinBlk hist blocks)
constexpr int kPxc = kN * kD / 8;                  // 800000 xconv items
constexpr int kPbnd = kPxc + kN + 1;               // 850001 bounds items
constexpr int kPw1 = kPbnd + kL * kD * kD;         // W1 conv
constexpr int kPw2 = kPw1 + kL * kD * kD;          // W2 conv = 948305
constexpr int kPrepThreadBlks = (kPw2 + 255) / 256;

typedef __attribute__((ext_vector_type(8))) short short8;
typedef __attribute__((ext_vector_type(4))) float f32x4;

__device__ __forceinline__ float4 bnrelu4(float4 v, float4 sc, float4 sh) {
  float4 r;
  r.x = fmaxf(fmaf(v.x, sc.x, sh.x), 0.f);
  r.y = fmaxf(fmaf(v.y, sc.y, sh.y), 0.f);
  r.z = fmaxf(fmaf(v.z, sc.z, sh.z), 0.f);
  r.w = fmaxf(fmaf(v.w, sc.w, sh.w), 0.f);
  return r;
}

__device__ __forceinline__ void acc4(float4& a, const float4& v) {
  a.x += v.x; a.y += v.y; a.z += v.z; a.w += v.w;
}
__device__ __forceinline__ void accsq4(float4& a, const float4& v) {
  a.x = fmaf(v.x, v.x, a.x); a.y = fmaf(v.y, v.y, a.y);
  a.z = fmaf(v.z, v.z, a.z); a.w = fmaf(v.w, v.w, a.w);
}

// fp32 -> bf16 round-to-nearest-even
__device__ __forceinline__ unsigned int f2bf(float x) {
  unsigned int u = __float_as_uint(x);
  u = u + 0x7FFFu + ((u >> 16) & 1u);
  return u >> 16;
}
__device__ __forceinline__ float bf2f(unsigned int lo16) {
  return __uint_as_float(lo16 << 16);
}

// BN scale/shift from raw stats
__device__ __forceinline__ void bnmake(float su, float sq, float ga, float be,
                                       float& sc, float& sh) {
  float mu = su * (1.f / kN);
  float var = fmaf(-mu, mu, sq * (1.f / kN));
  float s = ga * rsqrtf(var + kEps);
  sc = s;
  sh = fmaf(-mu, s, be);
}

// ---------------- merged preprocessing ----------------
// blocks [0, kNBinBlk): LDS-aggregated bucket histogram of dst (8192 edges each)
// remaining blocks, per-thread ranges:
//   [0,kPxc) xconv | [kPxc,kPbnd) bounds | [kPbnd,kPw1) W1 conv | [kPw1,kPw2) W2
__global__ __launch_bounds__(256) void k_prep(
    const float* __restrict__ x, const int* __restrict__ ei,
    const int* __restrict__ bat, const float* __restrict__ W1,
    const float* __restrict__ W2, unsigned short* __restrict__ x16,
    int* __restrict__ bhist, int* __restrict__ gstart,
    unsigned short* __restrict__ Wf1, unsigned short* __restrict__ Wf2) {
  __shared__ int cnt[kNBuk];
  if (blockIdx.x < (unsigned)kNBinBlk) {
    const int tid = threadIdx.x;
    const int e0 = blockIdx.x * kEPB;
    for (int t = tid; t < kNBuk; t += 256) cnt[t] = 0;
    __syncthreads();
#pragma unroll
    for (int i = 0; i < 32; ++i) {
      int e = e0 + i * 256 + tid;
      if (e < kE) atomicAdd(&cnt[ei[kE + e] >> kShift], 1);
    }
    __syncthreads();
    for (int t = tid; t < kNBuk; t += 256) {
      int c = cnt[t];
      if (c) atomicAdd(&bhist[t], c);
    }
    return;
  }
  int idx = (blockIdx.x - kNBinBlk) * 256 + threadIdx.x;
  if (idx < kPxc) {
    const float* ap = x + (size_t)idx * 8;
    float4 v0 = *reinterpret_cast<const float4*>(ap);
    float4 v1 = *reinterpret_cast<const float4*>(ap + 4);
    short8 u;
    u[0] = (short)f2bf(v0.x); u[1] = (short)f2bf(v0.y);
    u[2] = (short)f2bf(v0.z); u[3] = (short)f2bf(v0.w);
    u[4] = (short)f2bf(v1.x); u[5] = (short)f2bf(v1.y);
    u[6] = (short)f2bf(v1.z); u[7] = (short)f2bf(v1.w);
    *reinterpret_cast<short8*>(x16 + (size_t)idx * 8) = u;
  } else if (idx < kPbnd) {
    int n = idx - kPxc;
    int b = (n < kN) ? bat[n] : kB;
    int bp = (n > 0) ? bat[n - 1] : -1;
    for (int g = bp + 1; g <= b; ++g) gstart[g] = n;
  } else if (idx < kPw2) {
    const float* W = (idx < kPw1) ? W1 : W2;
    unsigned short* Wf = (idx < kPw1) ? Wf1 : Wf2;
    int id2 = idx - ((idx < kPw1) ? kPbnd : kPw1);
    int m = id2 & (kD * kD - 1);
    int w = id2 >> 14;
    int k = m >> 7, col = m & 127;
    int kb = k >> 5, cb = col >> 4;
    int lane = (col & 15) + 16 * ((k & 31) >> 3);
    int j = k & 7;
    Wf[(size_t)w * kD * kD + ((size_t)(kb * 8 + cb) * 64 + lane) * 8 + j] =
        (unsigned short)f2bf(W[id2]);
  }
}

// single block: exclusive scan of 391 bucket counts -> bstart[0..391], bcur
__global__ __launch_bounds__(512) void k_scanB(const int* __restrict__ bhist,
                                               int* __restrict__ bstart,
                                               int* __restrict__ bcur) {
  __shared__ int wsum[8];
  const int tid = threadIdx.x;
  const int lane = tid & 63, wid = tid >> 6;
  int v = (tid < kNBuk) ? bhist[tid] : 0;
  int inc = v;
#pragma unroll
  for (int off = 1; off < 64; off <<= 1) {
    int t = __shfl_up(inc, off);
    if (lane >= off) inc += t;
  }
  if (lane == 63) wsum[wid] = inc;
  __syncthreads();
  int wpre = 0;
#pragma unroll
  for (int k = 0; k < 8; ++k) {
    int t = wsum[k];
    if (k < wid) wpre += t;
  }
  int excl = wpre + inc - v;
  if (tid <= kNBuk) {
    bstart[tid] = excl;
    if (tid < kNBuk) bcur[tid] = excl;
  }
}

// bin edges into dst-buckets as packed (dst<<16)|src, block-aggregated
__global__ __launch_bounds__(256) void k_binpairs(
    const int* __restrict__ ei, int* __restrict__ bcur,
    unsigned int* __restrict__ pairs) {
  __shared__ int cnt[kNBuk];
  __shared__ int base[kNBuk];
  const int tid = threadIdx.x;
  const int e0 = blockIdx.x * kEPB;
  for (int t = tid; t < kNBuk; t += 256) cnt[t] = 0;
  __syncthreads();
  unsigned int dr[32];
#pragma unroll
  for (int i = 0; i < 32; ++i) {
    int e = e0 + i * 256 + tid;
    unsigned int v = 0xFFFFFFFFu;
    if (e < kE) {
      int d = ei[kE + e];
      int r = atomicAdd(&cnt[d >> kShift], 1);
      v = ((unsigned int)d << 16) | (unsigned int)r;
    }
    dr[i] = v;
  }
  __syncthreads();
  for (int t = tid; t < kNBuk; t += 256) {
    int c = cnt[t];
    base[t] = (c > 0) ? atomicAdd(&bcur[t], c) : 0;
  }
  __syncthreads();
#pragma unroll
  for (int i = 0; i < 32; ++i) {
    unsigned int v = dr[i];
    if (v == 0xFFFFFFFFu) continue;
    int e = e0 + i * 256 + tid;
    unsigned int s = (unsigned int)ei[e];
    int b = (int)(v >> 16) >> kShift;
    int pos = base[b] + (int)(v & 0xFFFFu);
    pairs[pos] = (v & 0xFFFF0000u) | s;
  }
}

// one block per bucket: build rowptr for its 128 nodes (LDS count + scan),
// then scatter srcs within the block-owned region.
__global__ __launch_bounds__(256) void k_csrfill(
    const unsigned int* __restrict__ pairs, const int* __restrict__ bstart,
    int* __restrict__ rowptr, int* __restrict__ srcs) {
  __shared__ int cnt[128];
  __shared__ int cur[128];
  __shared__ int w0tot;
  const int b = blockIdx.x;
  const int tid = threadIdx.x;
  const int n0 = b << kShift;
  const int pb = bstart[b];
  const int pe = bstart[b + 1];
  if (tid < 128) cnt[tid] = 0;
  __syncthreads();
  for (int p = pb + tid; p < pe; p += 256)
    atomicAdd(&cnt[(int)(pairs[p] >> 16) - n0], 1);
  __syncthreads();
  int v = 0, inc = 0;
  if (tid < 128) {
    v = cnt[tid];
    inc = v;
#pragma unroll
    for (int off = 1; off < 64; off <<= 1) {
      int t = __shfl_up(inc, off);
      if ((tid & 63) >= off) inc += t;
    }
    if (tid == 63) w0tot = inc;
  }
  __syncthreads();
  if (tid < 128) {
    int excl = inc - v + ((tid >= 64) ? w0tot : 0);
    int n = n0 + tid;
    if (n <= kN) rowptr[n] = pb + excl;   // n==kN: terminator = pe = kE
    cur[tid] = pb + excl;
  }
  __syncthreads();
  for (int p = pb + tid; p < pe; p += 256) {
    unsigned int u = pairs[p];
    int local = (int)(u >> 16) - n0;
    int pos = atomicAdd(&cur[local], 1);
    srcs[pos] = (int)(u & 0xFFFFu);
  }
}

// ---------------- aggregation ----------------
template <bool BN>
__global__ __launch_bounds__(256) void k_gather(
    const unsigned int* __restrict__ h16, const int* __restrict__ rowptr,
    const int* __restrict__ srcs, const float* __restrict__ stats,
    const float* __restrict__ gam, const float* __restrict__ bet,
    unsigned int* __restrict__ agg16) {
  const int node = blockIdx.x * 4 + (threadIdx.x >> 6);
  const int lane = threadIdx.x & 63;
  float scx, scy, shx, shy;
  if (BN) {
    int c = lane * 2;
    bnmake(stats[c], stats[kD + c], gam[c], bet[c], scx, shx);
    bnmake(stats[c + 1], stats[kD + c + 1], gam[c + 1], bet[c + 1], scy, shy);
  }
  unsigned int u = h16[(size_t)node * 64 + lane];
  float ax = bf2f(u & 0xFFFFu), ay = __uint_as_float(u & 0xFFFF0000u);
  if (BN) {
    ax = fmaxf(fmaf(ax, scx, shx), 0.f);
    ay = fmaxf(fmaf(ay, scy, shy), 0.f);
  }
  const int beg = __builtin_amdgcn_readfirstlane(rowptr[node]);
  const int end = __builtin_amdgcn_readfirstlane(rowptr[node + 1]);
  int j = beg;
  for (; j + 4 <= end; j += 4) {
    int s0 = srcs[j + 0];
    int s1 = srcs[j + 1];
    int s2 = srcs[j + 2];
    int s3 = srcs[j + 3];
    unsigned int v0 = h16[(size_t)s0 * 64 + lane];
    unsigned int v1 = h16[(size_t)s1 * 64 + lane];
    unsigned int v2 = h16[(size_t)s2 * 64 + lane];
    unsigned int v3 = h16[(size_t)s3 * 64 + lane];
    float x0 = bf2f(v0 & 0xFFFFu), y0 = __uint_as_float(v0 & 0xFFFF0000u);
    float x1 = bf2f(v1 & 0xFFFFu), y1 = __uint_as_float(v1 & 0xFFFF0000u);
    float x2 = bf2f(v2 & 0xFFFFu), y2 = __uint_as_float(v2 & 0xFFFF0000u);
    float x3 = bf2f(v3 & 0xFFFFu), y3 = __uint_as_float(v3 & 0xFFFF0000u);
    if (BN) {
      x0 = fmaxf(fmaf(x0, scx, shx), 0.f); y0 = fmaxf(fmaf(y0, scy, shy), 0.f);
      x1 = fmaxf(fmaf(x1, scx, shx), 0.f); y1 = fmaxf(fmaf(y1, scy, shy), 0.f);
      x2 = fmaxf(fmaf(x2, scx, shx), 0.f); y2 = fmaxf(fmaf(y2, scy, shy), 0.f);
      x3 = fmaxf(fmaf(x3, scx, shx), 0.f); y3 = fmaxf(fmaf(y3, scy, shy), 0.f);
    }
    ax += (x0 + x1) + (x2 + x3);
    ay += (y0 + y1) + (y2 + y3);
  }
  for (; j < end; ++j) {
    int s = srcs[j];
    unsigned int v = h16[(size_t)s * 64 + lane];
    float vx = bf2f(v & 0xFFFFu), vy = __uint_as_float(v & 0xFFFF0000u);
    if (BN) {
      vx = fmaxf(fmaf(vx, scx, shx), 0.f);
      vy = fmaxf(fmaf(vy, scy, shy), 0.f);
    }
    ax += vx;
    ay += vy;
  }
  agg16[(size_t)node * 64 + lane] = f2bf(ax) | (f2bf(ay) << 16);
}

// ---------------- MFMA GEMM + BN-stats ----------------
__global__ __launch_bounds__(256) void k_gemm(
    const unsigned short* __restrict__ A16, const unsigned short* __restrict__ Wf,
    const float* __restrict__ bias, const float* __restrict__ statsA,
    const float* __restrict__ gamA, const float* __restrict__ betA,
    unsigned short* __restrict__ Y16,
    float* __restrict__ s_sum, float* __restrict__ s_ss) {
  union SMem {
    unsigned short af[32 * 64 * 8];
    float epi[64 * 132];
  };
  __shared__ SMem sm;

  const int tid = threadIdx.x;
  const int w = tid >> 6;
  const int lane = tid & 63;
  const int row0 = blockIdx.x * 128;

  short8 bfr[4][2];
#pragma unroll
  for (int kb = 0; kb < 4; ++kb)
#pragma unroll
    for (int c = 0; c < 2; ++c)
      bfr[kb][c] = *reinterpret_cast<const short8*>(
          Wf + ((size_t)(kb * 8 + (2 * w + c)) * 64 + lane) * 8);

  {
    const int rlow = tid >> 4;
    const int k0 = (tid & 15) * 8;
    const int kb = k0 >> 5;
    const int lif = rlow + 16 * ((k0 & 31) >> 3);
    float4 sc0, sc1, sh0, sh1;
    if (statsA != nullptr) {
      float4 su0 = *reinterpret_cast<const float4*>(statsA + k0);
      float4 su1 = *reinterpret_cast<const float4*>(statsA + k0 + 4);
      float4 sq0 = *reinterpret_cast<const float4*>(statsA + kD + k0);
      float4 sq1 = *reinterpret_cast<const float4*>(statsA + kD + k0 + 4);
      float4 ga0 = *reinterpret_cast<const float4*>(gamA + k0);
      float4 ga1 = *reinterpret_cast<const float4*>(gamA + k0 + 4);
      float4 be0 = *reinterpret_cast<const float4*>(betA + k0);
      float4 be1 = *reinterpret_cast<const float4*>(betA + k0 + 4);
      bnmake(su0.x, sq0.x, ga0.x, be0.x, sc0.x, sh0.x);
      bnmake(su0.y, sq0.y, ga0.y, be0.y, sc0.y, sh0.y);
      bnmake(su0.z, sq0.z, ga0.z, be0.z, sc0.z, sh0.z);
      bnmake(su0.w, sq0.w, ga0.w, be0.w, sc0.w, sh0.w);
      bnmake(su1.x, sq1.x, ga1.x, be1.x, sc1.x, sh1.x);
      bnmake(su1.y, sq1.y, ga1.y, be1.y, sc1.y, sh1.y);
      bnmake(su1.z, sq1.z, ga1.z, be1.z, sc1.z, sh1.z);
      bnmake(su1.w, sq1.w, ga1.w, be1.w, sc1.w, sh1.w);
    }
#pragma unroll
    for (int i = 0; i < 8; ++i) {
      int grow = row0 + rlow + 16 * i;
      short8 u = (short8)0;
      if (grow < kN) {
        u = *reinterpret_cast<const short8*>(A16 + (size_t)grow * kD + k0);
        if (statsA != nullptr) {
          float4 v0, v1;
          v0.x = bf2f((unsigned short)u[0]); v0.y = bf2f((unsigned short)u[1]);
          v0.z = bf2f((unsigned short)u[2]); v0.w = bf2f((unsigned short)u[3]);
          v1.x = bf2f((unsigned short)u[4]); v1.y = bf2f((unsigned short)u[5]);
          v1.z = bf2f((unsigned short)u[6]); v1.w = bf2f((unsigned short)u[7]);
          v0 = bnrelu4(v0, sc0, sh0);
          v1 = bnrelu4(v1, sc1, sh1);
          u[0] = (short)f2bf(v0.x); u[1] = (short)f2bf(v0.y);
          u[2] = (short)f2bf(v0.z); u[3] = (short)f2bf(v0.w);
          u[4] = (short)f2bf(v1.x); u[5] = (short)f2bf(v1.y);
          u[6] = (short)f2bf(v1.z); u[7] = (short)f2bf(v1.w);
        }
      }
      int frag = i * 4 + kb;
      *reinterpret_cast<short8*>(&sm.af[((size_t)frag * 64 + lif) * 8]) = u;
    }
  }
  __syncthreads();

  f32x4 acc[8][2];
#pragma unroll
  for (int rb = 0; rb < 8; ++rb) {
    acc[rb][0] = (f32x4){0.f, 0.f, 0.f, 0.f};
    acc[rb][1] = (f32x4){0.f, 0.f, 0.f, 0.f};
  }
#pragma unroll
  for (int kb = 0; kb < 4; ++kb) {
    short8 afr[8];
#pragma unroll
    for (int rb = 0; rb < 8; ++rb)
      afr[rb] = *reinterpret_cast<const short8*>(
          &sm.af[((size_t)(rb * 4 + kb) * 64 + lane) * 8]);
#pragma unroll
    for (int rb = 0; rb < 8; ++rb) {
      acc[rb][0] = __builtin_amdgcn_mfma_f32_16x16x32_bf16(afr[rb], bfr[kb][0],
                                                           acc[rb][0], 0, 0, 0);
      acc[rb][1] = __builtin_amdgcn_mfma_f32_16x16x32_bf16(afr[rb], bfr[kb][1],
                                                           acc[rb][1], 0, 0, 0);
    }
  }

  const int col4 = tid & 31;
  const int rowg = tid >> 5;
  float4 b4 = reinterpret_cast<const float4*>(bias)[col4];
  float4 ss = make_float4(0.f, 0.f, 0.f, 0.f);
  float4 qq = make_float4(0.f, 0.f, 0.f, 0.f);

#pragma unroll
  for (int p = 0; p < 2; ++p) {
    __syncthreads();
#pragma unroll
    for (int rb4 = 0; rb4 < 4; ++rb4) {
      int rb = p * 4 + rb4;
#pragma unroll
      for (int c = 0; c < 2; ++c) {
#pragma unroll
        for (int j = 0; j < 4; ++j) {
          sm.epi[(size_t)(rb4 * 16 + (lane >> 4) * 4 + j) * 132 +
                 w * 32 + c * 16 + (lane & 15)] = acc[rb][c][j];
        }
      }
    }
    __syncthreads();
#pragma unroll
    for (int i = 0; i < 8; ++i) {
      int lrow = rowg * 8 + i;
      int grow = row0 + p * 64 + lrow;
      float4 v = *reinterpret_cast<float4*>(&sm.epi[(size_t)lrow * 132 + col4 * 4]);
      acc4(v, b4);
      if (grow < kN) {
        uint2 pk;
        pk.x = f2bf(v.x) | (f2bf(v.y) << 16);
        pk.y = f2bf(v.z) | (f2bf(v.w) << 16);
        *reinterpret_cast<uint2*>(Y16 + (size_t)grow * kD + col4 * 4) = pk;
        acc4(ss, v);
        accsq4(qq, v);
      }
    }
  }

  __syncthreads();
  *reinterpret_cast<float4*>(&sm.epi[(size_t)rowg * 128 + col4 * 4]) = ss;
  *reinterpret_cast<float4*>(&sm.epi[1024 + (size_t)rowg * 128 + col4 * 4]) = qq;
  __syncthreads();
  if (tid < kD) {
    float s = 0.f;
#pragma unroll
    for (int j = 0; j < 8; ++j) s += sm.epi[j * 128 + tid];
    atomicAdd(&s_sum[tid], s);
  } else {
    int c = tid - kD;
    float s = 0.f;
#pragma unroll
    for (int j = 0; j < 8; ++j) s += sm.epi[1024 + j * 128 + c];
    atomicAdd(&s_ss[c], s);
  }
}

// segmented pool over sorted batch; bf16 h, inline BN, fp32 out
__global__ __launch_bounds__(256) void k_pool(
    const unsigned short* __restrict__ h16, const int* __restrict__ gstart,
    const float* __restrict__ stats, const float* __restrict__ gam,
    const float* __restrict__ bet, float* __restrict__ out) {
  const int g = blockIdx.x;
  const int q = threadIdx.x & 31;
  const int r = threadIdx.x >> 5;
  const int s = gstart[g], e = gstart[g + 1];
  float4 sc, sh;
  {
    int c = q * 4;
    bnmake(stats[c + 0], stats[kD + c + 0], gam[c + 0], bet[c + 0], sc.x, sh.x);
    bnmake(stats[c + 1], stats[kD + c + 1], gam[c + 1], bet[c + 1], sc.y, sh.y);
    bnmake(stats[c + 2], stats[kD + c + 2], gam[c + 2], bet[c + 2], sc.z, sh.z);
    bnmake(stats[c + 3], stats[kD + c + 3], gam[c + 3], bet[c + 3], sc.w, sh.w);
  }
  float4 acc = make_float4(0.f, 0.f, 0.f, 0.f);
  for (int n = s + r; n < e; n += 8) {
    uint2 u = *reinterpret_cast<const uint2*>(h16 + (size_t)n * kD + q * 4);
    float4 v;
    v.x = bf2f(u.x & 0xFFFFu);
    v.y = __uint_as_float(u.x & 0xFFFF0000u);
    v.z = bf2f(u.y & 0xFFFFu);
    v.w = __uint_as_float(u.y & 0xFFFF0000u);
    acc4(acc, bnrelu4(v, sc, sh));
  }
  __shared__ float4 red[8][32];
  red[r][q] = acc;
  __syncthreads();
  if (r == 0) {
    float4 t = acc;
#pragma unroll
    for (int j = 1; j < 8; ++j) acc4(t, red[j][q]);
    reinterpret_cast<float4*>(out)[(size_t)g * 32 + q] = t;
  }
}

extern "C" void kernel_launch(void* const* d_in, const int* in_sizes, int n_in,
                              void* d_out, int out_size, void* d_ws, size_t ws_size,
                              hipStream_t stream) {
  const float* x   = (const float*)d_in[0];
  const int*   ei  = (const int*)d_in[1];
  const int*   bat = (const int*)d_in[2];
  const float* W1  = (const float*)d_in[3];
  const float* b1  = (const float*)d_in[4];
  const float* g1  = (const float*)d_in[5];
  const float* be1 = (const float*)d_in[6];
  const float* W2  = (const float*)d_in[7];
  const float* b2  = (const float*)d_in[8];
  const float* g2  = (const float*)d_in[9];
  const float* be2 = (const float*)d_in[10];
  float* out = (float*)d_out;

  char* p = (char*)d_ws;
  float* wsf = (float*)p;                       p += 16384;
  unsigned short* x16 = (unsigned short*)p;     p += (size_t)kN * kD * 2;
  unsigned short* bufA = (unsigned short*)p;    p += (size_t)kN * kD * 2;
  unsigned short* bufB = (unsigned short*)p;    p += (size_t)kN * kD * 2;
  unsigned short* Wf1 = (unsigned short*)p;     p += (size_t)kL * kD * kD * 2;
  unsigned short* Wf2 = (unsigned short*)p;     p += (size_t)kL * kD * kD * 2;
  int* rowptr = (int*)p;                        p += (kN + 2) * 4;
  int* bhist = (int*)p;                         p += (kNBuk + 1) * 4;
  int* bstart = (int*)p;                        p += (kNBuk + 1) * 4;
  int* bcur = (int*)p;                          p += (kNBuk + 1) * 4;
  int* gstart = (int*)p;                        p += (kB + 2) * 4;
  unsigned int* pairs = (unsigned int*)p;       p += (size_t)kE * 4;
  int* srcs = (int*)p;                          p += (size_t)kE * 4;

  (void)hipMemsetAsync(wsf, 0, 6 * 512 * sizeof(float), stream);
  (void)hipMemsetAsync(bhist, 0, kNBuk * sizeof(int), stream);

  // preprocessing: merged convert/bounds/bucket-hist, then tiny scan, bin, fill
  k_prep<<<kNBinBlk + kPrepThreadBlks, 256, 0, stream>>>(x, ei, bat, W1, W2, x16,
                                                         bhist, gstart, Wf1, Wf2);
  k_scanB<<<1, 512, 0, stream>>>(bhist, bstart, bcur);
  k_binpairs<<<kNBinBlk, 256, 0, stream>>>(ei, bcur, pairs);
  k_csrfill<<<kNBuk, 256, 0, stream>>>(pairs, bstart, rowptr, srcs);

  const unsigned short* curH = x16;
  const float* curStats = nullptr;
  const float* curGam = nullptr;
  const float* curBet = nullptr;
  const int ngemm = (kN + 127) / 128;

  unsigned short* aggBuf = bufA;
  unsigned short* yBuf = bufB;

  for (int l = 0; l < kL; ++l) {
    if (curStats == nullptr)
      k_gather<false><<<kN / 4, 256, 0, stream>>>(
          (const unsigned int*)curH, rowptr, srcs, nullptr, nullptr, nullptr,
          (unsigned int*)aggBuf);
    else
      k_gather<true><<<kN / 4, 256, 0, stream>>>(
          (const unsigned int*)curH, rowptr, srcs, curStats, curGam, curBet,
          (unsigned int*)aggBuf);

    float* st1 = wsf + (size_t)(l * 2 + 0) * 512;
    k_gemm<<<ngemm, 256, 0, stream>>>(aggBuf, Wf1 + (size_t)l * kD * kD,
                                      b1 + l * kD, nullptr, nullptr, nullptr,
                                      yBuf, st1, st1 + kD);

    float* st2 = wsf + (size_t)(l * 2 + 1) * 512;
    k_gemm<<<ngemm, 256, 0, stream>>>(yBuf, Wf2 + (size_t)l * kD * kD,
                                      b2 + l * kD, st1, g1 + l * kD, be1 + l * kD,
                                      aggBuf, st2, st2 + kD);

    curH = aggBuf;
    curStats = st2;
    curGam = g2 + l * kD;
    curBet = be2 + l * kD;
    unsigned short* tmp = aggBuf;
    aggBuf = yBuf;
    yBuf = tmp;
  }

  k_pool<<<kB, 256, 0, stream>>>(curH, gstart, curStats, curGam, curBet, out);
}